// Round 1
// baseline (577.198 us; speedup 1.0000x reference)
//
#include <hip/hip_runtime.h>
#include <math.h>

// Problem constants (verified against in_sizes at launch)
// x:[1,N,3,28,28] N=4096, S=64 segments, L=500, D=128, FLAT=800

// ---------------- K1: conv1 (3->20, 5x5 VALID) + bias + relu + maxpool2 ----------------
// x[n]: [3,28,28] -> h1[n]: [20,12,12]
__global__ __launch_bounds__(256) void k_conv1(const float* __restrict__ x,
                                               const float* __restrict__ w,   // [20,3,5,5]
                                               const float* __restrict__ b,   // [20]
                                               float* __restrict__ h1) {
  __shared__ float xs[3 * 28 * 28];   // 2352
  __shared__ float ws[20 * 3 * 25];   // 1500
  __shared__ float bs[20];
  int n = blockIdx.x;
  int tid = threadIdx.x;
  const float* xp = x + (size_t)n * 2352;
  for (int i = tid; i < 2352; i += 256) xs[i] = xp[i];
  for (int i = tid; i < 1500; i += 256) ws[i] = w[i];
  if (tid < 20) bs[tid] = b[tid];
  __syncthreads();
  if (tid >= 240) return;            // no further barriers
  int c = tid / 12, ph = tid % 12;
  float acc0[24], acc1[24];
  #pragma unroll
  for (int i = 0; i < 24; i++) { acc0[i] = 0.f; acc1[i] = 0.f; }
  int y0 = 2 * ph;
  for (int ci = 0; ci < 3; ci++) {
    const float* xci = xs + ci * 784;
    const float* wci = ws + (c * 3 + ci) * 25;
    for (int r = 0; r < 6; r++) {          // input rows y0..y0+5
      float xr[28];
      const float* row = xci + (y0 + r) * 28;
      #pragma unroll
      for (int j = 0; j < 28; j++) xr[j] = row[j];
      if (r <= 4) {                        // contributes to conv row y0 (kh=r)
        const float* wr = wci + r * 5;
        #pragma unroll
        for (int kw = 0; kw < 5; kw++) {
          float wv = wr[kw];
          #pragma unroll
          for (int xc = 0; xc < 24; xc++) acc0[xc] += wv * xr[xc + kw];
        }
      }
      if (r >= 1) {                        // conv row y0+1 (kh=r-1)
        const float* wr = wci + (r - 1) * 5;
        #pragma unroll
        for (int kw = 0; kw < 5; kw++) {
          float wv = wr[kw];
          #pragma unroll
          for (int xc = 0; xc < 24; xc++) acc1[xc] += wv * xr[xc + kw];
        }
      }
    }
  }
  float bias = bs[c];
  float* out = h1 + ((size_t)n * 20 + c) * 144 + ph * 12;
  #pragma unroll
  for (int pw = 0; pw < 12; pw++) {
    float m = fmaxf(fmaxf(acc0[2 * pw], acc0[2 * pw + 1]),
                    fmaxf(acc1[2 * pw], acc1[2 * pw + 1]));
    out[pw] = fmaxf(m + bias, 0.f);
  }
}

// ---------------- K2: conv2 (20->50, 5x5 VALID) + bias + relu + maxpool2 ----------------
// h1[n]: [20,12,12] -> flat[n]: [50,4,4] = 800
__global__ __launch_bounds__(256) void k_conv2(const float* __restrict__ h1,
                                               const float* __restrict__ w,   // [50,20,5,5]
                                               const float* __restrict__ b,   // [50]
                                               float* __restrict__ flat) {
  __shared__ float xsh[20 * 144];   // 2880
  __shared__ float wsh[50 * 25];    // 1250, staged per input channel
  int n = blockIdx.x;
  int tid = threadIdx.x;
  const float* xp = h1 + (size_t)n * 2880;
  for (int i = tid; i < 2880; i += 256) xsh[i] = xp[i];
  int c = tid / 4, ph = tid % 4;
  bool active = tid < 200;
  float acc0[8], acc1[8];
  #pragma unroll
  for (int i = 0; i < 8; i++) { acc0[i] = 0.f; acc1[i] = 0.f; }
  int y0 = 2 * ph;
  for (int ci = 0; ci < 20; ci++) {
    __syncthreads();                 // xsh ready (ci=0) / previous wsh consumed
    for (int i = tid; i < 1250; i += 256) {
      int cc = i / 25, kk = i % 25;
      wsh[i] = w[(cc * 20 + ci) * 25 + kk];
    }
    __syncthreads();
    if (active) {
      const float* xci = xsh + ci * 144;
      const float* wc = wsh + c * 25;
      for (int r = 0; r < 6; r++) {
        float xr[12];
        const float* row = xci + (y0 + r) * 12;
        #pragma unroll
        for (int j = 0; j < 12; j++) xr[j] = row[j];
        if (r <= 4) {
          const float* wr = wc + r * 5;
          #pragma unroll
          for (int kw = 0; kw < 5; kw++) {
            float wv = wr[kw];
            #pragma unroll
            for (int xc = 0; xc < 8; xc++) acc0[xc] += wv * xr[xc + kw];
          }
        }
        if (r >= 1) {
          const float* wr = wc + (r - 1) * 5;
          #pragma unroll
          for (int kw = 0; kw < 5; kw++) {
            float wv = wr[kw];
            #pragma unroll
            for (int xc = 0; xc < 8; xc++) acc1[xc] += wv * xr[xc + kw];
          }
        }
      }
    }
  }
  if (active) {
    float bias = b[c];
    float* out = flat + ((size_t)n * 50 + c) * 16 + ph * 4;
    #pragma unroll
    for (int pw = 0; pw < 4; pw++) {
      float m = fmaxf(fmaxf(acc0[2 * pw], acc0[2 * pw + 1]),
                      fmaxf(acc1[2 * pw], acc1[2 * pw + 1]));
      out[pw] = fmaxf(m + bias, 0.f);
    }
  }
}

// ---------------- K3: FC 800->500 + bias + relu ----------------
// flat:[N,800] @ fc_w:[800,500] ; 16 images per block
__global__ __launch_bounds__(256) void k_fc(const float* __restrict__ flat,
                                            const float* __restrict__ w,   // [800,500]
                                            const float* __restrict__ b,   // [500]
                                            float* __restrict__ H) {
  __shared__ float rows[16 * 800];   // 51.2 KB
  int n0 = blockIdx.x * 16, tid = threadIdx.x;
  for (int i = tid; i < 12800; i += 256) rows[i] = flat[(size_t)n0 * 800 + i];
  __syncthreads();
  if (tid >= 250) return;
  float acc0[16], acc1[16];
  #pragma unroll
  for (int m = 0; m < 16; m++) { acc0[m] = 0.f; acc1[m] = 0.f; }
  for (int k = 0; k < 800; k += 4) {
    #pragma unroll
    for (int kk = 0; kk < 4; kk++) {
      float w0 = w[(k + kk) * 500 + tid];
      float w1v = w[(k + kk) * 500 + tid + 250];
      #pragma unroll
      for (int m = 0; m < 16; m++) {
        float xv = rows[m * 800 + k + kk];
        acc0[m] += xv * w0;
        acc1[m] += xv * w1v;
      }
    }
  }
  float b0 = b[tid], b1v = b[tid + 250];
  #pragma unroll
  for (int m = 0; m < 16; m++) {
    H[(size_t)(n0 + m) * 500 + tid] = fmaxf(acc0[m] + b0, 0.f);
    H[(size_t)(n0 + m) * 500 + tid + 250] = fmaxf(acc1[m] + b1v, 0.f);
  }
}

// ---------------- K4: attn1 scores a[n] = tanh(H@w1+b1)@w2 + b2 ----------------
// 8 images per block, 128 threads (one per hidden unit)
__global__ __launch_bounds__(128) void k_attn1(const float* __restrict__ H,
                                               const float* __restrict__ w1,  // [500,128]
                                               const float* __restrict__ b1,  // [128]
                                               const float* __restrict__ w2,  // [128]
                                               const float* __restrict__ b2,  // [1]
                                               float* __restrict__ a,
                                               float* __restrict__ outA) {
  __shared__ float Hs[8 * 500];
  __shared__ float red[2][8];
  int n0 = blockIdx.x * 8, tid = threadIdx.x;
  for (int i = tid; i < 4000; i += 128) Hs[i] = H[(size_t)n0 * 500 + i];
  __syncthreads();
  float acc[8];
  #pragma unroll
  for (int m = 0; m < 8; m++) acc[m] = 0.f;
  #pragma unroll 4
  for (int k = 0; k < 500; k++) {
    float wv = w1[k * 128 + tid];
    #pragma unroll
    for (int m = 0; m < 8; m++) acc[m] += Hs[m * 500 + k] * wv;
  }
  float bb = b1[tid], w2v = w2[tid];
  #pragma unroll
  for (int m = 0; m < 8; m++) {
    float v = tanhf(acc[m] + bb) * w2v;
    #pragma unroll
    for (int off = 32; off > 0; off >>= 1) v += __shfl_down(v, off);
    if ((tid & 63) == 0) red[tid >> 6][m] = v;
  }
  __syncthreads();
  if (tid < 8) {
    float val = red[0][tid] + red[1][tid] + b2[0];
    a[n0 + tid] = val;
    outA[n0 + tid] = val;
  }
}

// ---------------- K5: per-segment softmax pooling -> instance_f[S,500] ----------------
__global__ __launch_bounds__(256) void k_segpool(const float* __restrict__ a,
                                                 const float* __restrict__ H,
                                                 const int* __restrict__ idx,
                                                 float* __restrict__ instf) {
  __shared__ float red[4];
  __shared__ float sval;
  int s = blockIdx.x, tid = threadIdx.x;
  int i0 = idx[s], i1 = idx[s + 1];
  // segment max
  float mx = -INFINITY;
  for (int i = i0 + tid; i < i1; i += 256) mx = fmaxf(mx, a[i]);
  #pragma unroll
  for (int off = 32; off > 0; off >>= 1) mx = fmaxf(mx, __shfl_down(mx, off));
  if ((tid & 63) == 0) red[tid >> 6] = mx;
  __syncthreads();
  if (tid == 0) sval = fmaxf(fmaxf(red[0], red[1]), fmaxf(red[2], red[3]));
  __syncthreads();
  float m = sval;
  // denom
  float sm = 0.f;
  for (int i = i0 + tid; i < i1; i += 256) sm += expf(a[i] - m);
  #pragma unroll
  for (int off = 32; off > 0; off >>= 1) sm += __shfl_down(sm, off);
  if ((tid & 63) == 0) red[tid >> 6] = sm;
  __syncthreads();
  if (tid == 0) sval = red[0] + red[1] + red[2] + red[3];
  __syncthreads();
  float inv = 1.f / sval;
  // weighted sum of H rows
  if (tid < 250) {
    float acc0 = 0.f, acc1 = 0.f;
    for (int i = i0; i < i1; i++) {
      float e = expf(a[i] - m) * inv;
      acc0 += e * H[(size_t)i * 500 + tid];
      acc1 += e * H[(size_t)i * 500 + tid + 250];
    }
    instf[s * 500 + tid] = acc0;
    instf[s * 500 + tid + 250] = acc1;
  }
}

// ---------------- K6: bag attention logits b_att[s] ----------------
__global__ __launch_bounds__(128) void k_batt(const float* __restrict__ instf,
                                              const float* __restrict__ w1,  // [500,128]
                                              const float* __restrict__ b1,  // [128]
                                              const float* __restrict__ w2,  // [128]
                                              const float* __restrict__ b2,  // [1]
                                              float* __restrict__ batt) {
  __shared__ float fs[500];
  __shared__ float red[2];
  int s = blockIdx.x, tid = threadIdx.x;
  for (int i = tid; i < 500; i += 128) fs[i] = instf[s * 500 + i];
  __syncthreads();
  float t = b1[tid];
  #pragma unroll 4
  for (int k = 0; k < 500; k++) t += fs[k] * w1[k * 128 + tid];
  float v = tanhf(t) * w2[tid];
  #pragma unroll
  for (int off = 32; off > 0; off >>= 1) v += __shfl_down(v, off);
  if ((tid & 63) == 0) red[tid >> 6] = v;
  __syncthreads();
  if (tid == 0) batt[s] = red[0] + red[1] + b2[0];
}

// ---------------- K7: softmax(b_att) -> bag feature -> classifier ----------------
__global__ __launch_bounds__(256) void k_final(const float* __restrict__ batt,
                                               const float* __restrict__ instf,
                                               const float* __restrict__ clfw,  // [500]
                                               const float* __restrict__ clfb,  // [1]
                                               float* __restrict__ out) {
  __shared__ float Bsh[64];
  __shared__ float red[4];
  int tid = threadIdx.x;
  if (tid < 64) {
    float v = batt[tid];
    float mx = v;
    #pragma unroll
    for (int off = 32; off > 0; off >>= 1) mx = fmaxf(mx, __shfl_xor(mx, off));
    float e = expf(v - mx);
    float smv = e;
    #pragma unroll
    for (int off = 32; off > 0; off >>= 1) smv += __shfl_xor(smv, off);
    Bsh[tid] = e / smv;
  }
  __syncthreads();
  float part = 0.f;
  if (tid < 250) {
    float bag0 = 0.f, bag1 = 0.f;
    #pragma unroll 4
    for (int s2 = 0; s2 < 64; s2++) {
      float Bv = Bsh[s2];
      bag0 += Bv * instf[s2 * 500 + tid];
      bag1 += Bv * instf[s2 * 500 + tid + 250];
    }
    part = bag0 * clfw[tid] + bag1 * clfw[tid + 250];
  }
  #pragma unroll
  for (int off = 32; off > 0; off >>= 1) part += __shfl_down(part, off);
  if ((tid & 63) == 0) red[tid >> 6] = part;
  __syncthreads();
  if (tid == 0) {
    float z = red[0] + red[1] + red[2] + red[3] + clfb[0];
    out[0] = 1.f / (1.f + expf(-z));
    out[1] = (z >= 0.f) ? 1.f : 0.f;   // sigmoid(z)>=0.5 <=> z>=0
  }
}

extern "C" void kernel_launch(void* const* d_in, const int* in_sizes, int n_in,
                              void* d_out, int out_size, void* d_ws, size_t ws_size,
                              hipStream_t stream) {
  const float* x       = (const float*)d_in[0];
  const int*   idx     = (const int*)d_in[1];
  const float* conv1_w = (const float*)d_in[2];
  const float* conv1_b = (const float*)d_in[3];
  const float* conv2_w = (const float*)d_in[4];
  const float* conv2_b = (const float*)d_in[5];
  const float* fc_w    = (const float*)d_in[6];
  const float* fc_b    = (const float*)d_in[7];
  const float* a1_w1   = (const float*)d_in[8];
  const float* a1_b1   = (const float*)d_in[9];
  const float* a1_w2   = (const float*)d_in[10];
  const float* a1_b2   = (const float*)d_in[11];
  const float* a2_w1   = (const float*)d_in[12];
  const float* a2_b1   = (const float*)d_in[13];
  const float* a2_w2   = (const float*)d_in[14];
  const float* a2_b2   = (const float*)d_in[15];
  const float* clf_w   = (const float*)d_in[16];
  const float* clf_b   = (const float*)d_in[17];
  float* out = (float*)d_out;

  int N = in_sizes[0] / 2352;     // 4096
  int S = in_sizes[1] - 1;        // 64

  // workspace layout (floats)
  float* ws    = (float*)d_ws;
  float* h1    = ws;                          // N*2880
  float* flat  = h1 + (size_t)N * 2880;       // N*800
  float* H     = flat + (size_t)N * 800;      // N*500
  float* a     = H + (size_t)N * 500;         // N
  float* instf = a + N;                       // S*500
  float* batt  = instf + (size_t)S * 500;     // S

  k_conv1<<<N, 256, 0, stream>>>(x, conv1_w, conv1_b, h1);
  k_conv2<<<N, 256, 0, stream>>>(h1, conv2_w, conv2_b, flat);
  k_fc<<<N / 16, 256, 0, stream>>>(flat, fc_w, fc_b, H);
  k_attn1<<<N / 8, 128, 0, stream>>>(H, a1_w1, a1_b1, a1_w2, a1_b2, a, out + 2);
  k_segpool<<<S, 256, 0, stream>>>(a, H, idx, instf);
  k_batt<<<S, 128, 0, stream>>>(instf, a2_w1, a2_b1, a2_w2, a2_b2, batt);
  k_final<<<1, 256, 0, stream>>>(batt, instf, clf_w, clf_b, out);
}

// Round 3
// 352.575 us; speedup vs baseline: 1.6371x; 1.6371x over previous
//
#include <hip/hip_runtime.h>
#include <math.h>

typedef _Float16 f16x8 __attribute__((ext_vector_type(8)));
typedef float    f32x4 __attribute__((ext_vector_type(4)));

static __device__ __forceinline__ unsigned short f2h(float f) {
  _Float16 h = (_Float16)f;                       // RNE
  return __builtin_bit_cast(unsigned short, h);
}

// ---------------- K0: one-time weight prep for conv2 ----------------
// conv2_w [50,20,5,5] fp32 -> Wg [25][64][24] fp16 (co pad 50->64, ci pad 20->24, zeros)
__global__ __launch_bounds__(256) void k_prepw(const float* __restrict__ w,
                                               unsigned short* __restrict__ Wg) {
  int i = blockIdx.x * 256 + threadIdx.x;        // < 38400
  if (i >= 38400) return;
  int tap = i / 1536, r = i % 1536;
  int co = r / 24, ci = r % 24;
  float val = (co < 50 && ci < 20) ? w[(co * 20 + ci) * 25 + tap] : 0.f;
  Wg[i] = f2h(val);
}

// ---------------- K1: conv1 (3->20, 5x5 VALID) + bias + relu + maxpool2 ----------------
// x[n]: [3,28,28] -> h1cl[n]: [12][12][24] fp16 channel-last (ci 20-23 zero)
__global__ __launch_bounds__(256) void k_conv1(const float* __restrict__ x,
                                               const float* __restrict__ w,   // [20,3,5,5]
                                               const float* __restrict__ b,   // [20]
                                               unsigned short* __restrict__ h1cl) {
  __shared__ float xs[3 * 28 * 28];   // 2352
  __shared__ float ws[20 * 3 * 25];   // 1500
  __shared__ float bs[20];
  int n = blockIdx.x;
  int tid = threadIdx.x;
  const float* xp = x + (size_t)n * 2352;
  for (int i = tid; i < 2352; i += 256) xs[i] = xp[i];
  for (int i = tid; i < 1500; i += 256) ws[i] = w[i];
  if (tid < 20) bs[tid] = b[tid];
  __syncthreads();
  unsigned short* outimg = h1cl + (size_t)n * 3456;
  if (tid >= 240) {
    int t = tid - 240;
    for (int i = t; i < 576; i += 16) {
      int pixel = i >> 2, cc = 20 + (i & 3);
      outimg[pixel * 24 + cc] = 0;
    }
    return;
  }
  int c = tid / 12, ph = tid % 12;
  float acc0[24], acc1[24];
  #pragma unroll
  for (int i = 0; i < 24; i++) { acc0[i] = 0.f; acc1[i] = 0.f; }
  int y0 = 2 * ph;
  for (int ci = 0; ci < 3; ci++) {
    const float* xci = xs + ci * 784;
    const float* wci = ws + (c * 3 + ci) * 25;
    for (int r = 0; r < 6; r++) {
      float xr[28];
      const float* row = xci + (y0 + r) * 28;
      #pragma unroll
      for (int j = 0; j < 28; j++) xr[j] = row[j];
      if (r <= 4) {
        const float* wr = wci + r * 5;
        #pragma unroll
        for (int kw = 0; kw < 5; kw++) {
          float wv = wr[kw];
          #pragma unroll
          for (int xc = 0; xc < 24; xc++) acc0[xc] += wv * xr[xc + kw];
        }
      }
      if (r >= 1) {
        const float* wr = wci + (r - 1) * 5;
        #pragma unroll
        for (int kw = 0; kw < 5; kw++) {
          float wv = wr[kw];
          #pragma unroll
          for (int xc = 0; xc < 24; xc++) acc1[xc] += wv * xr[xc + kw];
        }
      }
    }
  }
  float bias = bs[c];
  #pragma unroll
  for (int pw = 0; pw < 12; pw++) {
    float m = fmaxf(fmaxf(acc0[2 * pw], acc0[2 * pw + 1]),
                    fmaxf(acc1[2 * pw], acc1[2 * pw + 1]));
    outimg[(ph * 12 + pw) * 24 + c] = f2h(fmaxf(m + bias, 0.f));
  }
}

// ---------------- K2: conv2 via fp16 MFMA implicit GEMM ----------------
// h1cl[n]:[12][12][24] fp16 -> flat[n]:[50][4][4] fp32 (relu(maxpool+bias))
// per block: 8 images; per wave: 2 images (M=128 = 8 m-tiles), N=64 (50 pad), K=25 taps x 32 ci-pad

struct C2Frags { uint4 a[8]; uint4 b[4]; };

static __device__ __forceinline__ void c2_load(C2Frags& F, const unsigned short* Xs,
                                               const unsigned short* Ws, int tap,
                                               int wave, int r16, int g) {
  int kh = tap / 5, kw = tap % 5;
  #pragma unroll
  for (int nt = 0; nt < 4; nt++) {
    int co = 16 * nt + r16;
    int off = tap * 1536 + co * 24 + 8 * g;
    uint4 u = *(const uint4*)(Ws + (g == 3 ? 0 : off));
    if (g == 3) u = make_uint4(0, 0, 0, 0);   // ci 24..31 pad lanes -> zero
    F.b[nt] = u;
  }
  #pragma unroll
  for (int mt = 0; mt < 8; mt++) {
    int im = 2 * wave + (mt >> 2);
    int posl = (mt & 3) * 16 + r16;
    int oy = posl >> 3, ox = posl & 7;
    int off = im * 3456 + ((oy + kh) * 12 + (ox + kw)) * 24 + 8 * g;
    F.a[mt] = *(const uint4*)(Xs + off);      // g==3 reads junk; nullified by b==0
  }
}

static __device__ __forceinline__ void c2_mma(f32x4 acc[8][4], const C2Frags& F) {
  #pragma unroll
  for (int mt = 0; mt < 8; mt++) {
    f16x8 av = __builtin_bit_cast(f16x8, F.a[mt]);
    #pragma unroll
    for (int nt = 0; nt < 4; nt++) {
      acc[mt][nt] = __builtin_amdgcn_mfma_f32_16x16x32_f16(
          av, __builtin_bit_cast(f16x8, F.b[nt]), acc[mt][nt], 0, 0, 0);
    }
  }
}

__global__ __launch_bounds__(256, 1) void k_conv2_mfma(const unsigned short* __restrict__ h1cl,
                                                       const unsigned short* __restrict__ Wg,  // [25][64][24] fp16
                                                       const float* __restrict__ b,            // [50]
                                                       float* __restrict__ flat) {
  __shared__ unsigned short Xs[8 * 3456];     // 55296 B
  __shared__ unsigned short Ws[25 * 64 * 24]; // 76800 B
  int tid = threadIdx.x;
  int n0 = blockIdx.x * 8;

  {
    const uint4* src = (const uint4*)(h1cl + (size_t)n0 * 3456);
    uint4* dst = (uint4*)Xs;
    for (int i = tid; i < 3456; i += 256) dst[i] = src[i];
  }
  {
    const uint4* src = (const uint4*)Wg;
    uint4* dst = (uint4*)Ws;
    for (int i = tid; i < 4800; i += 256) dst[i] = src[i];
  }
  __syncthreads();

  int wave = tid >> 6, lane = tid & 63;
  int r16 = lane & 15, g = lane >> 4;

  f32x4 acc[8][4];
  #pragma unroll
  for (int mt = 0; mt < 8; mt++)
    #pragma unroll
    for (int nt = 0; nt < 4; nt++) acc[mt][nt] = (f32x4){0.f, 0.f, 0.f, 0.f};

  C2Frags FA, FB;
  c2_load(FA, Xs, Ws, 0, wave, r16, g);
  for (int tap = 0; tap < 25; tap += 2) {
    if (tap + 1 < 25) c2_load(FB, Xs, Ws, tap + 1, wave, r16, g);
    c2_mma(acc, FA);
    if (tap + 2 < 25) c2_load(FA, Xs, Ws, tap + 2, wave, r16, g);
    if (tap + 1 < 25) c2_mma(acc, FB);
  }

  // epilogue: 2x2 maxpool + bias + relu -> flat[n][50][4][4]
  #pragma unroll
  for (int mt = 0; mt < 8; mt++) {
    int n = n0 + 2 * wave + (mt >> 2);
    int py = mt & 3;
    #pragma unroll
    for (int nt = 0; nt < 4; nt++) {
      int co = 16 * nt + r16;
      f32x4 c = acc[mt][nt];
      float h0 = fmaxf(c[0], c[1]);
      float h1 = fmaxf(c[2], c[3]);
      float v0 = fmaxf(h0, __shfl_xor(h0, 32));   // g0<->g2, g1<->g3
      float v1 = fmaxf(h1, __shfl_xor(h1, 32));
      if (g < 2 && co < 50) {
        float bias = b[co];
        v0 = fmaxf(v0 + bias, 0.f);
        v1 = fmaxf(v1 + bias, 0.f);
        float2 val; val.x = v0; val.y = v1;
        *(float2*)(flat + ((size_t)n * 50 + co) * 16 + py * 4 + 2 * g) = val;
      }
    }
  }
}

// ---------------- K3: FC 800->500 + bias + relu ----------------
__global__ __launch_bounds__(256) void k_fc(const float* __restrict__ flat,
                                            const float* __restrict__ w,   // [800,500]
                                            const float* __restrict__ b,   // [500]
                                            float* __restrict__ H) {
  __shared__ float rows[16 * 800];   // 51.2 KB
  int n0 = blockIdx.x * 16, tid = threadIdx.x;
  for (int i = tid; i < 12800; i += 256) rows[i] = flat[(size_t)n0 * 800 + i];
  __syncthreads();
  if (tid >= 250) return;
  float acc0[16], acc1[16];
  #pragma unroll
  for (int m = 0; m < 16; m++) { acc0[m] = 0.f; acc1[m] = 0.f; }
  for (int k = 0; k < 800; k += 4) {
    #pragma unroll
    for (int kk = 0; kk < 4; kk++) {
      float w0 = w[(k + kk) * 500 + tid];
      float w1v = w[(k + kk) * 500 + tid + 250];
      #pragma unroll
      for (int m = 0; m < 16; m++) {
        float xv = rows[m * 800 + k + kk];
        acc0[m] += xv * w0;
        acc1[m] += xv * w1v;
      }
    }
  }
  float b0 = b[tid], b1v = b[tid + 250];
  #pragma unroll
  for (int m = 0; m < 16; m++) {
    H[(size_t)(n0 + m) * 500 + tid] = fmaxf(acc0[m] + b0, 0.f);
    H[(size_t)(n0 + m) * 500 + tid + 250] = fmaxf(acc1[m] + b1v, 0.f);
  }
}

// ---------------- K4: attn1 scores ----------------
__global__ __launch_bounds__(128) void k_attn1(const float* __restrict__ H,
                                               const float* __restrict__ w1,  // [500,128]
                                               const float* __restrict__ b1,  // [128]
                                               const float* __restrict__ w2,  // [128]
                                               const float* __restrict__ b2,  // [1]
                                               float* __restrict__ a,
                                               float* __restrict__ outA) {
  __shared__ float Hs[8 * 500];
  __shared__ float red[2][8];
  int n0 = blockIdx.x * 8, tid = threadIdx.x;
  for (int i = tid; i < 4000; i += 128) Hs[i] = H[(size_t)n0 * 500 + i];
  __syncthreads();
  float acc[8];
  #pragma unroll
  for (int m = 0; m < 8; m++) acc[m] = 0.f;
  #pragma unroll 4
  for (int k = 0; k < 500; k++) {
    float wv = w1[k * 128 + tid];
    #pragma unroll
    for (int m = 0; m < 8; m++) acc[m] += Hs[m * 500 + k] * wv;
  }
  float bb = b1[tid], w2v = w2[tid];
  #pragma unroll
  for (int m = 0; m < 8; m++) {
    float v = tanhf(acc[m] + bb) * w2v;
    #pragma unroll
    for (int off = 32; off > 0; off >>= 1) v += __shfl_down(v, off);
    if ((tid & 63) == 0) red[tid >> 6][m] = v;
  }
  __syncthreads();
  if (tid < 8) {
    float val = red[0][tid] + red[1][tid] + b2[0];
    a[n0 + tid] = val;
    outA[n0 + tid] = val;
  }
}

// ---------------- K5: per-segment softmax pooling -> instance_f[S,500] ----------------
__global__ __launch_bounds__(256) void k_segpool(const float* __restrict__ a,
                                                 const float* __restrict__ H,
                                                 const int* __restrict__ idx,
                                                 float* __restrict__ instf) {
  __shared__ float red[4];
  __shared__ float sval;
  int s = blockIdx.x, tid = threadIdx.x;
  int i0 = idx[s], i1 = idx[s + 1];
  float mx = -INFINITY;
  for (int i = i0 + tid; i < i1; i += 256) mx = fmaxf(mx, a[i]);
  #pragma unroll
  for (int off = 32; off > 0; off >>= 1) mx = fmaxf(mx, __shfl_down(mx, off));
  if ((tid & 63) == 0) red[tid >> 6] = mx;
  __syncthreads();
  if (tid == 0) sval = fmaxf(fmaxf(red[0], red[1]), fmaxf(red[2], red[3]));
  __syncthreads();
  float m = sval;
  float sm = 0.f;
  for (int i = i0 + tid; i < i1; i += 256) sm += expf(a[i] - m);
  #pragma unroll
  for (int off = 32; off > 0; off >>= 1) sm += __shfl_down(sm, off);
  if ((tid & 63) == 0) red[tid >> 6] = sm;
  __syncthreads();
  if (tid == 0) sval = red[0] + red[1] + red[2] + red[3];
  __syncthreads();
  float inv = 1.f / sval;
  if (tid < 250) {
    float acc0 = 0.f, acc1 = 0.f;
    for (int i = i0; i < i1; i++) {
      float e = expf(a[i] - m) * inv;
      acc0 += e * H[(size_t)i * 500 + tid];
      acc1 += e * H[(size_t)i * 500 + tid + 250];
    }
    instf[s * 500 + tid] = acc0;
    instf[s * 500 + tid + 250] = acc1;
  }
}

// ---------------- K6: bag attention logits ----------------
__global__ __launch_bounds__(128) void k_batt(const float* __restrict__ instf,
                                              const float* __restrict__ w1,
                                              const float* __restrict__ b1,
                                              const float* __restrict__ w2,
                                              const float* __restrict__ b2,
                                              float* __restrict__ batt) {
  __shared__ float fs[500];
  __shared__ float red[2];
  int s = blockIdx.x, tid = threadIdx.x;
  for (int i = tid; i < 500; i += 128) fs[i] = instf[s * 500 + i];
  __syncthreads();
  float t = b1[tid];
  #pragma unroll 4
  for (int k = 0; k < 500; k++) t += fs[k] * w1[k * 128 + tid];
  float v = tanhf(t) * w2[tid];
  #pragma unroll
  for (int off = 32; off > 0; off >>= 1) v += __shfl_down(v, off);
  if ((tid & 63) == 0) red[tid >> 6] = v;
  __syncthreads();
  if (tid == 0) batt[s] = red[0] + red[1] + b2[0];
}

// ---------------- K7: softmax(b_att) -> bag feature -> classifier ----------------
__global__ __launch_bounds__(256) void k_final(const float* __restrict__ batt,
                                               const float* __restrict__ instf,
                                               const float* __restrict__ clfw,
                                               const float* __restrict__ clfb,
                                               float* __restrict__ out) {
  __shared__ float Bsh[64];
  __shared__ float red[4];
  int tid = threadIdx.x;
  if (tid < 64) {
    float v = batt[tid];
    float mx = v;
    #pragma unroll
    for (int off = 32; off > 0; off >>= 1) mx = fmaxf(mx, __shfl_xor(mx, off));
    float e = expf(v - mx);
    float smv = e;
    #pragma unroll
    for (int off = 32; off > 0; off >>= 1) smv += __shfl_xor(smv, off);
    Bsh[tid] = e / smv;
  }
  __syncthreads();
  float part = 0.f;
  if (tid < 250) {
    float bag0 = 0.f, bag1 = 0.f;
    #pragma unroll 4
    for (int s2 = 0; s2 < 64; s2++) {
      float Bv = Bsh[s2];
      bag0 += Bv * instf[s2 * 500 + tid];
      bag1 += Bv * instf[s2 * 500 + tid + 250];
    }
    part = bag0 * clfw[tid] + bag1 * clfw[tid + 250];
  }
  #pragma unroll
  for (int off = 32; off > 0; off >>= 1) part += __shfl_down(part, off);
  if ((tid & 63) == 0) red[tid >> 6] = part;
  __syncthreads();
  if (tid == 0) {
    float z = red[0] + red[1] + red[2] + red[3] + clfb[0];
    out[0] = 1.f / (1.f + expf(-z));
    out[1] = (z >= 0.f) ? 1.f : 0.f;
  }
}

extern "C" void kernel_launch(void* const* d_in, const int* in_sizes, int n_in,
                              void* d_out, int out_size, void* d_ws, size_t ws_size,
                              hipStream_t stream) {
  const float* x       = (const float*)d_in[0];
  const int*   idx     = (const int*)d_in[1];
  const float* conv1_w = (const float*)d_in[2];
  const float* conv1_b = (const float*)d_in[3];
  const float* conv2_w = (const float*)d_in[4];
  const float* conv2_b = (const float*)d_in[5];
  const float* fc_w    = (const float*)d_in[6];
  const float* fc_b    = (const float*)d_in[7];
  const float* a1_w1   = (const float*)d_in[8];
  const float* a1_b1   = (const float*)d_in[9];
  const float* a1_w2   = (const float*)d_in[10];
  const float* a1_b2   = (const float*)d_in[11];
  const float* a2_w1   = (const float*)d_in[12];
  const float* a2_b1   = (const float*)d_in[13];
  const float* a2_w2   = (const float*)d_in[14];
  const float* a2_b2   = (const float*)d_in[15];
  const float* clf_w   = (const float*)d_in[16];
  const float* clf_b   = (const float*)d_in[17];
  float* out = (float*)d_out;

  int N = in_sizes[0] / 2352;     // 4096
  int S = in_sizes[1] - 1;        // 64

  // workspace layout
  float* wsf   = (float*)d_ws;
  float* flat  = wsf;                          // N*800 f32
  float* H     = flat + (size_t)N * 800;       // N*500
  float* a     = H + (size_t)N * 500;          // N
  float* instf = a + N;                        // S*500
  float* batt  = instf + (size_t)S * 500;      // S
  unsigned short* h1cl = (unsigned short*)(batt + S + 8);   // N*3456 fp16 (16B-aligned)
  unsigned short* Wg   = h1cl + (size_t)N * 3456;           // 38400 fp16

  k_prepw<<<150, 256, 0, stream>>>(conv2_w, Wg);
  k_conv1<<<N, 256, 0, stream>>>(x, conv1_w, conv1_b, h1cl);
  k_conv2_mfma<<<N / 8, 256, 0, stream>>>(h1cl, Wg, conv2_b, flat);
  k_fc<<<N / 16, 256, 0, stream>>>(flat, fc_w, fc_b, H);
  k_attn1<<<N / 8, 128, 0, stream>>>(H, a1_w1, a1_b1, a1_w2, a1_b2, a, out + 2);
  k_segpool<<<S, 256, 0, stream>>>(a, H, idx, instf);
  k_batt<<<S, 128, 0, stream>>>(instf, a2_w1, a2_b1, a2_w2, a2_b2, batt);
  k_final<<<1, 256, 0, stream>>>(batt, instf, clf_w, clf_b, out);
}

// Round 4
// 292.467 us; speedup vs baseline: 1.9735x; 1.2055x over previous
//
#include <hip/hip_runtime.h>
#include <math.h>

typedef _Float16 f16x8 __attribute__((ext_vector_type(8)));
typedef float    f32x4 __attribute__((ext_vector_type(4)));

static __device__ __forceinline__ unsigned short f2h(float f) {
  _Float16 h = (_Float16)f;                       // RNE
  return __builtin_bit_cast(unsigned short, h);
}

// ---------------- K0a: conv2 weight prep ----------------
// conv2_w [50,20,5,5] fp32 -> Wg [25][64][24] fp16 (co pad 50->64, ci pad 20->24)
__global__ __launch_bounds__(256) void k_prepw(const float* __restrict__ w,
                                               unsigned short* __restrict__ Wg) {
  int i = blockIdx.x * 256 + threadIdx.x;        // < 38400
  if (i >= 38400) return;
  int tap = i / 1536, r = i % 1536;
  int co = r / 24, ci = r % 24;
  float val = (co < 50 && ci < 20) ? w[(co * 20 + ci) * 25 + tap] : 0.f;
  Wg[i] = f2h(val);
}

// ---------------- K0b: conv1 weight prep ----------------
// conv1_w [20,3,5,5] fp32 -> Wc1g [5][32][40] fp16: [kh][co(pad32)][kw(8)*4ci], co-stride 40
__global__ __launch_bounds__(256) void k_prepw1(const float* __restrict__ w,
                                                unsigned short* __restrict__ Wc1g) {
  int i = blockIdx.x * 256 + threadIdx.x;        // < 6400
  if (i >= 6400) return;
  int kh = i / 1280, r = i % 1280;
  int co = r / 40, q = r % 40;
  int kw = q >> 2, ci = q & 3;
  float val = (co < 20 && ci < 3 && kw < 5) ? w[((co * 3 + ci) * 5 + kh) * 5 + kw] : 0.f;
  Wc1g[i] = f2h(val);
}

// ---------------- K1: conv1 via fp16 MFMA implicit GEMM ----------------
// x[n]:[3,28,28] f32 -> h1cl[n]:[12][12][24] fp16 channel-last (relu(pool(conv+bias)))
// Per block: 4 images (1/wave). M=576 pos (36 tiles of 2x8), N=2x16 co, K=5 kh-steps of 32 (8kw x 4ci)
__global__ __launch_bounds__(256, 2) void k_conv1_mfma(const float* __restrict__ x,
                                                       const unsigned short* __restrict__ Wc1g,
                                                       const float* __restrict__ b,   // [20]
                                                       unsigned short* __restrict__ h1cl) {
  __shared__ unsigned short xcl[4 * 3200];   // [img][28*28 px *4ci, pad to 3200] = 25600 B
  __shared__ unsigned short Wc1[6400];       // 12800 B
  __shared__ float bs[32];
  int tid = threadIdx.x;
  int n0 = blockIdx.x * 4;

  // stage conv1 weights (linear)
  {
    const uint4* src = (const uint4*)Wc1g;
    uint4* dst = (uint4*)Wc1;
    for (int i = tid; i < 800; i += 256) dst[i] = src[i];
  }
  if (tid < 32) bs[tid] = (tid < 20) ? b[tid] : 0.f;
  // zero pads: ci=3 per pixel, and tail 3136..3200 per image
  for (int i = tid; i < 3136; i += 256) {
    int n = i / 784, p = i - n * 784;
    xcl[n * 3200 + 4 * p + 3] = 0;
  }
  {
    int n = tid >> 6, t = tid & 63;            // 256 = 4*64
    xcl[n * 3200 + 3136 + t] = 0;
  }
  // stage x -> channel-last fp16
  {
    const float* xg = x + (size_t)n0 * 2352;
    for (int i = tid; i < 9408; i += 256) {
      float val = xg[i];
      int n = i / 2352, r = i - n * 2352;
      int ci = r / 784, p = r - ci * 784;
      xcl[n * 3200 + 4 * p + ci] = f2h(val);
    }
  }
  __syncthreads();

  int wave = tid >> 6, lane = tid & 63;
  int r16 = lane & 15, g = lane >> 4;
  const unsigned short* xb = xcl + wave * 3200;
  unsigned short* outimg = h1cl + (size_t)(n0 + wave) * 3456;

  int ay = (r16 >> 3), ax = (r16 & 7) + 2 * g;   // A-row position offsets within tile

  for (int chunk = 0; chunk < 9; ++chunk) {
    f32x4 acc[4][2];
    #pragma unroll
    for (int ti = 0; ti < 4; ti++) {
      acc[ti][0] = (f32x4){0.f, 0.f, 0.f, 0.f};
      acc[ti][1] = (f32x4){0.f, 0.f, 0.f, 0.f};
    }
    #pragma unroll
    for (int kh = 0; kh < 5; kh++) {
      uint4 bf0 = *(const uint4*)(Wc1 + (kh * 32 + r16) * 40 + 8 * g);
      uint4 bf1 = *(const uint4*)(Wc1 + (kh * 32 + 16 + r16) * 40 + 8 * g);
      f16x8 bv0 = __builtin_bit_cast(f16x8, bf0);
      f16x8 bv1 = __builtin_bit_cast(f16x8, bf1);
      #pragma unroll
      for (int ti = 0; ti < 4; ti++) {
        int t = chunk * 4 + ti;
        int ty = t / 3, tx = t - ty * 3;
        int oy = 2 * ty + ay + kh;
        int ox = 8 * tx + ax;
        const unsigned short* p = xb + (oy * 28 + ox) * 4;
        uint2 lo = *(const uint2*)p;
        uint2 hi = *(const uint2*)(p + 4);
        uint4 af; af.x = lo.x; af.y = lo.y; af.z = hi.x; af.w = hi.y;
        f16x8 av = __builtin_bit_cast(f16x8, af);
        acc[ti][0] = __builtin_amdgcn_mfma_f32_16x16x32_f16(av, bv0, acc[ti][0], 0, 0, 0);
        acc[ti][1] = __builtin_amdgcn_mfma_f32_16x16x32_f16(av, bv1, acc[ti][1], 0, 0, 0);
      }
    }
    // epilogue: 2x2 maxpool + bias + relu -> h1cl channel-last
    #pragma unroll
    for (int ti = 0; ti < 4; ti++) {
      int t = chunk * 4 + ti;
      int ty = t / 3, tx = t - ty * 3;
      #pragma unroll
      for (int nt = 0; nt < 2; nt++) {
        int co = 16 * nt + r16;
        f32x4 c = acc[ti][nt];
        float h0 = fmaxf(c[0], c[1]);
        float h1 = fmaxf(c[2], c[3]);
        float v0 = fmaxf(h0, __shfl_xor(h0, 32));   // pool rows: g <-> g^2
        float v1 = fmaxf(h1, __shfl_xor(h1, 32));
        if (g < 2 && co < 24) {
          float bias = bs[co];                       // bs=0, acc=0 for co 20..23 -> exact 0
          v0 = fmaxf(v0 + bias, 0.f);
          v1 = fmaxf(v1 + bias, 0.f);
          int px0 = 4 * tx + 2 * (g & 1);
          unsigned short* o = outimg + ((ty * 12 + px0) * 24 + co);
          o[0]  = f2h(v0);
          o[24] = f2h(v1);
        }
      }
    }
  }
}

// ---------------- K2: conv2 via fp16 MFMA implicit GEMM ----------------
struct C2Frags { uint4 a[8]; uint4 b[4]; };

static __device__ __forceinline__ void c2_load(C2Frags& F, const unsigned short* Xs,
                                               const unsigned short* Ws, int tap,
                                               int wave, int r16, int g) {
  int kh = tap / 5, kw = tap % 5;
  #pragma unroll
  for (int nt = 0; nt < 4; nt++) {
    int co = 16 * nt + r16;
    int off = tap * 1536 + co * 24 + 8 * g;
    uint4 u = *(const uint4*)(Ws + (g == 3 ? 0 : off));
    if (g == 3) u = make_uint4(0, 0, 0, 0);   // ci 24..31 pad lanes -> zero
    F.b[nt] = u;
  }
  #pragma unroll
  for (int mt = 0; mt < 8; mt++) {
    int im = 2 * wave + (mt >> 2);
    int posl = (mt & 3) * 16 + r16;
    int oy = posl >> 3, ox = posl & 7;
    int off = im * 3456 + ((oy + kh) * 12 + (ox + kw)) * 24 + 8 * g;
    F.a[mt] = *(const uint4*)(Xs + off);      // g==3 reads junk; nullified by b==0
  }
}

static __device__ __forceinline__ void c2_mma(f32x4 acc[8][4], const C2Frags& F) {
  #pragma unroll
  for (int mt = 0; mt < 8; mt++) {
    f16x8 av = __builtin_bit_cast(f16x8, F.a[mt]);
    #pragma unroll
    for (int nt = 0; nt < 4; nt++) {
      acc[mt][nt] = __builtin_amdgcn_mfma_f32_16x16x32_f16(
          av, __builtin_bit_cast(f16x8, F.b[nt]), acc[mt][nt], 0, 0, 0);
    }
  }
}

__global__ __launch_bounds__(256, 1) void k_conv2_mfma(const unsigned short* __restrict__ h1cl,
                                                       const unsigned short* __restrict__ Wg,  // [25][64][24] fp16
                                                       const float* __restrict__ b,            // [50]
                                                       float* __restrict__ flat) {
  __shared__ unsigned short Xs[8 * 3456];     // 55296 B
  __shared__ unsigned short Ws[25 * 64 * 24]; // 76800 B
  int tid = threadIdx.x;
  int n0 = blockIdx.x * 8;

  {
    const uint4* src = (const uint4*)(h1cl + (size_t)n0 * 3456);
    uint4* dst = (uint4*)Xs;
    for (int i = tid; i < 3456; i += 256) dst[i] = src[i];
  }
  {
    const uint4* src = (const uint4*)Wg;
    uint4* dst = (uint4*)Ws;
    for (int i = tid; i < 4800; i += 256) dst[i] = src[i];
  }
  __syncthreads();

  int wave = tid >> 6, lane = tid & 63;
  int r16 = lane & 15, g = lane >> 4;

  f32x4 acc[8][4];
  #pragma unroll
  for (int mt = 0; mt < 8; mt++)
    #pragma unroll
    for (int nt = 0; nt < 4; nt++) acc[mt][nt] = (f32x4){0.f, 0.f, 0.f, 0.f};

  C2Frags FA, FB;
  c2_load(FA, Xs, Ws, 0, wave, r16, g);
  for (int tap = 0; tap < 25; tap += 2) {
    if (tap + 1 < 25) c2_load(FB, Xs, Ws, tap + 1, wave, r16, g);
    c2_mma(acc, FA);
    if (tap + 2 < 25) c2_load(FA, Xs, Ws, tap + 2, wave, r16, g);
    if (tap + 1 < 25) c2_mma(acc, FB);
  }

  #pragma unroll
  for (int mt = 0; mt < 8; mt++) {
    int n = n0 + 2 * wave + (mt >> 2);
    int py = mt & 3;
    #pragma unroll
    for (int nt = 0; nt < 4; nt++) {
      int co = 16 * nt + r16;
      f32x4 c = acc[mt][nt];
      float h0 = fmaxf(c[0], c[1]);
      float h1 = fmaxf(c[2], c[3]);
      float v0 = fmaxf(h0, __shfl_xor(h0, 32));
      float v1 = fmaxf(h1, __shfl_xor(h1, 32));
      if (g < 2 && co < 50) {
        float bias = b[co];
        v0 = fmaxf(v0 + bias, 0.f);
        v1 = fmaxf(v1 + bias, 0.f);
        float2 val; val.x = v0; val.y = v1;
        *(float2*)(flat + ((size_t)n * 50 + co) * 16 + py * 4 + 2 * g) = val;
      }
    }
  }
}

// ---------------- K3: FC 800->500 + bias + relu ----------------
__global__ __launch_bounds__(256) void k_fc(const float* __restrict__ flat,
                                            const float* __restrict__ w,   // [800,500]
                                            const float* __restrict__ b,   // [500]
                                            float* __restrict__ H) {
  __shared__ float rows[16 * 800];   // 51.2 KB
  int n0 = blockIdx.x * 16, tid = threadIdx.x;
  for (int i = tid; i < 12800; i += 256) rows[i] = flat[(size_t)n0 * 800 + i];
  __syncthreads();
  if (tid >= 250) return;
  float acc0[16], acc1[16];
  #pragma unroll
  for (int m = 0; m < 16; m++) { acc0[m] = 0.f; acc1[m] = 0.f; }
  for (int k = 0; k < 800; k += 4) {
    #pragma unroll
    for (int kk = 0; kk < 4; kk++) {
      float w0 = w[(k + kk) * 500 + tid];
      float w1v = w[(k + kk) * 500 + tid + 250];
      #pragma unroll
      for (int m = 0; m < 16; m++) {
        float xv = rows[m * 800 + k + kk];
        acc0[m] += xv * w0;
        acc1[m] += xv * w1v;
      }
    }
  }
  float b0 = b[tid], b1v = b[tid + 250];
  #pragma unroll
  for (int m = 0; m < 16; m++) {
    H[(size_t)(n0 + m) * 500 + tid] = fmaxf(acc0[m] + b0, 0.f);
    H[(size_t)(n0 + m) * 500 + tid + 250] = fmaxf(acc1[m] + b1v, 0.f);
  }
}

// ---------------- K4: attn1 scores ----------------
__global__ __launch_bounds__(128) void k_attn1(const float* __restrict__ H,
                                               const float* __restrict__ w1,  // [500,128]
                                               const float* __restrict__ b1,  // [128]
                                               const float* __restrict__ w2,  // [128]
                                               const float* __restrict__ b2,  // [1]
                                               float* __restrict__ a,
                                               float* __restrict__ outA) {
  __shared__ float Hs[8 * 500];
  __shared__ float red[2][8];
  int n0 = blockIdx.x * 8, tid = threadIdx.x;
  for (int i = tid; i < 4000; i += 128) Hs[i] = H[(size_t)n0 * 500 + i];
  __syncthreads();
  float acc[8];
  #pragma unroll
  for (int m = 0; m < 8; m++) acc[m] = 0.f;
  #pragma unroll 4
  for (int k = 0; k < 500; k++) {
    float wv = w1[k * 128 + tid];
    #pragma unroll
    for (int m = 0; m < 8; m++) acc[m] += Hs[m * 500 + k] * wv;
  }
  float bb = b1[tid], w2v = w2[tid];
  #pragma unroll
  for (int m = 0; m < 8; m++) {
    float v = tanhf(acc[m] + bb) * w2v;
    #pragma unroll
    for (int off = 32; off > 0; off >>= 1) v += __shfl_down(v, off);
    if ((tid & 63) == 0) red[tid >> 6][m] = v;
  }
  __syncthreads();
  if (tid < 8) {
    float val = red[0][tid] + red[1][tid] + b2[0];
    a[n0 + tid] = val;
    outA[n0 + tid] = val;
  }
}

// ---------------- K5: per-segment softmax pooling -> instance_f[S,500] ----------------
__global__ __launch_bounds__(256) void k_segpool(const float* __restrict__ a,
                                                 const float* __restrict__ H,
                                                 const int* __restrict__ idx,
                                                 float* __restrict__ instf) {
  __shared__ float red[4];
  __shared__ float sval;
  int s = blockIdx.x, tid = threadIdx.x;
  int i0 = idx[s], i1 = idx[s + 1];
  float mx = -INFINITY;
  for (int i = i0 + tid; i < i1; i += 256) mx = fmaxf(mx, a[i]);
  #pragma unroll
  for (int off = 32; off > 0; off >>= 1) mx = fmaxf(mx, __shfl_down(mx, off));
  if ((tid & 63) == 0) red[tid >> 6] = mx;
  __syncthreads();
  if (tid == 0) sval = fmaxf(fmaxf(red[0], red[1]), fmaxf(red[2], red[3]));
  __syncthreads();
  float m = sval;
  float sm = 0.f;
  for (int i = i0 + tid; i < i1; i += 256) sm += expf(a[i] - m);
  #pragma unroll
  for (int off = 32; off > 0; off >>= 1) sm += __shfl_down(sm, off);
  if ((tid & 63) == 0) red[tid >> 6] = sm;
  __syncthreads();
  if (tid == 0) sval = red[0] + red[1] + red[2] + red[3];
  __syncthreads();
  float inv = 1.f / sval;
  if (tid < 250) {
    float acc0 = 0.f, acc1 = 0.f;
    for (int i = i0; i < i1; i++) {
      float e = expf(a[i] - m) * inv;
      acc0 += e * H[(size_t)i * 500 + tid];
      acc1 += e * H[(size_t)i * 500 + tid + 250];
    }
    instf[s * 500 + tid] = acc0;
    instf[s * 500 + tid + 250] = acc1;
  }
}

// ---------------- K6: bag attention logits ----------------
__global__ __launch_bounds__(128) void k_batt(const float* __restrict__ instf,
                                              const float* __restrict__ w1,
                                              const float* __restrict__ b1,
                                              const float* __restrict__ w2,
                                              const float* __restrict__ b2,
                                              float* __restrict__ batt) {
  __shared__ float fs[500];
  __shared__ float red[2];
  int s = blockIdx.x, tid = threadIdx.x;
  for (int i = tid; i < 500; i += 128) fs[i] = instf[s * 500 + i];
  __syncthreads();
  float t = b1[tid];
  #pragma unroll 4
  for (int k = 0; k < 500; k++) t += fs[k] * w1[k * 128 + tid];
  float v = tanhf(t) * w2[tid];
  #pragma unroll
  for (int off = 32; off > 0; off >>= 1) v += __shfl_down(v, off);
  if ((tid & 63) == 0) red[tid >> 6] = v;
  __syncthreads();
  if (tid == 0) batt[s] = red[0] + red[1] + b2[0];
}

// ---------------- K7: softmax(b_att) -> bag feature -> classifier ----------------
__global__ __launch_bounds__(256) void k_final(const float* __restrict__ batt,
                                               const float* __restrict__ instf,
                                               const float* __restrict__ clfw,
                                               const float* __restrict__ clfb,
                                               float* __restrict__ out) {
  __shared__ float Bsh[64];
  __shared__ float red[4];
  int tid = threadIdx.x;
  if (tid < 64) {
    float v = batt[tid];
    float mx = v;
    #pragma unroll
    for (int off = 32; off > 0; off >>= 1) mx = fmaxf(mx, __shfl_xor(mx, off));
    float e = expf(v - mx);
    float smv = e;
    #pragma unroll
    for (int off = 32; off > 0; off >>= 1) smv += __shfl_xor(smv, off);
    Bsh[tid] = e / smv;
  }
  __syncthreads();
  float part = 0.f;
  if (tid < 250) {
    float bag0 = 0.f, bag1 = 0.f;
    #pragma unroll 4
    for (int s2 = 0; s2 < 64; s2++) {
      float Bv = Bsh[s2];
      bag0 += Bv * instf[s2 * 500 + tid];
      bag1 += Bv * instf[s2 * 500 + tid + 250];
    }
    part = bag0 * clfw[tid] + bag1 * clfw[tid + 250];
  }
  #pragma unroll
  for (int off = 32; off > 0; off >>= 1) part += __shfl_down(part, off);
  if ((tid & 63) == 0) red[tid >> 6] = part;
  __syncthreads();
  if (tid == 0) {
    float z = red[0] + red[1] + red[2] + red[3] + clfb[0];
    out[0] = 1.f / (1.f + expf(-z));
    out[1] = (z >= 0.f) ? 1.f : 0.f;
  }
}

extern "C" void kernel_launch(void* const* d_in, const int* in_sizes, int n_in,
                              void* d_out, int out_size, void* d_ws, size_t ws_size,
                              hipStream_t stream) {
  const float* x       = (const float*)d_in[0];
  const int*   idx     = (const int*)d_in[1];
  const float* conv1_w = (const float*)d_in[2];
  const float* conv1_b = (const float*)d_in[3];
  const float* conv2_w = (const float*)d_in[4];
  const float* conv2_b = (const float*)d_in[5];
  const float* fc_w    = (const float*)d_in[6];
  const float* fc_b    = (const float*)d_in[7];
  const float* a1_w1   = (const float*)d_in[8];
  const float* a1_b1   = (const float*)d_in[9];
  const float* a1_w2   = (const float*)d_in[10];
  const float* a1_b2   = (const float*)d_in[11];
  const float* a2_w1   = (const float*)d_in[12];
  const float* a2_b1   = (const float*)d_in[13];
  const float* a2_w2   = (const float*)d_in[14];
  const float* a2_b2   = (const float*)d_in[15];
  const float* clf_w   = (const float*)d_in[16];
  const float* clf_b   = (const float*)d_in[17];
  float* out = (float*)d_out;

  int N = in_sizes[0] / 2352;     // 4096
  int S = in_sizes[1] - 1;        // 64

  // workspace layout
  float* wsf   = (float*)d_ws;
  float* flat  = wsf;                          // N*800 f32
  float* H     = flat + (size_t)N * 800;       // N*500
  float* a     = H + (size_t)N * 500;          // N
  float* instf = a + N;                        // S*500
  float* batt  = instf + (size_t)S * 500;      // S
  unsigned short* h1cl = (unsigned short*)(batt + S + 8);   // N*3456 fp16 (16B-aligned)
  unsigned short* Wg   = h1cl + (size_t)N * 3456;           // 38400 fp16
  unsigned short* Wc1g = Wg + 38400;                        // 6400 fp16

  k_prepw<<<150, 256, 0, stream>>>(conv2_w, Wg);
  k_prepw1<<<25, 256, 0, stream>>>(conv1_w, Wc1g);
  k_conv1_mfma<<<N / 4, 256, 0, stream>>>(x, Wc1g, conv1_b, h1cl);
  k_conv2_mfma<<<N / 8, 256, 0, stream>>>(h1cl, Wg, conv2_b, flat);
  k_fc<<<N / 16, 256, 0, stream>>>(flat, fc_w, fc_b, H);
  k_attn1<<<N / 8, 128, 0, stream>>>(H, a1_w1, a1_b1, a1_w2, a1_b2, a, out + 2);
  k_segpool<<<S, 256, 0, stream>>>(a, H, idx, instf);
  k_batt<<<S, 128, 0, stream>>>(instf, a2_w1, a2_b1, a2_w2, a2_b2, batt);
  k_final<<<1, 256, 0, stream>>>(batt, instf, clf_w, clf_b, out);
}

// Round 5
// 223.267 us; speedup vs baseline: 2.5852x; 1.3099x over previous
//
#include <hip/hip_runtime.h>
#include <math.h>

typedef _Float16 f16x8 __attribute__((ext_vector_type(8)));
typedef float    f32x4 __attribute__((ext_vector_type(4)));

static __device__ __forceinline__ unsigned short f2h(float f) {
  _Float16 h = (_Float16)f;                       // RNE
  return __builtin_bit_cast(unsigned short, h);
}

// ---------------- K0a: conv2 weight prep ----------------
// conv2_w [50,20,5,5] fp32 -> Wg [25][64][24] fp16 (co pad 50->64, ci pad 20->24)
__global__ __launch_bounds__(256) void k_prepw(const float* __restrict__ w,
                                               unsigned short* __restrict__ Wg) {
  int i = blockIdx.x * 256 + threadIdx.x;        // < 38400
  if (i >= 38400) return;
  int tap = i / 1536, r = i % 1536;
  int co = r / 24, ci = r % 24;
  float val = (co < 50 && ci < 20) ? w[(co * 20 + ci) * 25 + tap] : 0.f;
  Wg[i] = f2h(val);
}

// ---------------- K0b: conv1 weight prep ----------------
// conv1_w [20,3,5,5] fp32 -> Wc1g [5][32][40] fp16: [kh][co(pad32)][kw(8)*4ci]
__global__ __launch_bounds__(256) void k_prepw1(const float* __restrict__ w,
                                                unsigned short* __restrict__ Wc1g) {
  int i = blockIdx.x * 256 + threadIdx.x;        // < 6400
  if (i >= 6400) return;
  int kh = i / 1280, r = i % 1280;
  int co = r / 40, q = r % 40;
  int kw = q >> 2, ci = q & 3;
  float val = (co < 20 && ci < 3 && kw < 5) ? w[((co * 3 + ci) * 5 + kh) * 5 + kw] : 0.f;
  Wc1g[i] = f2h(val);
}

// ---------------- K0c: fc weight prep ----------------
// fc_w [800,500] fp32 -> Wt [25][512][32] fp16 (kt, col pad 500->512, 32 contiguous k)
__global__ __launch_bounds__(256) void k_prepwfc(const float* __restrict__ w,
                                                 unsigned short* __restrict__ Wt) {
  int i = blockIdx.x * 256 + threadIdx.x;        // < 409600
  if (i >= 409600) return;
  int kt = i >> 14;
  int r = i & 16383;
  int nn = r >> 5, kk = r & 31;
  int k = kt * 32 + kk;
  float val = (nn < 500) ? w[k * 500 + nn] : 0.f;
  Wt[i] = f2h(val);
}

// ---------------- K1: conv1 via fp16 MFMA implicit GEMM ----------------
__global__ __launch_bounds__(256, 2) void k_conv1_mfma(const float* __restrict__ x,
                                                       const unsigned short* __restrict__ Wc1g,
                                                       const float* __restrict__ b,   // [20]
                                                       unsigned short* __restrict__ h1cl) {
  __shared__ unsigned short xcl[4 * 3200];
  __shared__ unsigned short Wc1[6400];
  __shared__ float bs[32];
  int tid = threadIdx.x;
  int n0 = blockIdx.x * 4;

  {
    const uint4* src = (const uint4*)Wc1g;
    uint4* dst = (uint4*)Wc1;
    for (int i = tid; i < 800; i += 256) dst[i] = src[i];
  }
  if (tid < 32) bs[tid] = (tid < 20) ? b[tid] : 0.f;
  for (int i = tid; i < 3136; i += 256) {
    int n = i / 784, p = i - n * 784;
    xcl[n * 3200 + 4 * p + 3] = 0;
  }
  {
    int n = tid >> 6, t = tid & 63;
    xcl[n * 3200 + 3136 + t] = 0;
  }
  {
    const float* xg = x + (size_t)n0 * 2352;
    for (int i = tid; i < 9408; i += 256) {
      float val = xg[i];
      int n = i / 2352, r = i - n * 2352;
      int ci = r / 784, p = r - ci * 784;
      xcl[n * 3200 + 4 * p + ci] = f2h(val);
    }
  }
  __syncthreads();

  int wave = tid >> 6, lane = tid & 63;
  int r16 = lane & 15, g = lane >> 4;
  const unsigned short* xb = xcl + wave * 3200;
  unsigned short* outimg = h1cl + (size_t)(n0 + wave) * 3456;

  int ay = (r16 >> 3), ax = (r16 & 7) + 2 * g;

  for (int chunk = 0; chunk < 9; ++chunk) {
    f32x4 acc[4][2];
    #pragma unroll
    for (int ti = 0; ti < 4; ti++) {
      acc[ti][0] = (f32x4){0.f, 0.f, 0.f, 0.f};
      acc[ti][1] = (f32x4){0.f, 0.f, 0.f, 0.f};
    }
    #pragma unroll
    for (int kh = 0; kh < 5; kh++) {
      uint4 bf0 = *(const uint4*)(Wc1 + (kh * 32 + r16) * 40 + 8 * g);
      uint4 bf1 = *(const uint4*)(Wc1 + (kh * 32 + 16 + r16) * 40 + 8 * g);
      f16x8 bv0 = __builtin_bit_cast(f16x8, bf0);
      f16x8 bv1 = __builtin_bit_cast(f16x8, bf1);
      #pragma unroll
      for (int ti = 0; ti < 4; ti++) {
        int t = chunk * 4 + ti;
        int ty = t / 3, tx = t - ty * 3;
        int oy = 2 * ty + ay + kh;
        int ox = 8 * tx + ax;
        const unsigned short* p = xb + (oy * 28 + ox) * 4;
        uint2 lo = *(const uint2*)p;
        uint2 hi = *(const uint2*)(p + 4);
        uint4 af; af.x = lo.x; af.y = lo.y; af.z = hi.x; af.w = hi.y;
        f16x8 av = __builtin_bit_cast(f16x8, af);
        acc[ti][0] = __builtin_amdgcn_mfma_f32_16x16x32_f16(av, bv0, acc[ti][0], 0, 0, 0);
        acc[ti][1] = __builtin_amdgcn_mfma_f32_16x16x32_f16(av, bv1, acc[ti][1], 0, 0, 0);
      }
    }
    #pragma unroll
    for (int ti = 0; ti < 4; ti++) {
      int t = chunk * 4 + ti;
      int ty = t / 3, tx = t - ty * 3;
      #pragma unroll
      for (int nt = 0; nt < 2; nt++) {
        int co = 16 * nt + r16;
        f32x4 c = acc[ti][nt];
        float h0 = fmaxf(c[0], c[1]);
        float h1 = fmaxf(c[2], c[3]);
        float v0 = fmaxf(h0, __shfl_xor(h0, 32));
        float v1 = fmaxf(h1, __shfl_xor(h1, 32));
        if (g < 2 && co < 24) {
          float bias = bs[co];
          v0 = fmaxf(v0 + bias, 0.f);
          v1 = fmaxf(v1 + bias, 0.f);
          int px0 = 4 * tx + 2 * (g & 1);
          unsigned short* o = outimg + ((ty * 12 + px0) * 24 + co);
          o[0]  = f2h(v0);
          o[24] = f2h(v1);
        }
      }
    }
  }
}

// ---------------- K2: conv2 via fp16 MFMA implicit GEMM ----------------
struct C2Frags { uint4 a[8]; uint4 b[4]; };

static __device__ __forceinline__ void c2_load(C2Frags& F, const unsigned short* Xs,
                                               const unsigned short* Ws, int tap,
                                               int wave, int r16, int g) {
  int kh = tap / 5, kw = tap % 5;
  #pragma unroll
  for (int nt = 0; nt < 4; nt++) {
    int co = 16 * nt + r16;
    int off = tap * 1536 + co * 24 + 8 * g;
    uint4 u = *(const uint4*)(Ws + (g == 3 ? 0 : off));
    if (g == 3) u = make_uint4(0, 0, 0, 0);
    F.b[nt] = u;
  }
  #pragma unroll
  for (int mt = 0; mt < 8; mt++) {
    int im = 2 * wave + (mt >> 2);
    int posl = (mt & 3) * 16 + r16;
    int oy = posl >> 3, ox = posl & 7;
    int off = im * 3456 + ((oy + kh) * 12 + (ox + kw)) * 24 + 8 * g;
    F.a[mt] = *(const uint4*)(Xs + off);
  }
}

static __device__ __forceinline__ void c2_mma(f32x4 acc[8][4], const C2Frags& F) {
  #pragma unroll
  for (int mt = 0; mt < 8; mt++) {
    f16x8 av = __builtin_bit_cast(f16x8, F.a[mt]);
    #pragma unroll
    for (int nt = 0; nt < 4; nt++) {
      acc[mt][nt] = __builtin_amdgcn_mfma_f32_16x16x32_f16(
          av, __builtin_bit_cast(f16x8, F.b[nt]), acc[mt][nt], 0, 0, 0);
    }
  }
}

__global__ __launch_bounds__(256, 1) void k_conv2_mfma(const unsigned short* __restrict__ h1cl,
                                                       const unsigned short* __restrict__ Wg,
                                                       const float* __restrict__ b,
                                                       unsigned short* __restrict__ flat16) {
  __shared__ unsigned short Xs[8 * 3456];
  __shared__ unsigned short Ws[25 * 64 * 24];
  int tid = threadIdx.x;
  int n0 = blockIdx.x * 8;

  {
    const uint4* src = (const uint4*)(h1cl + (size_t)n0 * 3456);
    uint4* dst = (uint4*)Xs;
    for (int i = tid; i < 3456; i += 256) dst[i] = src[i];
  }
  {
    const uint4* src = (const uint4*)Wg;
    uint4* dst = (uint4*)Ws;
    for (int i = tid; i < 4800; i += 256) dst[i] = src[i];
  }
  __syncthreads();

  int wave = tid >> 6, lane = tid & 63;
  int r16 = lane & 15, g = lane >> 4;

  f32x4 acc[8][4];
  #pragma unroll
  for (int mt = 0; mt < 8; mt++)
    #pragma unroll
    for (int nt = 0; nt < 4; nt++) acc[mt][nt] = (f32x4){0.f, 0.f, 0.f, 0.f};

  C2Frags FA, FB;
  c2_load(FA, Xs, Ws, 0, wave, r16, g);
  for (int tap = 0; tap < 25; tap += 2) {
    if (tap + 1 < 25) c2_load(FB, Xs, Ws, tap + 1, wave, r16, g);
    c2_mma(acc, FA);
    if (tap + 2 < 25) c2_load(FA, Xs, Ws, tap + 2, wave, r16, g);
    if (tap + 1 < 25) c2_mma(acc, FB);
  }

  #pragma unroll
  for (int mt = 0; mt < 8; mt++) {
    int n = n0 + 2 * wave + (mt >> 2);
    int py = mt & 3;
    #pragma unroll
    for (int nt = 0; nt < 4; nt++) {
      int co = 16 * nt + r16;
      f32x4 c = acc[mt][nt];
      float h0 = fmaxf(c[0], c[1]);
      float h1 = fmaxf(c[2], c[3]);
      float v0 = fmaxf(h0, __shfl_xor(h0, 32));
      float v1 = fmaxf(h1, __shfl_xor(h1, 32));
      if (g < 2 && co < 50) {
        float bias = b[co];
        v0 = fmaxf(v0 + bias, 0.f);
        v1 = fmaxf(v1 + bias, 0.f);
        unsigned short* o = flat16 + ((size_t)n * 50 + co) * 16 + py * 4 + 2 * g;
        o[0] = f2h(v0);
        o[1] = f2h(v1);
      }
    }
  }
}

// ---------------- K3: FC 800->500 via fp16 MFMA (no LDS, direct global frags) ----------------
// flat16 [N,800] fp16 @ Wt [25][512][32] fp16 -> H [N,500] f32 relu(+bias)
// grid 16x16 blocks; block = 4 waves stacked in M; wave tile 64 rows x 32 cols
__global__ __launch_bounds__(256) void k_fc_mfma(const unsigned short* __restrict__ flat16,
                                                 const unsigned short* __restrict__ Wt,
                                                 const float* __restrict__ b,
                                                 float* __restrict__ H) {
  int tid = threadIdx.x;
  int wave = tid >> 6, lane = tid & 63;
  int r16 = lane & 15, g = lane >> 4;
  int bm = blockIdx.x & 15, bn = blockIdx.x >> 4;
  int m0 = bm * 256 + wave * 64;
  int n0 = bn * 32;

  f32x4 acc[4][2];
  #pragma unroll
  for (int mt = 0; mt < 4; mt++) {
    acc[mt][0] = (f32x4){0.f, 0.f, 0.f, 0.f};
    acc[mt][1] = (f32x4){0.f, 0.f, 0.f, 0.f};
  }

  const unsigned short* Abase = flat16 + (size_t)(m0 + r16) * 800 + 8 * g;
  const unsigned short* Bbase = Wt + (size_t)(n0 + r16) * 32 + 8 * g;

  for (int kt = 0; kt < 25; kt++) {
    uint4 bf0 = *(const uint4*)(Bbase + kt * 16384);
    uint4 bf1 = *(const uint4*)(Bbase + kt * 16384 + 512);
    f16x8 bv0 = __builtin_bit_cast(f16x8, bf0);
    f16x8 bv1 = __builtin_bit_cast(f16x8, bf1);
    #pragma unroll
    for (int mt = 0; mt < 4; mt++) {
      uint4 af = *(const uint4*)(Abase + mt * 12800 + kt * 32);
      f16x8 av = __builtin_bit_cast(f16x8, af);
      acc[mt][0] = __builtin_amdgcn_mfma_f32_16x16x32_f16(av, bv0, acc[mt][0], 0, 0, 0);
      acc[mt][1] = __builtin_amdgcn_mfma_f32_16x16x32_f16(av, bv1, acc[mt][1], 0, 0, 0);
    }
  }

  #pragma unroll
  for (int nt = 0; nt < 2; nt++) {
    int col = n0 + nt * 16 + r16;
    if (col < 500) {
      float bias = b[col];
      #pragma unroll
      for (int mt = 0; mt < 4; mt++) {
        #pragma unroll
        for (int j = 0; j < 4; j++) {
          int row = m0 + mt * 16 + 4 * g + j;
          H[(size_t)row * 500 + col] = fmaxf(acc[mt][nt][j] + bias, 0.f);
        }
      }
    }
  }
}

// ---------------- K4: attn1 scores ----------------
__global__ __launch_bounds__(128) void k_attn1(const float* __restrict__ H,
                                               const float* __restrict__ w1,  // [500,128]
                                               const float* __restrict__ b1,  // [128]
                                               const float* __restrict__ w2,  // [128]
                                               const float* __restrict__ b2,  // [1]
                                               float* __restrict__ a,
                                               float* __restrict__ outA) {
  __shared__ float Hs[8 * 500];
  __shared__ float red[2][8];
  int n0 = blockIdx.x * 8, tid = threadIdx.x;
  for (int i = tid; i < 4000; i += 128) Hs[i] = H[(size_t)n0 * 500 + i];
  __syncthreads();
  float acc[8];
  #pragma unroll
  for (int m = 0; m < 8; m++) acc[m] = 0.f;
  #pragma unroll 4
  for (int k = 0; k < 500; k++) {
    float wv = w1[k * 128 + tid];
    #pragma unroll
    for (int m = 0; m < 8; m++) acc[m] += Hs[m * 500 + k] * wv;
  }
  float bb = b1[tid], w2v = w2[tid];
  #pragma unroll
  for (int m = 0; m < 8; m++) {
    float v = tanhf(acc[m] + bb) * w2v;
    #pragma unroll
    for (int off = 32; off > 0; off >>= 1) v += __shfl_down(v, off);
    if ((tid & 63) == 0) red[tid >> 6][m] = v;
  }
  __syncthreads();
  if (tid < 8) {
    float val = red[0][tid] + red[1][tid] + b2[0];
    a[n0 + tid] = val;
    outA[n0 + tid] = val;
  }
}

// ---------------- K5: per-segment softmax pooling -> instance_f[S,500] ----------------
__global__ __launch_bounds__(256) void k_segpool(const float* __restrict__ a,
                                                 const float* __restrict__ H,
                                                 const int* __restrict__ idx,
                                                 float* __restrict__ instf) {
  __shared__ float red[4];
  __shared__ float sval;
  int s = blockIdx.x, tid = threadIdx.x;
  int i0 = idx[s], i1 = idx[s + 1];
  float mx = -INFINITY;
  for (int i = i0 + tid; i < i1; i += 256) mx = fmaxf(mx, a[i]);
  #pragma unroll
  for (int off = 32; off > 0; off >>= 1) mx = fmaxf(mx, __shfl_down(mx, off));
  if ((tid & 63) == 0) red[tid >> 6] = mx;
  __syncthreads();
  if (tid == 0) sval = fmaxf(fmaxf(red[0], red[1]), fmaxf(red[2], red[3]));
  __syncthreads();
  float m = sval;
  float sm = 0.f;
  for (int i = i0 + tid; i < i1; i += 256) sm += expf(a[i] - m);
  #pragma unroll
  for (int off = 32; off > 0; off >>= 1) sm += __shfl_down(sm, off);
  if ((tid & 63) == 0) red[tid >> 6] = sm;
  __syncthreads();
  if (tid == 0) sval = red[0] + red[1] + red[2] + red[3];
  __syncthreads();
  float inv = 1.f / sval;
  if (tid < 250) {
    float acc0 = 0.f, acc1 = 0.f;
    for (int i = i0; i < i1; i++) {
      float e = expf(a[i] - m) * inv;
      acc0 += e * H[(size_t)i * 500 + tid];
      acc1 += e * H[(size_t)i * 500 + tid + 250];
    }
    instf[s * 500 + tid] = acc0;
    instf[s * 500 + tid + 250] = acc1;
  }
}

// ---------------- K6: bag attention logits ----------------
__global__ __launch_bounds__(128) void k_batt(const float* __restrict__ instf,
                                              const float* __restrict__ w1,
                                              const float* __restrict__ b1,
                                              const float* __restrict__ w2,
                                              const float* __restrict__ b2,
                                              float* __restrict__ batt) {
  __shared__ float fs[500];
  __shared__ float red[2];
  int s = blockIdx.x, tid = threadIdx.x;
  for (int i = tid; i < 500; i += 128) fs[i] = instf[s * 500 + i];
  __syncthreads();
  float t = b1[tid];
  #pragma unroll 4
  for (int k = 0; k < 500; k++) t += fs[k] * w1[k * 128 + tid];
  float v = tanhf(t) * w2[tid];
  #pragma unroll
  for (int off = 32; off > 0; off >>= 1) v += __shfl_down(v, off);
  if ((tid & 63) == 0) red[tid >> 6] = v;
  __syncthreads();
  if (tid == 0) batt[s] = red[0] + red[1] + b2[0];
}

// ---------------- K7: softmax(b_att) -> bag feature -> classifier ----------------
__global__ __launch_bounds__(256) void k_final(const float* __restrict__ batt,
                                               const float* __restrict__ instf,
                                               const float* __restrict__ clfw,
                                               const float* __restrict__ clfb,
                                               float* __restrict__ out) {
  __shared__ float Bsh[64];
  __shared__ float red[4];
  int tid = threadIdx.x;
  if (tid < 64) {
    float v = batt[tid];
    float mx = v;
    #pragma unroll
    for (int off = 32; off > 0; off >>= 1) mx = fmaxf(mx, __shfl_xor(mx, off));
    float e = expf(v - mx);
    float smv = e;
    #pragma unroll
    for (int off = 32; off > 0; off >>= 1) smv += __shfl_xor(smv, off);
    Bsh[tid] = e / smv;
  }
  __syncthreads();
  float part = 0.f;
  if (tid < 250) {
    float bag0 = 0.f, bag1 = 0.f;
    #pragma unroll 4
    for (int s2 = 0; s2 < 64; s2++) {
      float Bv = Bsh[s2];
      bag0 += Bv * instf[s2 * 500 + tid];
      bag1 += Bv * instf[s2 * 500 + tid + 250];
    }
    part = bag0 * clfw[tid] + bag1 * clfw[tid + 250];
  }
  #pragma unroll
  for (int off = 32; off > 0; off >>= 1) part += __shfl_down(part, off);
  if ((tid & 63) == 0) red[tid >> 6] = part;
  __syncthreads();
  if (tid == 0) {
    float z = red[0] + red[1] + red[2] + red[3] + clfb[0];
    out[0] = 1.f / (1.f + expf(-z));
    out[1] = (z >= 0.f) ? 1.f : 0.f;
  }
}

extern "C" void kernel_launch(void* const* d_in, const int* in_sizes, int n_in,
                              void* d_out, int out_size, void* d_ws, size_t ws_size,
                              hipStream_t stream) {
  const float* x       = (const float*)d_in[0];
  const int*   idx     = (const int*)d_in[1];
  const float* conv1_w = (const float*)d_in[2];
  const float* conv1_b = (const float*)d_in[3];
  const float* conv2_w = (const float*)d_in[4];
  const float* conv2_b = (const float*)d_in[5];
  const float* fc_w    = (const float*)d_in[6];
  const float* fc_b    = (const float*)d_in[7];
  const float* a1_w1   = (const float*)d_in[8];
  const float* a1_b1   = (const float*)d_in[9];
  const float* a1_w2   = (const float*)d_in[10];
  const float* a1_b2   = (const float*)d_in[11];
  const float* a2_w1   = (const float*)d_in[12];
  const float* a2_b1   = (const float*)d_in[13];
  const float* a2_w2   = (const float*)d_in[14];
  const float* a2_b2   = (const float*)d_in[15];
  const float* clf_w   = (const float*)d_in[16];
  const float* clf_b   = (const float*)d_in[17];
  float* out = (float*)d_out;

  int N = in_sizes[0] / 2352;     // 4096
  int S = in_sizes[1] - 1;        // 64

  // workspace layout
  float* wsf   = (float*)d_ws;
  float* H     = wsf;                          // N*500 f32
  float* a     = H + (size_t)N * 500;          // N
  float* instf = a + N;                        // S*500
  float* batt  = instf + (size_t)S * 500;      // S
  unsigned short* h1cl  = (unsigned short*)(batt + S + 8);   // N*3456 fp16
  unsigned short* Wg    = h1cl + (size_t)N * 3456;           // 38400
  unsigned short* Wc1g  = Wg + 38400;                        // 6400
  unsigned short* Wtfc  = Wc1g + 6400;                       // 409600
  unsigned short* flat16= Wtfc + 409600;                     // N*800 fp16

  k_prepw<<<150, 256, 0, stream>>>(conv2_w, Wg);
  k_prepw1<<<25, 256, 0, stream>>>(conv1_w, Wc1g);
  k_prepwfc<<<1600, 256, 0, stream>>>(fc_w, Wtfc);
  k_conv1_mfma<<<N / 4, 256, 0, stream>>>(x, Wc1g, conv1_b, h1cl);
  k_conv2_mfma<<<N / 8, 256, 0, stream>>>(h1cl, Wg, conv2_b, flat16);
  k_fc_mfma<<<256, 256, 0, stream>>>(flat16, Wtfc, fc_b, H);
  k_attn1<<<N / 8, 128, 0, stream>>>(H, a1_w1, a1_b1, a1_w2, a1_b2, a, out + 2);
  k_segpool<<<S, 256, 0, stream>>>(a, H, idx, instf);
  k_batt<<<S, 128, 0, stream>>>(instf, a2_w1, a2_b1, a2_w2, a2_b2, batt);
  k_final<<<1, 256, 0, stream>>>(batt, instf, clf_w, clf_b, out);
}

// Round 6
// 203.939 us; speedup vs baseline: 2.8302x; 1.0948x over previous
//
#include <hip/hip_runtime.h>
#include <math.h>

typedef _Float16 f16x8 __attribute__((ext_vector_type(8)));
typedef float    f32x4 __attribute__((ext_vector_type(4)));

static __device__ __forceinline__ unsigned short f2h(float f) {
  _Float16 h = (_Float16)f;                       // RNE
  return __builtin_bit_cast(unsigned short, h);
}

// ---------------- K0a: conv2 weight prep ----------------
__global__ __launch_bounds__(256) void k_prepw(const float* __restrict__ w,
                                               unsigned short* __restrict__ Wg) {
  int i = blockIdx.x * 256 + threadIdx.x;        // < 38400
  if (i >= 38400) return;
  int tap = i / 1536, r = i % 1536;
  int co = r / 24, ci = r % 24;
  float val = (co < 50 && ci < 20) ? w[(co * 20 + ci) * 25 + tap] : 0.f;
  Wg[i] = f2h(val);
}

// ---------------- K0b: conv1 weight prep ----------------
__global__ __launch_bounds__(256) void k_prepw1(const float* __restrict__ w,
                                                unsigned short* __restrict__ Wc1g) {
  int i = blockIdx.x * 256 + threadIdx.x;        // < 6400
  if (i >= 6400) return;
  int kh = i / 1280, r = i % 1280;
  int co = r / 40, q = r % 40;
  int kw = q >> 2, ci = q & 3;
  float val = (co < 20 && ci < 3 && kw < 5) ? w[((co * 3 + ci) * 5 + kh) * 5 + kw] : 0.f;
  Wc1g[i] = f2h(val);
}

// ---------------- K0c: fc weight prep ----------------
// fc_w [800,500] -> Wt [25][512][32] fp16
__global__ __launch_bounds__(256) void k_prepwfc(const float* __restrict__ w,
                                                 unsigned short* __restrict__ Wt) {
  int i = blockIdx.x * 256 + threadIdx.x;        // < 409600
  if (i >= 409600) return;
  int kt = i >> 14;
  int r = i & 16383;
  int nn = r >> 5, kk = r & 31;
  int k = kt * 32 + kk;
  float val = (nn < 500) ? w[k * 500 + nn] : 0.f;
  Wt[i] = f2h(val);
}

// ---------------- K0d: attn1 w1 prep ----------------
// a1_w1 [500,128] -> Wt1 [16][128][32] fp16 (K pad 500->512)
__global__ __launch_bounds__(256) void k_prepwa1(const float* __restrict__ w,
                                                 unsigned short* __restrict__ Wt1) {
  int i = blockIdx.x * 256 + threadIdx.x;        // < 65536
  if (i >= 65536) return;
  int kt = i >> 12;
  int r = i & 4095;
  int col = r >> 5, kk = r & 31;
  int k = kt * 32 + kk;
  float val = (k < 500) ? w[k * 128 + col] : 0.f;
  Wt1[i] = f2h(val);
}

// ---------------- K1: conv1 via fp16 MFMA implicit GEMM ----------------
__global__ __launch_bounds__(256, 2) void k_conv1_mfma(const float* __restrict__ x,
                                                       const unsigned short* __restrict__ Wc1g,
                                                       const float* __restrict__ b,   // [20]
                                                       unsigned short* __restrict__ h1cl) {
  __shared__ unsigned short xcl[4 * 3200];
  __shared__ unsigned short Wc1[6400];
  __shared__ float bs[32];
  int tid = threadIdx.x;
  int n0 = blockIdx.x * 4;

  {
    const uint4* src = (const uint4*)Wc1g;
    uint4* dst = (uint4*)Wc1;
    for (int i = tid; i < 800; i += 256) dst[i] = src[i];
  }
  if (tid < 32) bs[tid] = (tid < 20) ? b[tid] : 0.f;
  for (int i = tid; i < 3136; i += 256) {
    int n = i / 784, p = i - n * 784;
    xcl[n * 3200 + 4 * p + 3] = 0;
  }
  {
    int n = tid >> 6, t = tid & 63;
    xcl[n * 3200 + 3136 + t] = 0;
  }
  {
    const float* xg = x + (size_t)n0 * 2352;
    for (int i = tid; i < 9408; i += 256) {
      float val = xg[i];
      int n = i / 2352, r = i - n * 2352;
      int ci = r / 784, p = r - ci * 784;
      xcl[n * 3200 + 4 * p + ci] = f2h(val);
    }
  }
  __syncthreads();

  int wave = tid >> 6, lane = tid & 63;
  int r16 = lane & 15, g = lane >> 4;
  const unsigned short* xb = xcl + wave * 3200;
  unsigned short* outimg = h1cl + (size_t)(n0 + wave) * 3456;

  int ay = (r16 >> 3), ax = (r16 & 7) + 2 * g;

  for (int chunk = 0; chunk < 9; ++chunk) {
    f32x4 acc[4][2];
    #pragma unroll
    for (int ti = 0; ti < 4; ti++) {
      acc[ti][0] = (f32x4){0.f, 0.f, 0.f, 0.f};
      acc[ti][1] = (f32x4){0.f, 0.f, 0.f, 0.f};
    }
    #pragma unroll
    for (int kh = 0; kh < 5; kh++) {
      uint4 bf0 = *(const uint4*)(Wc1 + (kh * 32 + r16) * 40 + 8 * g);
      uint4 bf1 = *(const uint4*)(Wc1 + (kh * 32 + 16 + r16) * 40 + 8 * g);
      f16x8 bv0 = __builtin_bit_cast(f16x8, bf0);
      f16x8 bv1 = __builtin_bit_cast(f16x8, bf1);
      #pragma unroll
      for (int ti = 0; ti < 4; ti++) {
        int t = chunk * 4 + ti;
        int ty = t / 3, tx = t - ty * 3;
        int oy = 2 * ty + ay + kh;
        int ox = 8 * tx + ax;
        const unsigned short* p = xb + (oy * 28 + ox) * 4;
        uint2 lo = *(const uint2*)p;
        uint2 hi = *(const uint2*)(p + 4);
        uint4 af; af.x = lo.x; af.y = lo.y; af.z = hi.x; af.w = hi.y;
        f16x8 av = __builtin_bit_cast(f16x8, af);
        acc[ti][0] = __builtin_amdgcn_mfma_f32_16x16x32_f16(av, bv0, acc[ti][0], 0, 0, 0);
        acc[ti][1] = __builtin_amdgcn_mfma_f32_16x16x32_f16(av, bv1, acc[ti][1], 0, 0, 0);
      }
    }
    #pragma unroll
    for (int ti = 0; ti < 4; ti++) {
      int t = chunk * 4 + ti;
      int ty = t / 3, tx = t - ty * 3;
      #pragma unroll
      for (int nt = 0; nt < 2; nt++) {
        int co = 16 * nt + r16;
        f32x4 c = acc[ti][nt];
        float h0 = fmaxf(c[0], c[1]);
        float h1 = fmaxf(c[2], c[3]);
        float v0 = fmaxf(h0, __shfl_xor(h0, 32));
        float v1 = fmaxf(h1, __shfl_xor(h1, 32));
        if (g < 2 && co < 24) {
          float bias = bs[co];
          v0 = fmaxf(v0 + bias, 0.f);
          v1 = fmaxf(v1 + bias, 0.f);
          int px0 = 4 * tx + 2 * (g & 1);
          unsigned short* o = outimg + ((ty * 12 + px0) * 24 + co);
          o[0]  = f2h(v0);
          o[24] = f2h(v1);
        }
      }
    }
  }
}

// ---------------- K2: conv2 via fp16 MFMA implicit GEMM ----------------
struct C2Frags { uint4 a[8]; uint4 b[4]; };

static __device__ __forceinline__ void c2_load(C2Frags& F, const unsigned short* Xs,
                                               const unsigned short* Ws, int tap,
                                               int wave, int r16, int g) {
  int kh = tap / 5, kw = tap % 5;
  #pragma unroll
  for (int nt = 0; nt < 4; nt++) {
    int co = 16 * nt + r16;
    int off = tap * 1536 + co * 24 + 8 * g;
    uint4 u = *(const uint4*)(Ws + (g == 3 ? 0 : off));
    if (g == 3) u = make_uint4(0, 0, 0, 0);
    F.b[nt] = u;
  }
  #pragma unroll
  for (int mt = 0; mt < 8; mt++) {
    int im = 2 * wave + (mt >> 2);
    int posl = (mt & 3) * 16 + r16;
    int oy = posl >> 3, ox = posl & 7;
    int off = im * 3456 + ((oy + kh) * 12 + (ox + kw)) * 24 + 8 * g;
    F.a[mt] = *(const uint4*)(Xs + off);
  }
}

static __device__ __forceinline__ void c2_mma(f32x4 acc[8][4], const C2Frags& F) {
  #pragma unroll
  for (int mt = 0; mt < 8; mt++) {
    f16x8 av = __builtin_bit_cast(f16x8, F.a[mt]);
    #pragma unroll
    for (int nt = 0; nt < 4; nt++) {
      acc[mt][nt] = __builtin_amdgcn_mfma_f32_16x16x32_f16(
          av, __builtin_bit_cast(f16x8, F.b[nt]), acc[mt][nt], 0, 0, 0);
    }
  }
}

__global__ __launch_bounds__(256, 1) void k_conv2_mfma(const unsigned short* __restrict__ h1cl,
                                                       const unsigned short* __restrict__ Wg,
                                                       const float* __restrict__ b,
                                                       unsigned short* __restrict__ flat16) {
  __shared__ unsigned short Xs[8 * 3456];
  __shared__ unsigned short Ws[25 * 64 * 24];
  int tid = threadIdx.x;
  int n0 = blockIdx.x * 8;

  {
    const uint4* src = (const uint4*)(h1cl + (size_t)n0 * 3456);
    uint4* dst = (uint4*)Xs;
    for (int i = tid; i < 3456; i += 256) dst[i] = src[i];
  }
  {
    const uint4* src = (const uint4*)Wg;
    uint4* dst = (uint4*)Ws;
    for (int i = tid; i < 4800; i += 256) dst[i] = src[i];
  }
  __syncthreads();

  int wave = tid >> 6, lane = tid & 63;
  int r16 = lane & 15, g = lane >> 4;

  f32x4 acc[8][4];
  #pragma unroll
  for (int mt = 0; mt < 8; mt++)
    #pragma unroll
    for (int nt = 0; nt < 4; nt++) acc[mt][nt] = (f32x4){0.f, 0.f, 0.f, 0.f};

  C2Frags FA, FB;
  c2_load(FA, Xs, Ws, 0, wave, r16, g);
  for (int tap = 0; tap < 25; tap += 2) {
    if (tap + 1 < 25) c2_load(FB, Xs, Ws, tap + 1, wave, r16, g);
    c2_mma(acc, FA);
    if (tap + 2 < 25) c2_load(FA, Xs, Ws, tap + 2, wave, r16, g);
    if (tap + 1 < 25) c2_mma(acc, FB);
  }

  #pragma unroll
  for (int mt = 0; mt < 8; mt++) {
    int n = n0 + 2 * wave + (mt >> 2);
    int py = mt & 3;
    #pragma unroll
    for (int nt = 0; nt < 4; nt++) {
      int co = 16 * nt + r16;
      f32x4 c = acc[mt][nt];
      float h0 = fmaxf(c[0], c[1]);
      float h1 = fmaxf(c[2], c[3]);
      float v0 = fmaxf(h0, __shfl_xor(h0, 32));
      float v1 = fmaxf(h1, __shfl_xor(h1, 32));
      if (g < 2 && co < 50) {
        float bias = b[co];
        v0 = fmaxf(v0 + bias, 0.f);
        v1 = fmaxf(v1 + bias, 0.f);
        unsigned short* o = flat16 + ((size_t)n * 50 + co) * 16 + py * 4 + 2 * g;
        o[0] = f2h(v0);
        o[1] = f2h(v1);
      }
    }
  }
}

// ---------------- K3: FC 800->500 via fp16 MFMA ----------------
// writes H (f32, [N,500]) and H16 (fp16, [N,512], cols 500-511 = 0)
__global__ __launch_bounds__(256) void k_fc_mfma(const unsigned short* __restrict__ flat16,
                                                 const unsigned short* __restrict__ Wt,
                                                 const float* __restrict__ b,
                                                 float* __restrict__ H,
                                                 unsigned short* __restrict__ H16) {
  int tid = threadIdx.x;
  int wave = tid >> 6, lane = tid & 63;
  int r16 = lane & 15, g = lane >> 4;
  int bm = blockIdx.x & 15, bn = blockIdx.x >> 4;
  int m0 = bm * 256 + wave * 64;
  int n0 = bn * 32;

  f32x4 acc[4][2];
  #pragma unroll
  for (int mt = 0; mt < 4; mt++) {
    acc[mt][0] = (f32x4){0.f, 0.f, 0.f, 0.f};
    acc[mt][1] = (f32x4){0.f, 0.f, 0.f, 0.f};
  }

  const unsigned short* Abase = flat16 + (size_t)(m0 + r16) * 800 + 8 * g;
  const unsigned short* Bbase = Wt + (size_t)(n0 + r16) * 32 + 8 * g;

  for (int kt = 0; kt < 25; kt++) {
    uint4 bf0 = *(const uint4*)(Bbase + kt * 16384);
    uint4 bf1 = *(const uint4*)(Bbase + kt * 16384 + 512);
    f16x8 bv0 = __builtin_bit_cast(f16x8, bf0);
    f16x8 bv1 = __builtin_bit_cast(f16x8, bf1);
    #pragma unroll
    for (int mt = 0; mt < 4; mt++) {
      uint4 af = *(const uint4*)(Abase + mt * 12800 + kt * 32);
      f16x8 av = __builtin_bit_cast(f16x8, af);
      acc[mt][0] = __builtin_amdgcn_mfma_f32_16x16x32_f16(av, bv0, acc[mt][0], 0, 0, 0);
      acc[mt][1] = __builtin_amdgcn_mfma_f32_16x16x32_f16(av, bv1, acc[mt][1], 0, 0, 0);
    }
  }

  #pragma unroll
  for (int nt = 0; nt < 2; nt++) {
    int col = n0 + nt * 16 + r16;
    bool real = col < 500;
    float bias = real ? b[col] : 0.f;
    #pragma unroll
    for (int mt = 0; mt < 4; mt++) {
      #pragma unroll
      for (int j = 0; j < 4; j++) {
        int row = m0 + mt * 16 + 4 * g + j;
        float val = fmaxf(acc[mt][nt][j] + bias, 0.f);   // col>=500: acc=0,bias=0 -> 0
        if (real) H[(size_t)row * 500 + col] = val;
        H16[(size_t)row * 512 + col] = f2h(val);
      }
    }
  }
}

// ---------------- K4: attn1 via fp16 MFMA + fused tanh/w2 reduction ----------------
// H16 [N,512] @ Wt1 [16][128][32] -> scores a[N] (and A output)
// 1 wave/block, 2 m-tiles (32 rows), 8 n-tiles, 16 k-steps
__global__ __launch_bounds__(64) void k_attn1_mfma(const unsigned short* __restrict__ H16,
                                                   const unsigned short* __restrict__ Wt1,
                                                   const float* __restrict__ b1,   // [128]
                                                   const float* __restrict__ w2,   // [128]
                                                   const float* __restrict__ b2,   // [1]
                                                   float* __restrict__ a,
                                                   float* __restrict__ outA) {
  int lane = threadIdx.x;
  int r16 = lane & 15, g = lane >> 4;
  int m0 = blockIdx.x * 32;

  f32x4 acc[2][8];
  #pragma unroll
  for (int mt = 0; mt < 2; mt++)
    #pragma unroll
    for (int nt = 0; nt < 8; nt++) acc[mt][nt] = (f32x4){0.f, 0.f, 0.f, 0.f};

  const unsigned short* Abase = H16 + (size_t)(m0 + r16) * 512 + 8 * g;
  const unsigned short* Bbase = Wt1 + r16 * 32 + 8 * g;

  for (int kt = 0; kt < 16; kt++) {
    uint4 a0 = *(const uint4*)(Abase + kt * 32);
    uint4 a1 = *(const uint4*)(Abase + 16 * 512 + kt * 32);
    f16x8 av0 = __builtin_bit_cast(f16x8, a0);
    f16x8 av1 = __builtin_bit_cast(f16x8, a1);
    #pragma unroll
    for (int nt = 0; nt < 8; nt++) {
      uint4 bf = *(const uint4*)(Bbase + kt * 4096 + nt * 512);
      f16x8 bv = __builtin_bit_cast(f16x8, bf);
      acc[0][nt] = __builtin_amdgcn_mfma_f32_16x16x32_f16(av0, bv, acc[0][nt], 0, 0, 0);
      acc[1][nt] = __builtin_amdgcn_mfma_f32_16x16x32_f16(av1, bv, acc[1][nt], 0, 0, 0);
    }
  }

  float b1v[8], w2v[8];
  #pragma unroll
  for (int nt = 0; nt < 8; nt++) {
    int col = nt * 16 + r16;
    b1v[nt] = b1[col];
    w2v[nt] = w2[col];
  }
  float bb2 = b2[0];

  #pragma unroll
  for (int mt = 0; mt < 2; mt++) {
    float part[4];
    #pragma unroll
    for (int j = 0; j < 4; j++) {
      float s = 0.f;
      #pragma unroll
      for (int nt = 0; nt < 8; nt++)
        s += tanhf(acc[mt][nt][j] + b1v[nt]) * w2v[nt];
      part[j] = s;
    }
    #pragma unroll
    for (int off = 1; off < 16; off <<= 1) {
      #pragma unroll
      for (int j = 0; j < 4; j++) part[j] += __shfl_xor(part[j], off);
    }
    if (r16 == 0) {
      #pragma unroll
      for (int j = 0; j < 4; j++) {
        int row = m0 + mt * 16 + 4 * g + j;
        float val = part[j] + bb2;
        a[row] = val;
        outA[row] = val;
      }
    }
  }
}

// ---------------- K5: per-segment softmax pooling -> instance_f[S,500] ----------------
__global__ __launch_bounds__(256) void k_segpool(const float* __restrict__ a,
                                                 const float* __restrict__ H,
                                                 const int* __restrict__ idx,
                                                 float* __restrict__ instf) {
  __shared__ float red[4];
  __shared__ float sval;
  int s = blockIdx.x, tid = threadIdx.x;
  int i0 = idx[s], i1 = idx[s + 1];
  float mx = -INFINITY;
  for (int i = i0 + tid; i < i1; i += 256) mx = fmaxf(mx, a[i]);
  #pragma unroll
  for (int off = 32; off > 0; off >>= 1) mx = fmaxf(mx, __shfl_down(mx, off));
  if ((tid & 63) == 0) red[tid >> 6] = mx;
  __syncthreads();
  if (tid == 0) sval = fmaxf(fmaxf(red[0], red[1]), fmaxf(red[2], red[3]));
  __syncthreads();
  float m = sval;
  float sm = 0.f;
  for (int i = i0 + tid; i < i1; i += 256) sm += expf(a[i] - m);
  #pragma unroll
  for (int off = 32; off > 0; off >>= 1) sm += __shfl_down(sm, off);
  if ((tid & 63) == 0) red[tid >> 6] = sm;
  __syncthreads();
  if (tid == 0) sval = red[0] + red[1] + red[2] + red[3];
  __syncthreads();
  float inv = 1.f / sval;
  if (tid < 250) {
    float acc0 = 0.f, acc1 = 0.f;
    for (int i = i0; i < i1; i++) {
      float e = expf(a[i] - m) * inv;
      acc0 += e * H[(size_t)i * 500 + tid];
      acc1 += e * H[(size_t)i * 500 + tid + 250];
    }
    instf[s * 500 + tid] = acc0;
    instf[s * 500 + tid + 250] = acc1;
  }
}

// ---------------- K6: bag attention logits ----------------
__global__ __launch_bounds__(128) void k_batt(const float* __restrict__ instf,
                                              const float* __restrict__ w1,
                                              const float* __restrict__ b1,
                                              const float* __restrict__ w2,
                                              const float* __restrict__ b2,
                                              float* __restrict__ batt) {
  __shared__ float fs[500];
  __shared__ float red[2];
  int s = blockIdx.x, tid = threadIdx.x;
  for (int i = tid; i < 500; i += 128) fs[i] = instf[s * 500 + i];
  __syncthreads();
  float t = b1[tid];
  #pragma unroll 4
  for (int k = 0; k < 500; k++) t += fs[k] * w1[k * 128 + tid];
  float v = tanhf(t) * w2[tid];
  #pragma unroll
  for (int off = 32; off > 0; off >>= 1) v += __shfl_down(v, off);
  if ((tid & 63) == 0) red[tid >> 6] = v;
  __syncthreads();
  if (tid == 0) batt[s] = red[0] + red[1] + b2[0];
}

// ---------------- K7: softmax(b_att) -> bag feature -> classifier ----------------
__global__ __launch_bounds__(256) void k_final(const float* __restrict__ batt,
                                               const float* __restrict__ instf,
                                               const float* __restrict__ clfw,
                                               const float* __restrict__ clfb,
                                               float* __restrict__ out) {
  __shared__ float Bsh[64];
  __shared__ float red[4];
  int tid = threadIdx.x;
  if (tid < 64) {
    float v = batt[tid];
    float mx = v;
    #pragma unroll
    for (int off = 32; off > 0; off >>= 1) mx = fmaxf(mx, __shfl_xor(mx, off));
    float e = expf(v - mx);
    float smv = e;
    #pragma unroll
    for (int off = 32; off > 0; off >>= 1) smv += __shfl_xor(smv, off);
    Bsh[tid] = e / smv;
  }
  __syncthreads();
  float part = 0.f;
  if (tid < 250) {
    float bag0 = 0.f, bag1 = 0.f;
    #pragma unroll 4
    for (int s2 = 0; s2 < 64; s2++) {
      float Bv = Bsh[s2];
      bag0 += Bv * instf[s2 * 500 + tid];
      bag1 += Bv * instf[s2 * 500 + tid + 250];
    }
    part = bag0 * clfw[tid] + bag1 * clfw[tid + 250];
  }
  #pragma unroll
  for (int off = 32; off > 0; off >>= 1) part += __shfl_down(part, off);
  if ((tid & 63) == 0) red[tid >> 6] = part;
  __syncthreads();
  if (tid == 0) {
    float z = red[0] + red[1] + red[2] + red[3] + clfb[0];
    out[0] = 1.f / (1.f + expf(-z));
    out[1] = (z >= 0.f) ? 1.f : 0.f;
  }
}

extern "C" void kernel_launch(void* const* d_in, const int* in_sizes, int n_in,
                              void* d_out, int out_size, void* d_ws, size_t ws_size,
                              hipStream_t stream) {
  const float* x       = (const float*)d_in[0];
  const int*   idx     = (const int*)d_in[1];
  const float* conv1_w = (const float*)d_in[2];
  const float* conv1_b = (const float*)d_in[3];
  const float* conv2_w = (const float*)d_in[4];
  const float* conv2_b = (const float*)d_in[5];
  const float* fc_w    = (const float*)d_in[6];
  const float* fc_b    = (const float*)d_in[7];
  const float* a1_w1   = (const float*)d_in[8];
  const float* a1_b1   = (const float*)d_in[9];
  const float* a1_w2   = (const float*)d_in[10];
  const float* a1_b2   = (const float*)d_in[11];
  const float* a2_w1   = (const float*)d_in[12];
  const float* a2_b1   = (const float*)d_in[13];
  const float* a2_w2   = (const float*)d_in[14];
  const float* a2_b2   = (const float*)d_in[15];
  const float* clf_w   = (const float*)d_in[16];
  const float* clf_b   = (const float*)d_in[17];
  float* out = (float*)d_out;

  int N = in_sizes[0] / 2352;     // 4096
  int S = in_sizes[1] - 1;        // 64

  // workspace layout
  float* wsf   = (float*)d_ws;
  float* H     = wsf;                          // N*500 f32
  float* a     = H + (size_t)N * 500;          // N
  float* instf = a + N;                        // S*500
  float* batt  = instf + (size_t)S * 500;      // S
  unsigned short* h1cl  = (unsigned short*)(batt + S + 8);   // N*3456 fp16
  unsigned short* Wg    = h1cl + (size_t)N * 3456;           // 38400
  unsigned short* Wc1g  = Wg + 38400;                        // 6400
  unsigned short* Wtfc  = Wc1g + 6400;                       // 409600
  unsigned short* Wt1   = Wtfc + 409600;                     // 65536
  unsigned short* flat16= Wt1 + 65536;                       // N*800 fp16
  unsigned short* H16   = flat16 + (size_t)N * 800;          // N*512 fp16

  k_prepw<<<150, 256, 0, stream>>>(conv2_w, Wg);
  k_prepw1<<<25, 256, 0, stream>>>(conv1_w, Wc1g);
  k_prepwfc<<<1600, 256, 0, stream>>>(fc_w, Wtfc);
  k_prepwa1<<<256, 256, 0, stream>>>(a1_w1, Wt1);
  k_conv1_mfma<<<N / 4, 256, 0, stream>>>(x, Wc1g, conv1_b, h1cl);
  k_conv2_mfma<<<N / 8, 256, 0, stream>>>(h1cl, Wg, conv2_b, flat16);
  k_fc_mfma<<<256, 256, 0, stream>>>(flat16, Wtfc, fc_b, H, H16);
  k_attn1_mfma<<<N / 32, 64, 0, stream>>>(H16, Wt1, a1_b1, a1_w2, a1_b2, a, out + 2);
  k_segpool<<<S, 256, 0, stream>>>(a, H, idx, instf);
  k_batt<<<S, 128, 0, stream>>>(instf, a2_w1, a2_b1, a2_w2, a2_b2, batt);
  k_final<<<1, 256, 0, stream>>>(batt, instf, clf_w, clf_b, out);
}

// Round 7
// 159.957 us; speedup vs baseline: 3.6085x; 1.2750x over previous
//
#include <hip/hip_runtime.h>
#include <math.h>

typedef _Float16 f16x8 __attribute__((ext_vector_type(8)));
typedef float    f32x4 __attribute__((ext_vector_type(4)));

static __device__ __forceinline__ unsigned short f2h(float f) {
  _Float16 h = (_Float16)f;                       // RNE
  return __builtin_bit_cast(unsigned short, h);
}

// ---------------- K0a: conv2 weight prep ----------------
__global__ __launch_bounds__(256) void k_prepw(const float* __restrict__ w,
                                               unsigned short* __restrict__ Wg) {
  int i = blockIdx.x * 256 + threadIdx.x;        // < 38400
  if (i >= 38400) return;
  int tap = i / 1536, r = i % 1536;
  int co = r / 24, ci = r % 24;
  float val = (co < 50 && ci < 20) ? w[(co * 20 + ci) * 25 + tap] : 0.f;
  Wg[i] = f2h(val);
}

// ---------------- K0b: conv1 weight prep ----------------
__global__ __launch_bounds__(256) void k_prepw1(const float* __restrict__ w,
                                                unsigned short* __restrict__ Wc1g) {
  int i = blockIdx.x * 256 + threadIdx.x;        // < 6400
  if (i >= 6400) return;
  int kh = i / 1280, r = i % 1280;
  int co = r / 40, q = r % 40;
  int kw = q >> 2, ci = q & 3;
  float val = (co < 20 && ci < 3 && kw < 5) ? w[((co * 3 + ci) * 5 + kh) * 5 + kw] : 0.f;
  Wc1g[i] = f2h(val);
}

// ---------------- K0c: fc weight prep ----------------
// fc_w [800,500] -> Wt [25][512][32] fp16
__global__ __launch_bounds__(256) void k_prepwfc(const float* __restrict__ w,
                                                 unsigned short* __restrict__ Wt) {
  int i = blockIdx.x * 256 + threadIdx.x;        // < 409600
  if (i >= 409600) return;
  int kt = i >> 14;
  int r = i & 16383;
  int nn = r >> 5, kk = r & 31;
  int k = kt * 32 + kk;
  float val = (nn < 500) ? w[k * 500 + nn] : 0.f;
  Wt[i] = f2h(val);
}

// ---------------- K0d: attn1 w1 prep ----------------
// a1_w1 [500,128] -> Wt1 [16][128][32] fp16 (K pad 500->512)
__global__ __launch_bounds__(256) void k_prepwa1(const float* __restrict__ w,
                                                 unsigned short* __restrict__ Wt1) {
  int i = blockIdx.x * 256 + threadIdx.x;        // < 65536
  if (i >= 65536) return;
  int kt = i >> 12;
  int r = i & 4095;
  int col = r >> 5, kk = r & 31;
  int k = kt * 32 + kk;
  float val = (k < 500) ? w[k * 128 + col] : 0.f;
  Wt1[i] = f2h(val);
}

// ---------------- K1: conv1 via fp16 MFMA implicit GEMM ----------------
__global__ __launch_bounds__(256, 2) void k_conv1_mfma(const float* __restrict__ x,
                                                       const unsigned short* __restrict__ Wc1g,
                                                       const float* __restrict__ b,   // [20]
                                                       unsigned short* __restrict__ h1cl) {
  __shared__ unsigned short xcl[4 * 3200];
  __shared__ unsigned short Wc1[6400];
  __shared__ float bs[32];
  int tid = threadIdx.x;
  int n0 = blockIdx.x * 4;

  {
    const uint4* src = (const uint4*)Wc1g;
    uint4* dst = (uint4*)Wc1;
    for (int i = tid; i < 800; i += 256) dst[i] = src[i];
  }
  if (tid < 32) bs[tid] = (tid < 20) ? b[tid] : 0.f;
  for (int i = tid; i < 3136; i += 256) {
    int n = i / 784, p = i - n * 784;
    xcl[n * 3200 + 4 * p + 3] = 0;
  }
  {
    int n = tid >> 6, t = tid & 63;
    xcl[n * 3200 + 3136 + t] = 0;
  }
  {
    const float* xg = x + (size_t)n0 * 2352;
    for (int i = tid; i < 9408; i += 256) {
      float val = xg[i];
      int n = i / 2352, r = i - n * 2352;
      int ci = r / 784, p = r - ci * 784;
      xcl[n * 3200 + 4 * p + ci] = f2h(val);
    }
  }
  __syncthreads();

  int wave = tid >> 6, lane = tid & 63;
  int r16 = lane & 15, g = lane >> 4;
  const unsigned short* xb = xcl + wave * 3200;
  unsigned short* outimg = h1cl + (size_t)(n0 + wave) * 3456;

  int ay = (r16 >> 3), ax = (r16 & 7) + 2 * g;

  for (int chunk = 0; chunk < 9; ++chunk) {
    f32x4 acc[4][2];
    #pragma unroll
    for (int ti = 0; ti < 4; ti++) {
      acc[ti][0] = (f32x4){0.f, 0.f, 0.f, 0.f};
      acc[ti][1] = (f32x4){0.f, 0.f, 0.f, 0.f};
    }
    #pragma unroll
    for (int kh = 0; kh < 5; kh++) {
      uint4 bf0 = *(const uint4*)(Wc1 + (kh * 32 + r16) * 40 + 8 * g);
      uint4 bf1 = *(const uint4*)(Wc1 + (kh * 32 + 16 + r16) * 40 + 8 * g);
      f16x8 bv0 = __builtin_bit_cast(f16x8, bf0);
      f16x8 bv1 = __builtin_bit_cast(f16x8, bf1);
      #pragma unroll
      for (int ti = 0; ti < 4; ti++) {
        int t = chunk * 4 + ti;
        int ty = t / 3, tx = t - ty * 3;
        int oy = 2 * ty + ay + kh;
        int ox = 8 * tx + ax;
        const unsigned short* p = xb + (oy * 28 + ox) * 4;
        uint2 lo = *(const uint2*)p;
        uint2 hi = *(const uint2*)(p + 4);
        uint4 af; af.x = lo.x; af.y = lo.y; af.z = hi.x; af.w = hi.y;
        f16x8 av = __builtin_bit_cast(f16x8, af);
        acc[ti][0] = __builtin_amdgcn_mfma_f32_16x16x32_f16(av, bv0, acc[ti][0], 0, 0, 0);
        acc[ti][1] = __builtin_amdgcn_mfma_f32_16x16x32_f16(av, bv1, acc[ti][1], 0, 0, 0);
      }
    }
    #pragma unroll
    for (int ti = 0; ti < 4; ti++) {
      int t = chunk * 4 + ti;
      int ty = t / 3, tx = t - ty * 3;
      #pragma unroll
      for (int nt = 0; nt < 2; nt++) {
        int co = 16 * nt + r16;
        f32x4 c = acc[ti][nt];
        float h0 = fmaxf(c[0], c[1]);
        float h1 = fmaxf(c[2], c[3]);
        float v0 = fmaxf(h0, __shfl_xor(h0, 32));
        float v1 = fmaxf(h1, __shfl_xor(h1, 32));
        if (g < 2 && co < 24) {
          float bias = bs[co];
          v0 = fmaxf(v0 + bias, 0.f);
          v1 = fmaxf(v1 + bias, 0.f);
          int px0 = 4 * tx + 2 * (g & 1);
          unsigned short* o = outimg + ((ty * 12 + px0) * 24 + co);
          o[0]  = f2h(v0);
          o[24] = f2h(v1);
        }
      }
    }
  }
}

// ---------------- K2: conv2 via fp16 MFMA implicit GEMM ----------------
// B-fragments now load directly from global Wg (L2-resident); only images staged in LDS.
struct C2Frags { uint4 a[8]; uint4 b[4]; };

static __device__ __forceinline__ void c2_load(C2Frags& F, const unsigned short* Xs,
                                               const unsigned short* __restrict__ Wg, int tap,
                                               int wave, int r16, int g) {
  int kh = tap / 5, kw = tap % 5;
  #pragma unroll
  for (int nt = 0; nt < 4; nt++) {
    uint4 u = make_uint4(0, 0, 0, 0);
    if (g < 3) {                                   // ci 24..31 pad lanes -> zero
      int co = 16 * nt + r16;
      u = *(const uint4*)(Wg + tap * 1536 + co * 24 + 8 * g);
    }
    F.b[nt] = u;
  }
  #pragma unroll
  for (int mt = 0; mt < 8; mt++) {
    int im = 2 * wave + (mt >> 2);
    int posl = (mt & 3) * 16 + r16;
    int oy = posl >> 3, ox = posl & 7;
    int off = im * 3456 + ((oy + kh) * 12 + (ox + kw)) * 24 + 8 * g;
    F.a[mt] = *(const uint4*)(Xs + off);
  }
}

static __device__ __forceinline__ void c2_mma(f32x4 acc[8][4], const C2Frags& F) {
  #pragma unroll
  for (int mt = 0; mt < 8; mt++) {
    f16x8 av = __builtin_bit_cast(f16x8, F.a[mt]);
    #pragma unroll
    for (int nt = 0; nt < 4; nt++) {
      acc[mt][nt] = __builtin_amdgcn_mfma_f32_16x16x32_f16(
          av, __builtin_bit_cast(f16x8, F.b[nt]), acc[mt][nt], 0, 0, 0);
    }
  }
}

__global__ __launch_bounds__(256, 2) void k_conv2_mfma(const unsigned short* __restrict__ h1cl,
                                                       const unsigned short* __restrict__ Wg,
                                                       const float* __restrict__ b,
                                                       unsigned short* __restrict__ flat16) {
  __shared__ unsigned short Xs[8 * 3456];     // 55296 B -> 2 blocks/CU
  int tid = threadIdx.x;
  int n0 = blockIdx.x * 8;

  {
    const uint4* src = (const uint4*)(h1cl + (size_t)n0 * 3456);
    uint4* dst = (uint4*)Xs;
    for (int i = tid; i < 3456; i += 256) dst[i] = src[i];
  }
  __syncthreads();

  int wave = tid >> 6, lane = tid & 63;
  int r16 = lane & 15, g = lane >> 4;

  f32x4 acc[8][4];
  #pragma unroll
  for (int mt = 0; mt < 8; mt++)
    #pragma unroll
    for (int nt = 0; nt < 4; nt++) acc[mt][nt] = (f32x4){0.f, 0.f, 0.f, 0.f};

  C2Frags FA, FB;
  c2_load(FA, Xs, Wg, 0, wave, r16, g);
  for (int tap = 0; tap < 25; tap += 2) {
    if (tap + 1 < 25) c2_load(FB, Xs, Wg, tap + 1, wave, r16, g);
    c2_mma(acc, FA);
    if (tap + 2 < 25) c2_load(FA, Xs, Wg, tap + 2, wave, r16, g);
    if (tap + 1 < 25) c2_mma(acc, FB);
  }

  #pragma unroll
  for (int mt = 0; mt < 8; mt++) {
    int n = n0 + 2 * wave + (mt >> 2);
    int py = mt & 3;
    #pragma unroll
    for (int nt = 0; nt < 4; nt++) {
      int co = 16 * nt + r16;
      f32x4 c = acc[mt][nt];
      float h0 = fmaxf(c[0], c[1]);
      float h1 = fmaxf(c[2], c[3]);
      float v0 = fmaxf(h0, __shfl_xor(h0, 32));
      float v1 = fmaxf(h1, __shfl_xor(h1, 32));
      if (g < 2 && co < 50) {
        float bias = b[co];
        v0 = fmaxf(v0 + bias, 0.f);
        v1 = fmaxf(v1 + bias, 0.f);
        unsigned short* o = flat16 + ((size_t)n * 50 + co) * 16 + py * 4 + 2 * g;
        o[0] = f2h(v0);
        o[1] = f2h(v1);
      }
    }
  }
}

// ---------------- K3: FC 800->500 via fp16 MFMA ----------------
__global__ __launch_bounds__(256) void k_fc_mfma(const unsigned short* __restrict__ flat16,
                                                 const unsigned short* __restrict__ Wt,
                                                 const float* __restrict__ b,
                                                 float* __restrict__ H,
                                                 unsigned short* __restrict__ H16) {
  int tid = threadIdx.x;
  int wave = tid >> 6, lane = tid & 63;
  int r16 = lane & 15, g = lane >> 4;
  int bm = blockIdx.x & 15, bn = blockIdx.x >> 4;
  int m0 = bm * 256 + wave * 64;
  int n0 = bn * 32;

  f32x4 acc[4][2];
  #pragma unroll
  for (int mt = 0; mt < 4; mt++) {
    acc[mt][0] = (f32x4){0.f, 0.f, 0.f, 0.f};
    acc[mt][1] = (f32x4){0.f, 0.f, 0.f, 0.f};
  }

  const unsigned short* Abase = flat16 + (size_t)(m0 + r16) * 800 + 8 * g;
  const unsigned short* Bbase = Wt + (size_t)(n0 + r16) * 32 + 8 * g;

  for (int kt = 0; kt < 25; kt++) {
    uint4 bf0 = *(const uint4*)(Bbase + kt * 16384);
    uint4 bf1 = *(const uint4*)(Bbase + kt * 16384 + 512);
    f16x8 bv0 = __builtin_bit_cast(f16x8, bf0);
    f16x8 bv1 = __builtin_bit_cast(f16x8, bf1);
    #pragma unroll
    for (int mt = 0; mt < 4; mt++) {
      uint4 af = *(const uint4*)(Abase + mt * 12800 + kt * 32);
      f16x8 av = __builtin_bit_cast(f16x8, af);
      acc[mt][0] = __builtin_amdgcn_mfma_f32_16x16x32_f16(av, bv0, acc[mt][0], 0, 0, 0);
      acc[mt][1] = __builtin_amdgcn_mfma_f32_16x16x32_f16(av, bv1, acc[mt][1], 0, 0, 0);
    }
  }

  #pragma unroll
  for (int nt = 0; nt < 2; nt++) {
    int col = n0 + nt * 16 + r16;
    bool real = col < 500;
    float bias = real ? b[col] : 0.f;
    #pragma unroll
    for (int mt = 0; mt < 4; mt++) {
      #pragma unroll
      for (int j = 0; j < 4; j++) {
        int row = m0 + mt * 16 + 4 * g + j;
        float val = fmaxf(acc[mt][nt][j] + bias, 0.f);
        if (real) H[(size_t)row * 500 + col] = val;
        H16[(size_t)row * 512 + col] = f2h(val);
      }
    }
  }
}

// ---------------- K4: attn1 via fp16 MFMA + fused tanh/w2 reduction ----------------
__global__ __launch_bounds__(64) void k_attn1_mfma(const unsigned short* __restrict__ H16,
                                                   const unsigned short* __restrict__ Wt1,
                                                   const float* __restrict__ b1,   // [128]
                                                   const float* __restrict__ w2,   // [128]
                                                   const float* __restrict__ b2,   // [1]
                                                   float* __restrict__ a,
                                                   float* __restrict__ outA) {
  int lane = threadIdx.x;
  int r16 = lane & 15, g = lane >> 4;
  int m0 = blockIdx.x * 32;

  f32x4 acc[2][8];
  #pragma unroll
  for (int mt = 0; mt < 2; mt++)
    #pragma unroll
    for (int nt = 0; nt < 8; nt++) acc[mt][nt] = (f32x4){0.f, 0.f, 0.f, 0.f};

  const unsigned short* Abase = H16 + (size_t)(m0 + r16) * 512 + 8 * g;
  const unsigned short* Bbase = Wt1 + r16 * 32 + 8 * g;

  for (int kt = 0; kt < 16; kt++) {
    uint4 a0 = *(const uint4*)(Abase + kt * 32);
    uint4 a1 = *(const uint4*)(Abase + 16 * 512 + kt * 32);
    f16x8 av0 = __builtin_bit_cast(f16x8, a0);
    f16x8 av1 = __builtin_bit_cast(f16x8, a1);
    #pragma unroll
    for (int nt = 0; nt < 8; nt++) {
      uint4 bf = *(const uint4*)(Bbase + kt * 4096 + nt * 512);
      f16x8 bv = __builtin_bit_cast(f16x8, bf);
      acc[0][nt] = __builtin_amdgcn_mfma_f32_16x16x32_f16(av0, bv, acc[0][nt], 0, 0, 0);
      acc[1][nt] = __builtin_amdgcn_mfma_f32_16x16x32_f16(av1, bv, acc[1][nt], 0, 0, 0);
    }
  }

  float b1v[8], w2v[8];
  #pragma unroll
  for (int nt = 0; nt < 8; nt++) {
    int col = nt * 16 + r16;
    b1v[nt] = b1[col];
    w2v[nt] = w2[col];
  }
  float bb2 = b2[0];

  #pragma unroll
  for (int mt = 0; mt < 2; mt++) {
    float part[4];
    #pragma unroll
    for (int j = 0; j < 4; j++) {
      float s = 0.f;
      #pragma unroll
      for (int nt = 0; nt < 8; nt++)
        s += tanhf(acc[mt][nt][j] + b1v[nt]) * w2v[nt];
      part[j] = s;
    }
    #pragma unroll
    for (int off = 1; off < 16; off <<= 1) {
      #pragma unroll
      for (int j = 0; j < 4; j++) part[j] += __shfl_xor(part[j], off);
    }
    if (r16 == 0) {
      #pragma unroll
      for (int j = 0; j < 4; j++) {
        int row = m0 + mt * 16 + 4 * g + j;
        float val = part[j] + bb2;
        a[row] = val;
        outA[row] = val;
      }
    }
  }
}

// ---------------- K5: per-segment softmax pooling -> instance_f[S,500] ----------------
__global__ __launch_bounds__(256) void k_segpool(const float* __restrict__ a,
                                                 const float* __restrict__ H,
                                                 const int* __restrict__ idx,
                                                 float* __restrict__ instf) {
  __shared__ float red[4];
  __shared__ float sval;
  int s = blockIdx.x, tid = threadIdx.x;
  int i0 = idx[s], i1 = idx[s + 1];
  float mx = -INFINITY;
  for (int i = i0 + tid; i < i1; i += 256) mx = fmaxf(mx, a[i]);
  #pragma unroll
  for (int off = 32; off > 0; off >>= 1) mx = fmaxf(mx, __shfl_down(mx, off));
  if ((tid & 63) == 0) red[tid >> 6] = mx;
  __syncthreads();
  if (tid == 0) sval = fmaxf(fmaxf(red[0], red[1]), fmaxf(red[2], red[3]));
  __syncthreads();
  float m = sval;
  float sm = 0.f;
  for (int i = i0 + tid; i < i1; i += 256) sm += expf(a[i] - m);
  #pragma unroll
  for (int off = 32; off > 0; off >>= 1) sm += __shfl_down(sm, off);
  if ((tid & 63) == 0) red[tid >> 6] = sm;
  __syncthreads();
  if (tid == 0) sval = red[0] + red[1] + red[2] + red[3];
  __syncthreads();
  float inv = 1.f / sval;
  if (tid < 250) {
    float acc0 = 0.f, acc1 = 0.f;
    for (int i = i0; i < i1; i++) {
      float e = expf(a[i] - m) * inv;
      acc0 += e * H[(size_t)i * 500 + tid];
      acc1 += e * H[(size_t)i * 500 + tid + 250];
    }
    instf[s * 500 + tid] = acc0;
    instf[s * 500 + tid + 250] = acc1;
  }
}

// ---------------- K6: bag attention logits (split-K latency fix) ----------------
__global__ __launch_bounds__(512) void k_batt(const float* __restrict__ instf,
                                              const float* __restrict__ w1,
                                              const float* __restrict__ b1,
                                              const float* __restrict__ w2,
                                              const float* __restrict__ b2,
                                              float* __restrict__ batt) {
  __shared__ float fs[500];
  __shared__ float part[512];
  __shared__ float red[2];
  int s = blockIdx.x, tid = threadIdx.x;
  for (int i = tid; i < 500; i += 512) fs[i] = instf[s * 500 + i];
  __syncthreads();
  int c = tid & 127, q = tid >> 7;     // 4 K-chunks of 125
  float t = 0.f;
  int k0 = q * 125;
  #pragma unroll 5
  for (int k = k0; k < k0 + 125; k++) t += fs[k] * w1[k * 128 + c];
  part[tid] = t;
  __syncthreads();
  if (tid < 128) {
    float tt = part[tid] + part[tid + 128] + part[tid + 256] + part[tid + 384] + b1[tid];
    float v = tanhf(tt) * w2[tid];
    #pragma unroll
    for (int off = 32; off > 0; off >>= 1) v += __shfl_down(v, off);
    if ((tid & 63) == 0) red[tid >> 6] = v;
  }
  __syncthreads();
  if (tid == 0) batt[s] = red[0] + red[1] + b2[0];
}

// ---------------- K7: softmax(b_att) -> bag feature -> classifier ----------------
__global__ __launch_bounds__(256) void k_final(const float* __restrict__ batt,
                                               const float* __restrict__ instf,
                                               const float* __restrict__ clfw,
                                               const float* __restrict__ clfb,
                                               float* __restrict__ out) {
  __shared__ float Bsh[64];
  __shared__ float red[4];
  int tid = threadIdx.x;
  if (tid < 64) {
    float v = batt[tid];
    float mx = v;
    #pragma unroll
    for (int off = 32; off > 0; off >>= 1) mx = fmaxf(mx, __shfl_xor(mx, off));
    float e = expf(v - mx);
    float smv = e;
    #pragma unroll
    for (int off = 32; off > 0; off >>= 1) smv += __shfl_xor(smv, off);
    Bsh[tid] = e / smv;
  }
  __syncthreads();
  float part = 0.f;
  if (tid < 250) {
    float bag0 = 0.f, bag1 = 0.f;
    #pragma unroll 4
    for (int s2 = 0; s2 < 64; s2++) {
      float Bv = Bsh[s2];
      bag0 += Bv * instf[s2 * 500 + tid];
      bag1 += Bv * instf[s2 * 500 + tid + 250];
    }
    part = bag0 * clfw[tid] + bag1 * clfw[tid + 250];
  }
  #pragma unroll
  for (int off = 32; off > 0; off >>= 1) part += __shfl_down(part, off);
  if ((tid & 63) == 0) red[tid >> 6] = part;
  __syncthreads();
  if (tid == 0) {
    float z = red[0] + red[1] + red[2] + red[3] + clfb[0];
    out[0] = 1.f / (1.f + expf(-z));
    out[1] = (z >= 0.f) ? 1.f : 0.f;
  }
}

extern "C" void kernel_launch(void* const* d_in, const int* in_sizes, int n_in,
                              void* d_out, int out_size, void* d_ws, size_t ws_size,
                              hipStream_t stream) {
  const float* x       = (const float*)d_in[0];
  const int*   idx     = (const int*)d_in[1];
  const float* conv1_w = (const float*)d_in[2];
  const float* conv1_b = (const float*)d_in[3];
  const float* conv2_w = (const float*)d_in[4];
  const float* conv2_b = (const float*)d_in[5];
  const float* fc_w    = (const float*)d_in[6];
  const float* fc_b    = (const float*)d_in[7];
  const float* a1_w1   = (const float*)d_in[8];
  const float* a1_b1   = (const float*)d_in[9];
  const float* a1_w2   = (const float*)d_in[10];
  const float* a1_b2   = (const float*)d_in[11];
  const float* a2_w1   = (const float*)d_in[12];
  const float* a2_b1   = (const float*)d_in[13];
  const float* a2_w2   = (const float*)d_in[14];
  const float* a2_b2   = (const float*)d_in[15];
  const float* clf_w   = (const float*)d_in[16];
  const float* clf_b   = (const float*)d_in[17];
  float* out = (float*)d_out;

  int N = in_sizes[0] / 2352;     // 4096
  int S = in_sizes[1] - 1;        // 64

  // workspace layout
  float* wsf   = (float*)d_ws;
  float* H     = wsf;                          // N*500 f32
  float* a     = H + (size_t)N * 500;          // N
  float* instf = a + N;                        // S*500
  float* batt  = instf + (size_t)S * 500;      // S
  unsigned short* h1cl  = (unsigned short*)(batt + S + 8);   // N*3456 fp16
  unsigned short* Wg    = h1cl + (size_t)N * 3456;           // 38400
  unsigned short* Wc1g  = Wg + 38400;                        // 6400
  unsigned short* Wtfc  = Wc1g + 6400;                       // 409600
  unsigned short* Wt1   = Wtfc + 409600;                     // 65536
  unsigned short* flat16= Wt1 + 65536;                       // N*800 fp16
  unsigned short* H16   = flat16 + (size_t)N * 800;          // N*512 fp16

  k_prepw<<<150, 256, 0, stream>>>(conv2_w, Wg);
  k_prepw1<<<25, 256, 0, stream>>>(conv1_w, Wc1g);
  k_prepwfc<<<1600, 256, 0, stream>>>(fc_w, Wtfc);
  k_prepwa1<<<256, 256, 0, stream>>>(a1_w1, Wt1);
  k_conv1_mfma<<<N / 4, 256, 0, stream>>>(x, Wc1g, conv1_b, h1cl);
  k_conv2_mfma<<<N / 8, 256, 0, stream>>>(h1cl, Wg, conv2_b, flat16);
  k_fc_mfma<<<256, 256, 0, stream>>>(flat16, Wtfc, fc_b, H, H16);
  k_attn1_mfma<<<N / 32, 64, 0, stream>>>(H16, Wt1, a1_b1, a1_w2, a1_b2, a, out + 2);
  k_segpool<<<S, 256, 0, stream>>>(a, H, idx, instf);
  k_batt<<<S, 512, 0, stream>>>(instf, a2_w1, a2_b1, a2_w2, a2_b2, batt);
  k_final<<<1, 256, 0, stream>>>(batt, instf, clf_w, clf_b, out);
}

// Round 9
// 157.807 us; speedup vs baseline: 3.6576x; 1.0136x over previous
//
#include <hip/hip_runtime.h>
#include <math.h>

typedef _Float16 f16x8 __attribute__((ext_vector_type(8)));
typedef float    f32x4 __attribute__((ext_vector_type(4)));

static __device__ __forceinline__ unsigned short f2h(float f) {
  _Float16 h = (_Float16)f;                       // RNE
  return __builtin_bit_cast(unsigned short, h);
}

// ---------------- K0: merged one-time weight prep ----------------
// [0,6400)      : conv1 -> Wc1g [5][32][40]  (co pad 32, kw pad 8, ci pad 4)
// [6400,44800)  : conv2 -> Wg   [25][64][24] (co pad 64, ci pad 24)
// [44800,454400): fc    -> Wtfc [25][512][32]
// [454400,519936): attn1 -> Wt1 [16][128][32]
__global__ __launch_bounds__(256) void k_prep_all(const float* __restrict__ c1w,
                                                  const float* __restrict__ c2w,
                                                  const float* __restrict__ fcw,
                                                  const float* __restrict__ a1w1,
                                                  unsigned short* __restrict__ Wc1g,
                                                  unsigned short* __restrict__ Wg,
                                                  unsigned short* __restrict__ Wtfc,
                                                  unsigned short* __restrict__ Wt1) {
  int i = blockIdx.x * 256 + threadIdx.x;
  if (i < 6400) {
    int kh = i / 1280, r = i % 1280;
    int co = r / 40, q = r % 40;
    int kw = q >> 2, ci = q & 3;
    Wc1g[i] = f2h((co < 20 && ci < 3 && kw < 5) ? c1w[((co * 3 + ci) * 5 + kh) * 5 + kw] : 0.f);
    return;
  }
  i -= 6400;
  if (i < 38400) {
    int tap = i / 1536, r = i % 1536;
    int co = r / 24, ci = r % 24;
    Wg[i] = f2h((co < 50 && ci < 20) ? c2w[(co * 20 + ci) * 25 + tap] : 0.f);
    return;
  }
  i -= 38400;
  if (i < 409600) {
    int kt = i >> 14, r = i & 16383;
    int nn = r >> 5, kk = r & 31;
    int k = kt * 32 + kk;
    Wtfc[i] = f2h((nn < 500) ? fcw[k * 500 + nn] : 0.f);
    return;
  }
  i -= 409600;
  if (i < 65536) {
    int kt = i >> 12, r = i & 4095;
    int col = r >> 5, kk = r & 31;
    int k = kt * 32 + kk;
    Wt1[i] = f2h((k < 500) ? a1w1[k * 128 + col] : 0.f);
  }
}

// ---------------- K1: FUSED conv1+pool -> conv2+pool (all fp16 MFMA) ----------------
// 4 images/block, 1 image/wave. conv1 output stays in LDS; flat16 [n][50][4][4] out.
__global__ __launch_bounds__(256, 2) void k_conv12(const float* __restrict__ x,
                                                   const unsigned short* __restrict__ Wc1g,
                                                   const float* __restrict__ cb1,   // conv1_b [20]
                                                   const unsigned short* __restrict__ Wg,
                                                   const float* __restrict__ cb2,   // conv2_b [50]
                                                   unsigned short* __restrict__ flat16) {
  __shared__ unsigned short xcl[4 * 3200];        // 25600 B  [img][800px][4ci]
  __shared__ unsigned short h1s[4 * 3456 + 16];   // 27680 B  [img][144px][24co] (+pad)
  __shared__ unsigned short Wc1[6400];            // 12800 B
  __shared__ float bs[32];
  int tid = threadIdx.x;
  int n0 = blockIdx.x * 4;

  // stage conv1 weights
  {
    const uint4* src = (const uint4*)Wc1g;
    uint4* dst = (uint4*)Wc1;
    for (int i = tid; i < 800; i += 256) dst[i] = src[i];
  }
  if (tid < 32) bs[tid] = (tid < 20) ? cb1[tid] : 0.f;
  // CRITICAL: zero the h1s pad — wave 3's conv2 g=3 junk A-read (pixel 143, tap 24)
  // lands here; uninit NaN would poison the MFMA row and get laundered by fmaxf.
  if (tid < 16) h1s[4 * 3456 + tid] = 0;
  // zero tail pixels 784..799 per image (conv1 kw-pad reads land there)
  {
    int n = tid >> 6, t = tid & 63;
    xcl[n * 3200 + 3136 + t] = 0;
  }
  // stage x -> channel-last fp16, one pixel per thread, packed b64 writes
  #pragma unroll
  for (int img = 0; img < 4; img++) {
    const float* xg = x + (size_t)(n0 + img) * 2352;
    unsigned short* xc = xcl + img * 3200;
    #pragma unroll
    for (int p0 = 0; p0 < 784; p0 += 256) {
      int p = p0 + tid;
      if (p < 784) {
        unsigned int lo = (unsigned int)f2h(xg[p]) | ((unsigned int)f2h(xg[784 + p]) << 16);
        unsigned int hi = (unsigned int)f2h(xg[1568 + p]);   // ci3 = 0
        uint2 v; v.x = lo; v.y = hi;
        *(uint2*)(xc + 4 * p) = v;
      }
    }
  }
  __syncthreads();

  int wave = tid >> 6, lane = tid & 63;
  int r16 = lane & 15, g = lane >> 4;

  // ================= conv1 (per-wave image) =================
  {
    const unsigned short* xb = xcl + wave * 3200;
    unsigned short* oimg = h1s + wave * 3456;

    // hoist all 10 B-fragments (5 kh x 2 n-tiles)
    f16x8 bv[5][2];
    #pragma unroll
    for (int kh = 0; kh < 5; kh++) {
      bv[kh][0] = __builtin_bit_cast(f16x8, *(const uint4*)(Wc1 + (kh * 32 + r16) * 40 + 8 * g));
      bv[kh][1] = __builtin_bit_cast(f16x8, *(const uint4*)(Wc1 + (kh * 32 + 16 + r16) * 40 + 8 * g));
    }
    int ay = (r16 >> 3), ax = (r16 & 7) + 2 * g;

    for (int chunk = 0; chunk < 9; ++chunk) {
      f32x4 acc[4][2];
      #pragma unroll
      for (int ti = 0; ti < 4; ti++) {
        acc[ti][0] = (f32x4){0.f, 0.f, 0.f, 0.f};
        acc[ti][1] = (f32x4){0.f, 0.f, 0.f, 0.f};
      }
      #pragma unroll
      for (int kh = 0; kh < 5; kh++) {
        #pragma unroll
        for (int ti = 0; ti < 4; ti++) {
          int t = chunk * 4 + ti;
          int ty = t / 3, tx = t - ty * 3;
          int oy = 2 * ty + ay + kh;
          int ox = 8 * tx + ax;
          const unsigned short* p = xb + (oy * 28 + ox) * 4;
          uint2 lo = *(const uint2*)p;
          uint2 hi = *(const uint2*)(p + 4);
          uint4 af; af.x = lo.x; af.y = lo.y; af.z = hi.x; af.w = hi.y;
          f16x8 av = __builtin_bit_cast(f16x8, af);
          acc[ti][0] = __builtin_amdgcn_mfma_f32_16x16x32_f16(av, bv[kh][0], acc[ti][0], 0, 0, 0);
          acc[ti][1] = __builtin_amdgcn_mfma_f32_16x16x32_f16(av, bv[kh][1], acc[ti][1], 0, 0, 0);
        }
      }
      // epilogue: 2x2 maxpool + bias + relu -> LDS h1s (channel-last)
      #pragma unroll
      for (int ti = 0; ti < 4; ti++) {
        int t = chunk * 4 + ti;
        int ty = t / 3, tx = t - ty * 3;
        #pragma unroll
        for (int nt = 0; nt < 2; nt++) {
          int co = 16 * nt + r16;
          f32x4 c = acc[ti][nt];
          float h0 = fmaxf(c[0], c[1]);
          float h1 = fmaxf(c[2], c[3]);
          float v0 = fmaxf(h0, __shfl_xor(h0, 32));
          float v1 = fmaxf(h1, __shfl_xor(h1, 32));
          if (g < 2 && co < 24) {
            float bias = bs[co];
            v0 = fmaxf(v0 + bias, 0.f);
            v1 = fmaxf(v1 + bias, 0.f);
            int px0 = 4 * tx + 2 * g;
            unsigned short* o = oimg + ((ty * 12 + px0) * 24 + co);
            o[0]  = f2h(v0);
            o[24] = f2h(v1);
          }
        }
      }
    }
  }
  __syncthreads();

  // ================= conv2 (per-wave image, from LDS h1s) =================
  {
    const unsigned short* hb = h1s + wave * 3456;
    f32x4 acc[4][4];
    #pragma unroll
    for (int mt = 0; mt < 4; mt++)
      #pragma unroll
      for (int nt = 0; nt < 4; nt++) acc[mt][nt] = (f32x4){0.f, 0.f, 0.f, 0.f};

    uint4 FAa[4], FAb[4], FBa[4], FBb[4];
    auto load_frags = [&](uint4* A, uint4* B, int tap) {
      int kh = tap / 5, kw = tap % 5;
      #pragma unroll
      for (int nt = 0; nt < 4; nt++) {
        uint4 u = make_uint4(0, 0, 0, 0);
        if (g < 3) {
          int co = 16 * nt + r16;
          u = *(const uint4*)(Wg + tap * 1536 + co * 24 + 8 * g);
        }
        B[nt] = u;
      }
      #pragma unroll
      for (int mt = 0; mt < 4; mt++) {
        int posl = mt * 16 + r16;
        int oy = posl >> 3, ox = posl & 7;
        A[mt] = *(const uint4*)(hb + ((oy + kh) * 12 + (ox + kw)) * 24 + 8 * g);
      }
    };
    auto mma = [&](const uint4* A, const uint4* B) {
      #pragma unroll
      for (int mt = 0; mt < 4; mt++) {
        f16x8 av = __builtin_bit_cast(f16x8, A[mt]);
        #pragma unroll
        for (int nt = 0; nt < 4; nt++) {
          acc[mt][nt] = __builtin_amdgcn_mfma_f32_16x16x32_f16(
              av, __builtin_bit_cast(f16x8, B[nt]), acc[mt][nt], 0, 0, 0);
        }
      }
    };

    load_frags(FAa, FAb, 0);
    for (int tap = 0; tap < 25; tap += 2) {
      if (tap + 1 < 25) load_frags(FBa, FBb, tap + 1);
      mma(FAa, FAb);
      if (tap + 2 < 25) load_frags(FAa, FAb, tap + 2);
      if (tap + 1 < 25) mma(FBa, FBb);
    }

    int n = n0 + wave;
    #pragma unroll
    for (int mt = 0; mt < 4; mt++) {
      #pragma unroll
      for (int nt = 0; nt < 4; nt++) {
        int co = 16 * nt + r16;
        f32x4 c = acc[mt][nt];
        float h0 = fmaxf(c[0], c[1]);
        float h1 = fmaxf(c[2], c[3]);
        float v0 = fmaxf(h0, __shfl_xor(h0, 32));
        float v1 = fmaxf(h1, __shfl_xor(h1, 32));
        if (g < 2 && co < 50) {
          float bias = cb2[co];
          v0 = fmaxf(v0 + bias, 0.f);
          v1 = fmaxf(v1 + bias, 0.f);
          unsigned short* o = flat16 + ((size_t)n * 50 + co) * 16 + mt * 4 + 2 * g;
          o[0] = f2h(v0);
          o[1] = f2h(v1);
        }
      }
    }
  }
}

// ---------------- K3: FC 800->500 via fp16 MFMA ----------------
__global__ __launch_bounds__(256) void k_fc_mfma(const unsigned short* __restrict__ flat16,
                                                 const unsigned short* __restrict__ Wt,
                                                 const float* __restrict__ b,
                                                 float* __restrict__ H,
                                                 unsigned short* __restrict__ H16) {
  int tid = threadIdx.x;
  int wave = tid >> 6, lane = tid & 63;
  int r16 = lane & 15, g = lane >> 4;
  int bm = blockIdx.x & 15, bn = blockIdx.x >> 4;
  int m0 = bm * 256 + wave * 64;
  int n0 = bn * 32;

  f32x4 acc[4][2];
  #pragma unroll
  for (int mt = 0; mt < 4; mt++) {
    acc[mt][0] = (f32x4){0.f, 0.f, 0.f, 0.f};
    acc[mt][1] = (f32x4){0.f, 0.f, 0.f, 0.f};
  }

  const unsigned short* Abase = flat16 + (size_t)(m0 + r16) * 800 + 8 * g;
  const unsigned short* Bbase = Wt + (size_t)(n0 + r16) * 32 + 8 * g;

  for (int kt = 0; kt < 25; kt++) {
    uint4 bf0 = *(const uint4*)(Bbase + kt * 16384);
    uint4 bf1 = *(const uint4*)(Bbase + kt * 16384 + 512);
    f16x8 bv0 = __builtin_bit_cast(f16x8, bf0);
    f16x8 bv1 = __builtin_bit_cast(f16x8, bf1);
    #pragma unroll
    for (int mt = 0; mt < 4; mt++) {
      uint4 af = *(const uint4*)(Abase + mt * 12800 + kt * 32);
      f16x8 av = __builtin_bit_cast(f16x8, af);
      acc[mt][0] = __builtin_amdgcn_mfma_f32_16x16x32_f16(av, bv0, acc[mt][0], 0, 0, 0);
      acc[mt][1] = __builtin_amdgcn_mfma_f32_16x16x32_f16(av, bv1, acc[mt][1], 0, 0, 0);
    }
  }

  #pragma unroll
  for (int nt = 0; nt < 2; nt++) {
    int col = n0 + nt * 16 + r16;
    bool real = col < 500;
    float bias = real ? b[col] : 0.f;
    #pragma unroll
    for (int mt = 0; mt < 4; mt++) {
      #pragma unroll
      for (int j = 0; j < 4; j++) {
        int row = m0 + mt * 16 + 4 * g + j;
        float val = fmaxf(acc[mt][nt][j] + bias, 0.f);
        if (real) H[(size_t)row * 500 + col] = val;
        H16[(size_t)row * 512 + col] = f2h(val);
      }
    }
  }
}

// ---------------- K4: attn1 via fp16 MFMA + fused tanh/w2 reduction ----------------
__global__ __launch_bounds__(64) void k_attn1_mfma(const unsigned short* __restrict__ H16,
                                                   const unsigned short* __restrict__ Wt1,
                                                   const float* __restrict__ b1,   // [128]
                                                   const float* __restrict__ w2,   // [128]
                                                   const float* __restrict__ b2,   // [1]
                                                   float* __restrict__ a,
                                                   float* __restrict__ outA) {
  int lane = threadIdx.x;
  int r16 = lane & 15, g = lane >> 4;
  int m0 = blockIdx.x * 32;

  f32x4 acc[2][8];
  #pragma unroll
  for (int mt = 0; mt < 2; mt++)
    #pragma unroll
    for (int nt = 0; nt < 8; nt++) acc[mt][nt] = (f32x4){0.f, 0.f, 0.f, 0.f};

  const unsigned short* Abase = H16 + (size_t)(m0 + r16) * 512 + 8 * g;
  const unsigned short* Bbase = Wt1 + r16 * 32 + 8 * g;

  for (int kt = 0; kt < 16; kt++) {
    uint4 a0 = *(const uint4*)(Abase + kt * 32);
    uint4 a1 = *(const uint4*)(Abase + 16 * 512 + kt * 32);
    f16x8 av0 = __builtin_bit_cast(f16x8, a0);
    f16x8 av1 = __builtin_bit_cast(f16x8, a1);
    #pragma unroll
    for (int nt = 0; nt < 8; nt++) {
      uint4 bf = *(const uint4*)(Bbase + kt * 4096 + nt * 512);
      f16x8 bv = __builtin_bit_cast(f16x8, bf);
      acc[0][nt] = __builtin_amdgcn_mfma_f32_16x16x32_f16(av0, bv, acc[0][nt], 0, 0, 0);
      acc[1][nt] = __builtin_amdgcn_mfma_f32_16x16x32_f16(av1, bv, acc[1][nt], 0, 0, 0);
    }
  }

  float b1v[8], w2v[8];
  #pragma unroll
  for (int nt = 0; nt < 8; nt++) {
    int col = nt * 16 + r16;
    b1v[nt] = b1[col];
    w2v[nt] = w2[col];
  }
  float bb2 = b2[0];

  #pragma unroll
  for (int mt = 0; mt < 2; mt++) {
    float part[4];
    #pragma unroll
    for (int j = 0; j < 4; j++) {
      float s = 0.f;
      #pragma unroll
      for (int nt = 0; nt < 8; nt++)
        s += tanhf(acc[mt][nt][j] + b1v[nt]) * w2v[nt];
      part[j] = s;
    }
    #pragma unroll
    for (int off = 1; off < 16; off <<= 1) {
      #pragma unroll
      for (int j = 0; j < 4; j++) part[j] += __shfl_xor(part[j], off);
    }
    if (r16 == 0) {
      #pragma unroll
      for (int j = 0; j < 4; j++) {
        int row = m0 + mt * 16 + 4 * g + j;
        float val = part[j] + bb2;
        a[row] = val;
        outA[row] = val;
      }
    }
  }
}

// ---------------- K5: per-segment softmax pooling -> instance_f[S,500] ----------------
__global__ __launch_bounds__(256) void k_segpool(const float* __restrict__ a,
                                                 const float* __restrict__ H,
                                                 const int* __restrict__ idx,
                                                 float* __restrict__ instf) {
  __shared__ float red[4];
  __shared__ float sval;
  int s = blockIdx.x, tid = threadIdx.x;
  int i0 = idx[s], i1 = idx[s + 1];
  float mx = -INFINITY;
  for (int i = i0 + tid; i < i1; i += 256) mx = fmaxf(mx, a[i]);
  #pragma unroll
  for (int off = 32; off > 0; off >>= 1) mx = fmaxf(mx, __shfl_down(mx, off));
  if ((tid & 63) == 0) red[tid >> 6] = mx;
  __syncthreads();
  if (tid == 0) sval = fmaxf(fmaxf(red[0], red[1]), fmaxf(red[2], red[3]));
  __syncthreads();
  float m = sval;
  float sm = 0.f;
  for (int i = i0 + tid; i < i1; i += 256) sm += expf(a[i] - m);
  #pragma unroll
  for (int off = 32; off > 0; off >>= 1) sm += __shfl_down(sm, off);
  if ((tid & 63) == 0) red[tid >> 6] = sm;
  __syncthreads();
  if (tid == 0) sval = red[0] + red[1] + red[2] + red[3];
  __syncthreads();
  float inv = 1.f / sval;
  if (tid < 250) {
    float acc0 = 0.f, acc1 = 0.f;
    for (int i = i0; i < i1; i++) {
      float e = expf(a[i] - m) * inv;
      acc0 += e * H[(size_t)i * 500 + tid];
      acc1 += e * H[(size_t)i * 500 + tid + 250];
    }
    instf[s * 500 + tid] = acc0;
    instf[s * 500 + tid + 250] = acc1;
  }
}

// ---------------- K6: bag attention logits (split-K) ----------------
__global__ __launch_bounds__(512) void k_batt(const float* __restrict__ instf,
                                              const float* __restrict__ w1,
                                              const float* __restrict__ b1,
                                              const float* __restrict__ w2,
                                              const float* __restrict__ b2,
                                              float* __restrict__ batt) {
  __shared__ float fs[500];
  __shared__ float part[512];
  __shared__ float red[2];
  int s = blockIdx.x, tid = threadIdx.x;
  for (int i = tid; i < 500; i += 512) fs[i] = instf[s * 500 + i];
  __syncthreads();
  int c = tid & 127, q = tid >> 7;     // 4 K-chunks of 125
  float t = 0.f;
  int k0 = q * 125;
  #pragma unroll 5
  for (int k = k0; k < k0 + 125; k++) t += fs[k] * w1[k * 128 + c];
  part[tid] = t;
  __syncthreads();
  if (tid < 128) {
    float tt = part[tid] + part[tid + 128] + part[tid + 256] + part[tid + 384] + b1[tid];
    float v = tanhf(tt) * w2[tid];
    #pragma unroll
    for (int off = 32; off > 0; off >>= 1) v += __shfl_down(v, off);
    if ((tid & 63) == 0) red[tid >> 6] = v;
  }
  __syncthreads();
  if (tid == 0) batt[s] = red[0] + red[1] + b2[0];
}

// ---------------- K7: softmax(b_att) -> bag feature -> classifier ----------------
__global__ __launch_bounds__(256) void k_final(const float* __restrict__ batt,
                                               const float* __restrict__ instf,
                                               const float* __restrict__ clfw,
                                               const float* __restrict__ clfb,
                                               float* __restrict__ out) {
  __shared__ float Bsh[64];
  __shared__ float red[4];
  int tid = threadIdx.x;
  if (tid < 64) {
    float v = batt[tid];
    float mx = v;
    #pragma unroll
    for (int off = 32; off > 0; off >>= 1) mx = fmaxf(mx, __shfl_xor(mx, off));
    float e = expf(v - mx);
    float smv = e;
    #pragma unroll
    for (int off = 32; off > 0; off >>= 1) smv += __shfl_xor(smv, off);
    Bsh[tid] = e / smv;
  }
  __syncthreads();
  float part = 0.f;
  if (tid < 250) {
    float bag0 = 0.f, bag1 = 0.f;
    #pragma unroll 4
    for (int s2 = 0; s2 < 64; s2++) {
      float Bv = Bsh[s2];
      bag0 += Bv * instf[s2 * 500 + tid];
      bag1 += Bv * instf[s2 * 500 + tid + 250];
    }
    part = bag0 * clfw[tid] + bag1 * clfw[tid + 250];
  }
  #pragma unroll
  for (int off = 32; off > 0; off >>= 1) part += __shfl_down(part, off);
  if ((tid & 63) == 0) red[tid >> 6] = part;
  __syncthreads();
  if (tid == 0) {
    float z = red[0] + red[1] + red[2] + red[3] + clfb[0];
    out[0] = 1.f / (1.f + expf(-z));
    out[1] = (z >= 0.f) ? 1.f : 0.f;
  }
}

extern "C" void kernel_launch(void* const* d_in, const int* in_sizes, int n_in,
                              void* d_out, int out_size, void* d_ws, size_t ws_size,
                              hipStream_t stream) {
  const float* x       = (const float*)d_in[0];
  const int*   idx     = (const int*)d_in[1];
  const float* conv1_w = (const float*)d_in[2];
  const float* conv1_b = (const float*)d_in[3];
  const float* conv2_w = (const float*)d_in[4];
  const float* conv2_b = (const float*)d_in[5];
  const float* fc_w    = (const float*)d_in[6];
  const float* fc_b    = (const float*)d_in[7];
  const float* a1_w1   = (const float*)d_in[8];
  const float* a1_b1   = (const float*)d_in[9];
  const float* a1_w2   = (const float*)d_in[10];
  const float* a1_b2   = (const float*)d_in[11];
  const float* a2_w1   = (const float*)d_in[12];
  const float* a2_b1   = (const float*)d_in[13];
  const float* a2_w2   = (const float*)d_in[14];
  const float* a2_b2   = (const float*)d_in[15];
  const float* clf_w   = (const float*)d_in[16];
  const float* clf_b   = (const float*)d_in[17];
  float* out = (float*)d_out;

  int N = in_sizes[0] / 2352;     // 4096
  int S = in_sizes[1] - 1;        // 64

  // workspace layout
  float* wsf   = (float*)d_ws;
  float* H     = wsf;                          // N*500 f32
  float* a     = H + (size_t)N * 500;          // N
  float* instf = a + N;                        // S*500
  float* batt  = instf + (size_t)S * 500;     // S
  unsigned short* Wg    = (unsigned short*)(batt + S + 8);   // 38400
  unsigned short* Wc1g  = Wg + 38400;                        // 6400
  unsigned short* Wtfc  = Wc1g + 6400;                       // 409600
  unsigned short* Wt1   = Wtfc + 409600;                     // 65536
  unsigned short* flat16= Wt1 + 65536;                       // N*800 fp16
  unsigned short* H16   = flat16 + (size_t)N * 800;          // N*512 fp16

  k_prep_all<<<2031, 256, 0, stream>>>(conv1_w, conv2_w, fc_w, a1_w1, Wc1g, Wg, Wtfc, Wt1);
  k_conv12<<<N / 4, 256, 0, stream>>>(x, Wc1g, conv1_b, Wg, conv2_b, flat16);
  k_fc_mfma<<<256, 256, 0, stream>>>(flat16, Wtfc, fc_b, H, H16);
  k_attn1_mfma<<<N / 32, 64, 0, stream>>>(H16, Wt1, a1_b1, a1_w2, a1_b2, a, out + 2);
  k_segpool<<<S, 256, 0, stream>>>(a, H, idx, instf);
  k_batt<<<S, 512, 0, stream>>>(instf, a2_w1, a2_b1, a2_w2, a2_b2, batt);
  k_final<<<1, 256, 0, stream>>>(batt, instf, clf_w, clf_b, out);
}

// Round 10
// 153.762 us; speedup vs baseline: 3.7538x; 1.0263x over previous
//
#include <hip/hip_runtime.h>
#include <math.h>

typedef _Float16 f16x8 __attribute__((ext_vector_type(8)));
typedef float    f32x4 __attribute__((ext_vector_type(4)));

static __device__ __forceinline__ unsigned short f2h(float f) {
  _Float16 h = (_Float16)f;                       // RNE
  return __builtin_bit_cast(unsigned short, h);
}

// ---------------- K0: merged one-time weight prep ----------------
// [0,6400)      : conv1 -> Wc1g [5][32][40]  (co pad 32, kw pad 8, ci pad 4)
// [6400,44800)  : conv2 -> Wg   [25][64][24] (co pad 64, ci pad 24)
// [44800,454400): fc    -> Wtfc [25][512][32]
// [454400,519936): attn1 -> Wt1 [16][128][32]
__global__ __launch_bounds__(256) void k_prep_all(const float* __restrict__ c1w,
                                                  const float* __restrict__ c2w,
                                                  const float* __restrict__ fcw,
                                                  const float* __restrict__ a1w1,
                                                  unsigned short* __restrict__ Wc1g,
                                                  unsigned short* __restrict__ Wg,
                                                  unsigned short* __restrict__ Wtfc,
                                                  unsigned short* __restrict__ Wt1) {
  int i = blockIdx.x * 256 + threadIdx.x;
  if (i < 6400) {
    int kh = i / 1280, r = i % 1280;
    int co = r / 40, q = r % 40;
    int kw = q >> 2, ci = q & 3;
    Wc1g[i] = f2h((co < 20 && ci < 3 && kw < 5) ? c1w[((co * 3 + ci) * 5 + kh) * 5 + kw] : 0.f);
    return;
  }
  i -= 6400;
  if (i < 38400) {
    int tap = i / 1536, r = i % 1536;
    int co = r / 24, ci = r % 24;
    Wg[i] = f2h((co < 50 && ci < 20) ? c2w[(co * 20 + ci) * 25 + tap] : 0.f);
    return;
  }
  i -= 38400;
  if (i < 409600) {
    int kt = i >> 14, r = i & 16383;
    int nn = r >> 5, kk = r & 31;
    int k = kt * 32 + kk;
    Wtfc[i] = f2h((nn < 500) ? fcw[k * 500 + nn] : 0.f);
    return;
  }
  i -= 409600;
  if (i < 65536) {
    int kt = i >> 12, r = i & 4095;
    int col = r >> 5, kk = r & 31;
    int k = kt * 32 + kk;
    Wt1[i] = f2h((k < 500) ? a1w1[k * 128 + col] : 0.f);
  }
}

// ---------------- K1: FUSED conv1+pool -> conv2+pool, 64 threads / 1 image ----------------
// LDS 13.3 KB/block -> ~12 blocks/CU; single-wave barriers; conv1+conv2 B-frags from L2.
__global__ __launch_bounds__(64, 2) void k_conv12(const float* __restrict__ x,
                                                  const unsigned short* __restrict__ Wc1g,
                                                  const float* __restrict__ cb1,   // conv1_b [20]
                                                  const unsigned short* __restrict__ Wg,
                                                  const float* __restrict__ cb2,   // conv2_b [50]
                                                  unsigned short* __restrict__ flat16) {
  __shared__ unsigned short xcl[3200];       // [800px][4ci] fp16 (tail 784..799 zero)
  __shared__ unsigned short h1s[3472];       // [144px][24co] + 16-short zero pad
  int tid = threadIdx.x;                     // == lane
  int n = blockIdx.x;
  int r16 = tid & 15, g = tid >> 4;

  // zero h1s pad: wave's conv2 g=3 junk A-read (pixel 143, tap 24) lands at 3456..3463.
  if (tid < 16) h1s[3456 + tid] = 0;
  // zero xcl tail (conv1 kw-pad junk reads land there)
  xcl[3136 + tid] = 0;
  // stage x -> channel-last fp16 (3 coalesced f32 streams, packed b64 writes)
  {
    const float* xg = x + (size_t)n * 2352;
    for (int p = tid; p < 784; p += 64) {
      unsigned int lo = (unsigned int)f2h(xg[p]) | ((unsigned int)f2h(xg[784 + p]) << 16);
      unsigned int hi = (unsigned int)f2h(xg[1568 + p]);   // ci3 = 0
      uint2 v; v.x = lo; v.y = hi;
      *(uint2*)(xcl + 4 * p) = v;
    }
  }
  __syncthreads();   // single wave: cheap

  // ================= conv1 =================
  {
    // B-fragments direct from L2-resident Wc1g (16B-aligned: 80B co-stride)
    f16x8 bv[5][2];
    #pragma unroll
    for (int kh = 0; kh < 5; kh++) {
      bv[kh][0] = __builtin_bit_cast(f16x8, *(const uint4*)(Wc1g + (kh * 32 + r16) * 40 + 8 * g));
      bv[kh][1] = __builtin_bit_cast(f16x8, *(const uint4*)(Wc1g + (kh * 32 + 16 + r16) * 40 + 8 * g));
    }
    float bias0 = cb1[r16];                               // co = r16 (<16)
    float bias1 = (r16 < 4) ? cb1[16 + r16] : 0.f;        // co = 16+r16 (<20), else 0
    int ay = (r16 >> 3), ax = (r16 & 7) + 2 * g;

    for (int chunk = 0; chunk < 9; ++chunk) {
      f32x4 acc[4][2];
      #pragma unroll
      for (int ti = 0; ti < 4; ti++) {
        acc[ti][0] = (f32x4){0.f, 0.f, 0.f, 0.f};
        acc[ti][1] = (f32x4){0.f, 0.f, 0.f, 0.f};
      }
      #pragma unroll
      for (int kh = 0; kh < 5; kh++) {
        #pragma unroll
        for (int ti = 0; ti < 4; ti++) {
          int t = chunk * 4 + ti;
          int ty = t / 3, tx = t - ty * 3;
          int oy = 2 * ty + ay + kh;
          int ox = 8 * tx + ax;
          const unsigned short* p = xcl + (oy * 28 + ox) * 4;
          uint2 lo = *(const uint2*)p;
          uint2 hi = *(const uint2*)(p + 4);
          uint4 af; af.x = lo.x; af.y = lo.y; af.z = hi.x; af.w = hi.y;
          f16x8 av = __builtin_bit_cast(f16x8, af);
          acc[ti][0] = __builtin_amdgcn_mfma_f32_16x16x32_f16(av, bv[kh][0], acc[ti][0], 0, 0, 0);
          acc[ti][1] = __builtin_amdgcn_mfma_f32_16x16x32_f16(av, bv[kh][1], acc[ti][1], 0, 0, 0);
        }
      }
      // epilogue: 2x2 maxpool + bias + relu -> LDS h1s (channel-last, stride 24)
      #pragma unroll
      for (int ti = 0; ti < 4; ti++) {
        int t = chunk * 4 + ti;
        int ty = t / 3, tx = t - ty * 3;
        #pragma unroll
        for (int nt = 0; nt < 2; nt++) {
          int co = 16 * nt + r16;
          f32x4 c = acc[ti][nt];
          float h0 = fmaxf(c[0], c[1]);
          float h1 = fmaxf(c[2], c[3]);
          float v0 = fmaxf(h0, __shfl_xor(h0, 32));
          float v1 = fmaxf(h1, __shfl_xor(h1, 32));
          if (g < 2 && co < 24) {
            float bias = nt ? bias1 : bias0;              // co 20..23: acc=0,bias=0 -> 0
            v0 = fmaxf(v0 + bias, 0.f);
            v1 = fmaxf(v1 + bias, 0.f);
            int px0 = 4 * tx + 2 * g;
            unsigned short* o = h1s + (ty * 12 + px0) * 24 + co;
            o[0]  = f2h(v0);
            o[24] = f2h(v1);
          }
        }
      }
    }
  }
  __syncthreads();

  // ================= conv2 (from LDS h1s) =================
  {
    float cbias0 = cb2[r16];
    float cbias1 = cb2[16 + r16];
    float cbias2 = cb2[32 + r16];
    float cbias3 = (r16 < 2) ? cb2[48 + r16] : 0.f;

    f32x4 acc[4][4];
    #pragma unroll
    for (int mt = 0; mt < 4; mt++)
      #pragma unroll
      for (int nt = 0; nt < 4; nt++) acc[mt][nt] = (f32x4){0.f, 0.f, 0.f, 0.f};

    uint4 FAa[4], FAb[4], FBa[4], FBb[4];
    auto load_frags = [&](uint4* A, uint4* B, int tap) {
      int kh = tap / 5, kw = tap % 5;
      #pragma unroll
      for (int nt = 0; nt < 4; nt++) {
        uint4 u = make_uint4(0, 0, 0, 0);
        if (g < 3) {
          int co = 16 * nt + r16;
          u = *(const uint4*)(Wg + tap * 1536 + co * 24 + 8 * g);
        }
        B[nt] = u;
      }
      #pragma unroll
      for (int mt = 0; mt < 4; mt++) {
        int posl = mt * 16 + r16;
        int oy = posl >> 3, ox = posl & 7;
        A[mt] = *(const uint4*)(h1s + ((oy + kh) * 12 + (ox + kw)) * 24 + 8 * g);
      }
    };
    auto mma = [&](const uint4* A, const uint4* B) {
      #pragma unroll
      for (int mt = 0; mt < 4; mt++) {
        f16x8 av = __builtin_bit_cast(f16x8, A[mt]);
        #pragma unroll
        for (int nt = 0; nt < 4; nt++) {
          acc[mt][nt] = __builtin_amdgcn_mfma_f32_16x16x32_f16(
              av, __builtin_bit_cast(f16x8, B[nt]), acc[mt][nt], 0, 0, 0);
        }
      }
    };

    load_frags(FAa, FAb, 0);
    for (int tap = 0; tap < 25; tap += 2) {
      if (tap + 1 < 25) load_frags(FBa, FBb, tap + 1);
      mma(FAa, FAb);
      if (tap + 2 < 25) load_frags(FAa, FAb, tap + 2);
      if (tap + 1 < 25) mma(FBa, FBb);
    }

    #pragma unroll
    for (int mt = 0; mt < 4; mt++) {
      #pragma unroll
      for (int nt = 0; nt < 4; nt++) {
        int co = 16 * nt + r16;
        f32x4 c = acc[mt][nt];
        float h0 = fmaxf(c[0], c[1]);
        float h1 = fmaxf(c[2], c[3]);
        float v0 = fmaxf(h0, __shfl_xor(h0, 32));
        float v1 = fmaxf(h1, __shfl_xor(h1, 32));
        if (g < 2 && co < 50) {
          float bias = (nt == 0) ? cbias0 : (nt == 1) ? cbias1 : (nt == 2) ? cbias2 : cbias3;
          v0 = fmaxf(v0 + bias, 0.f);
          v1 = fmaxf(v1 + bias, 0.f);
          unsigned short* o = flat16 + ((size_t)n * 50 + co) * 16 + mt * 4 + 2 * g;
          o[0] = f2h(v0);
          o[1] = f2h(v1);
        }
      }
    }
  }
}

// ---------------- K3: FC 800->500 via fp16 MFMA ----------------
__global__ __launch_bounds__(256) void k_fc_mfma(const unsigned short* __restrict__ flat16,
                                                 const unsigned short* __restrict__ Wt,
                                                 const float* __restrict__ b,
                                                 float* __restrict__ H,
                                                 unsigned short* __restrict__ H16) {
  int tid = threadIdx.x;
  int wave = tid >> 6, lane = tid & 63;
  int r16 = lane & 15, g = lane >> 4;
  int bm = blockIdx.x & 15, bn = blockIdx.x >> 4;
  int m0 = bm * 256 + wave * 64;
  int n0 = bn * 32;

  f32x4 acc[4][2];
  #pragma unroll
  for (int mt = 0; mt < 4; mt++) {
    acc[mt][0] = (f32x4){0.f, 0.f, 0.f, 0.f};
    acc[mt][1] = (f32x4){0.f, 0.f, 0.f, 0.f};
  }

  const unsigned short* Abase = flat16 + (size_t)(m0 + r16) * 800 + 8 * g;
  const unsigned short* Bbase = Wt + (size_t)(n0 + r16) * 32 + 8 * g;

  for (int kt = 0; kt < 25; kt++) {
    uint4 bf0 = *(const uint4*)(Bbase + kt * 16384);
    uint4 bf1 = *(const uint4*)(Bbase + kt * 16384 + 512);
    f16x8 bv0 = __builtin_bit_cast(f16x8, bf0);
    f16x8 bv1 = __builtin_bit_cast(f16x8, bf1);
    #pragma unroll
    for (int mt = 0; mt < 4; mt++) {
      uint4 af = *(const uint4*)(Abase + mt * 12800 + kt * 32);
      f16x8 av = __builtin_bit_cast(f16x8, af);
      acc[mt][0] = __builtin_amdgcn_mfma_f32_16x16x32_f16(av, bv0, acc[mt][0], 0, 0, 0);
      acc[mt][1] = __builtin_amdgcn_mfma_f32_16x16x32_f16(av, bv1, acc[mt][1], 0, 0, 0);
    }
  }

  #pragma unroll
  for (int nt = 0; nt < 2; nt++) {
    int col = n0 + nt * 16 + r16;
    bool real = col < 500;
    float bias = real ? b[col] : 0.f;
    #pragma unroll
    for (int mt = 0; mt < 4; mt++) {
      #pragma unroll
      for (int j = 0; j < 4; j++) {
        int row = m0 + mt * 16 + 4 * g + j;
        float val = fmaxf(acc[mt][nt][j] + bias, 0.f);
        if (real) H[(size_t)row * 500 + col] = val;
        H16[(size_t)row * 512 + col] = f2h(val);
      }
    }
  }
}

// ---------------- K4: attn1 via fp16 MFMA + fused tanh/w2 reduction ----------------
__global__ __launch_bounds__(64) void k_attn1_mfma(const unsigned short* __restrict__ H16,
                                                   const unsigned short* __restrict__ Wt1,
                                                   const float* __restrict__ b1,   // [128]
                                                   const float* __restrict__ w2,   // [128]
                                                   const float* __restrict__ b2,   // [1]
                                                   float* __restrict__ a,
                                                   float* __restrict__ outA) {
  int lane = threadIdx.x;
  int r16 = lane & 15, g = lane >> 4;
  int m0 = blockIdx.x * 32;

  f32x4 acc[2][8];
  #pragma unroll
  for (int mt = 0; mt < 2; mt++)
    #pragma unroll
    for (int nt = 0; nt < 8; nt++) acc[mt][nt] = (f32x4){0.f, 0.f, 0.f, 0.f};

  const unsigned short* Abase = H16 + (size_t)(m0 + r16) * 512 + 8 * g;
  const unsigned short* Bbase = Wt1 + r16 * 32 + 8 * g;

  for (int kt = 0; kt < 16; kt++) {
    uint4 a0 = *(const uint4*)(Abase + kt * 32);
    uint4 a1 = *(const uint4*)(Abase + 16 * 512 + kt * 32);
    f16x8 av0 = __builtin_bit_cast(f16x8, a0);
    f16x8 av1 = __builtin_bit_cast(f16x8, a1);
    #pragma unroll
    for (int nt = 0; nt < 8; nt++) {
      uint4 bf = *(const uint4*)(Bbase + kt * 4096 + nt * 512);
      f16x8 bv = __builtin_bit_cast(f16x8, bf);
      acc[0][nt] = __builtin_amdgcn_mfma_f32_16x16x32_f16(av0, bv, acc[0][nt], 0, 0, 0);
      acc[1][nt] = __builtin_amdgcn_mfma_f32_16x16x32_f16(av1, bv, acc[1][nt], 0, 0, 0);
    }
  }

  float b1v[8], w2v[8];
  #pragma unroll
  for (int nt = 0; nt < 8; nt++) {
    int col = nt * 16 + r16;
    b1v[nt] = b1[col];
    w2v[nt] = w2[col];
  }
  float bb2 = b2[0];

  #pragma unroll
  for (int mt = 0; mt < 2; mt++) {
    float part[4];
    #pragma unroll
    for (int j = 0; j < 4; j++) {
      float s = 0.f;
      #pragma unroll
      for (int nt = 0; nt < 8; nt++)
        s += tanhf(acc[mt][nt][j] + b1v[nt]) * w2v[nt];
      part[j] = s;
    }
    #pragma unroll
    for (int off = 1; off < 16; off <<= 1) {
      #pragma unroll
      for (int j = 0; j < 4; j++) part[j] += __shfl_xor(part[j], off);
    }
    if (r16 == 0) {
      #pragma unroll
      for (int j = 0; j < 4; j++) {
        int row = m0 + mt * 16 + 4 * g + j;
        float val = part[j] + bb2;
        a[row] = val;
        outA[row] = val;
      }
    }
  }
}

// ---------------- K5: per-segment softmax pooling -> instance_f[S,500] ----------------
__global__ __launch_bounds__(256) void k_segpool(const float* __restrict__ a,
                                                 const float* __restrict__ H,
                                                 const int* __restrict__ idx,
                                                 float* __restrict__ instf) {
  __shared__ float red[4];
  __shared__ float sval;
  int s = blockIdx.x, tid = threadIdx.x;
  int i0 = idx[s], i1 = idx[s + 1];
  float mx = -INFINITY;
  for (int i = i0 + tid; i < i1; i += 256) mx = fmaxf(mx, a[i]);
  #pragma unroll
  for (int off = 32; off > 0; off >>= 1) mx = fmaxf(mx, __shfl_down(mx, off));
  if ((tid & 63) == 0) red[tid >> 6] = mx;
  __syncthreads();
  if (tid == 0) sval = fmaxf(fmaxf(red[0], red[1]), fmaxf(red[2], red[3]));
  __syncthreads();
  float m = sval;
  float sm = 0.f;
  for (int i = i0 + tid; i < i1; i += 256) sm += expf(a[i] - m);
  #pragma unroll
  for (int off = 32; off > 0; off >>= 1) sm += __shfl_down(sm, off);
  if ((tid & 63) == 0) red[tid >> 6] = sm;
  __syncthreads();
  if (tid == 0) sval = red[0] + red[1] + red[2] + red[3];
  __syncthreads();
  float inv = 1.f / sval;
  if (tid < 250) {
    float acc0 = 0.f, acc1 = 0.f;
    for (int i = i0; i < i1; i++) {
      float e = expf(a[i] - m) * inv;
      acc0 += e * H[(size_t)i * 500 + tid];
      acc1 += e * H[(size_t)i * 500 + tid + 250];
    }
    instf[s * 500 + tid] = acc0;
    instf[s * 500 + tid + 250] = acc1;
  }
}

// ---------------- K6: bag attention logits (split-K) ----------------
__global__ __launch_bounds__(512) void k_batt(const float* __restrict__ instf,
                                              const float* __restrict__ w1,
                                              const float* __restrict__ b1,
                                              const float* __restrict__ w2,
                                              const float* __restrict__ b2,
                                              float* __restrict__ batt) {
  __shared__ float fs[500];
  __shared__ float part[512];
  __shared__ float red[2];
  int s = blockIdx.x, tid = threadIdx.x;
  for (int i = tid; i < 500; i += 512) fs[i] = instf[s * 500 + i];
  __syncthreads();
  int c = tid & 127, q = tid >> 7;     // 4 K-chunks of 125
  float t = 0.f;
  int k0 = q * 125;
  #pragma unroll 5
  for (int k = k0; k < k0 + 125; k++) t += fs[k] * w1[k * 128 + c];
  part[tid] = t;
  __syncthreads();
  if (tid < 128) {
    float tt = part[tid] + part[tid + 128] + part[tid + 256] + part[tid + 384] + b1[tid];
    float v = tanhf(tt) * w2[tid];
    #pragma unroll
    for (int off = 32; off > 0; off >>= 1) v += __shfl_down(v, off);
    if ((tid & 63) == 0) red[tid >> 6] = v;
  }
  __syncthreads();
  if (tid == 0) batt[s] = red[0] + red[1] + b2[0];
}

// ---------------- K7: softmax(b_att) -> bag feature -> classifier ----------------
__global__ __launch_bounds__(256) void k_final(const float* __restrict__ batt,
                                               const float* __restrict__ instf,
                                               const float* __restrict__ clfw,
                                               const float* __restrict__ clfb,
                                               float* __restrict__ out) {
  __shared__ float Bsh[64];
  __shared__ float red[4];
  int tid = threadIdx.x;
  if (tid < 64) {
    float v = batt[tid];
    float mx = v;
    #pragma unroll
    for (int off = 32; off > 0; off >>= 1) mx = fmaxf(mx, __shfl_xor(mx, off));
    float e = expf(v - mx);
    float smv = e;
    #pragma unroll
    for (int off = 32; off > 0; off >>= 1) smv += __shfl_xor(smv, off);
    Bsh[tid] = e / smv;
  }
  __syncthreads();
  float part = 0.f;
  if (tid < 250) {
    float bag0 = 0.f, bag1 = 0.f;
    #pragma unroll 4
    for (int s2 = 0; s2 < 64; s2++) {
      float Bv = Bsh[s2];
      bag0 += Bv * instf[s2 * 500 + tid];
      bag1 += Bv * instf[s2 * 500 + tid + 250];
    }
    part = bag0 * clfw[tid] + bag1 * clfw[tid + 250];
  }
  #pragma unroll
  for (int off = 32; off > 0; off >>= 1) part += __shfl_down(part, off);
  if ((tid & 63) == 0) red[tid >> 6] = part;
  __syncthreads();
  if (tid == 0) {
    float z = red[0] + red[1] + red[2] + red[3] + clfb[0];
    out[0] = 1.f / (1.f + expf(-z));
    out[1] = (z >= 0.f) ? 1.f : 0.f;
  }
}

extern "C" void kernel_launch(void* const* d_in, const int* in_sizes, int n_in,
                              void* d_out, int out_size, void* d_ws, size_t ws_size,
                              hipStream_t stream) {
  const float* x       = (const float*)d_in[0];
  const int*   idx     = (const int*)d_in[1];
  const float* conv1_w = (const float*)d_in[2];
  const float* conv1_b = (const float*)d_in[3];
  const float* conv2_w = (const float*)d_in[4];
  const float* conv2_b = (const float*)d_in[5];
  const float* fc_w    = (const float*)d_in[6];
  const float* fc_b    = (const float*)d_in[7];
  const float* a1_w1   = (const float*)d_in[8];
  const float* a1_b1   = (const float*)d_in[9];
  const float* a1_w2   = (const float*)d_in[10];
  const float* a1_b2   = (const float*)d_in[11];
  const float* a2_w1   = (const float*)d_in[12];
  const float* a2_b1   = (const float*)d_in[13];
  const float* a2_w2   = (const float*)d_in[14];
  const float* a2_b2   = (const float*)d_in[15];
  const float* clf_w   = (const float*)d_in[16];
  const float* clf_b   = (const float*)d_in[17];
  float* out = (float*)d_out;

  int N = in_sizes[0] / 2352;     // 4096
  int S = in_sizes[1] - 1;        // 64

  // workspace layout
  float* wsf   = (float*)d_ws;
  float* H     = wsf;                          // N*500 f32
  float* a     = H + (size_t)N * 500;          // N
  float* instf = a + N;                        // S*500
  float* batt  = instf + (size_t)S * 500;      // S
  unsigned short* Wg    = (unsigned short*)(batt + S + 8);   // 38400
  unsigned short* Wc1g  = Wg + 38400;                        // 6400
  unsigned short* Wtfc  = Wc1g + 6400;                       // 409600
  unsigned short* Wt1   = Wtfc + 409600;                     // 65536
  unsigned short* flat16= Wt1 + 65536;                       // N*800 fp16
  unsigned short* H16   = flat16 + (size_t)N * 800;          // N*512 fp16

  k_prep_all<<<2031, 256, 0, stream>>>(conv1_w, conv2_w, fc_w, a1_w1, Wc1g, Wg, Wtfc, Wt1);
  k_conv12<<<N, 64, 0, stream>>>(x, Wc1g, conv1_b, Wg, conv2_b, flat16);
  k_fc_mfma<<<256, 256, 0, stream>>>(flat16, Wtfc, fc_b, H, H16);
  k_attn1_mfma<<<N / 32, 64, 0, stream>>>(H16, Wt1, a1_b1, a1_w2, a1_b2, a, out + 2);
  k_segpool<<<S, 256, 0, stream>>>(a, H, idx, instf);
  k_batt<<<S, 512, 0, stream>>>(instf, a2_w1, a2_b1, a2_w2, a2_b2, batt);
  k_final<<<1, 256, 0, stream>>>(batt, instf, clf_w, clf_b, out);
}

// Round 11
// 149.742 us; speedup vs baseline: 3.8546x; 1.0269x over previous
//
#include <hip/hip_runtime.h>
#include <math.h>

typedef _Float16 f16x8 __attribute__((ext_vector_type(8)));
typedef float    f32x4 __attribute__((ext_vector_type(4)));

static __device__ __forceinline__ unsigned short f2h(float f) {
  _Float16 h = (_Float16)f;                       // RNE
  return __builtin_bit_cast(unsigned short, h);
}

// ---------------- K0: merged one-time weight prep ----------------
__global__ __launch_bounds__(256) void k_prep_all(const float* __restrict__ c1w,
                                                  const float* __restrict__ c2w,
                                                  const float* __restrict__ fcw,
                                                  const float* __restrict__ a1w1,
                                                  unsigned short* __restrict__ Wc1g,
                                                  unsigned short* __restrict__ Wg,
                                                  unsigned short* __restrict__ Wtfc,
                                                  unsigned short* __restrict__ Wt1) {
  int i = blockIdx.x * 256 + threadIdx.x;
  if (i < 6400) {
    int kh = i / 1280, r = i % 1280;
    int co = r / 40, q = r % 40;
    int kw = q >> 2, ci = q & 3;
    Wc1g[i] = f2h((co < 20 && ci < 3 && kw < 5) ? c1w[((co * 3 + ci) * 5 + kh) * 5 + kw] : 0.f);
    return;
  }
  i -= 6400;
  if (i < 38400) {
    int tap = i / 1536, r = i % 1536;
    int co = r / 24, ci = r % 24;
    Wg[i] = f2h((co < 50 && ci < 20) ? c2w[(co * 20 + ci) * 25 + tap] : 0.f);
    return;
  }
  i -= 38400;
  if (i < 409600) {
    int kt = i >> 14, r = i & 16383;
    int nn = r >> 5, kk = r & 31;
    int k = kt * 32 + kk;
    Wtfc[i] = f2h((nn < 500) ? fcw[k * 500 + nn] : 0.f);
    return;
  }
  i -= 409600;
  if (i < 65536) {
    int kt = i >> 12, r = i & 4095;
    int col = r >> 5, kk = r & 31;
    int k = kt * 32 + kk;
    Wt1[i] = f2h((k < 500) ? a1w1[k * 128 + col] : 0.f);
  }
}

// ---------------- K1: FUSED conv1+pool -> conv2+pool, 128 threads / 1 image ----------------
// Wave0/wave1 split conv1 by chunk parity, conv2 by m-tile pair. LDS 13.3 KB.
__global__ __launch_bounds__(128, 2) void k_conv12(const float* __restrict__ x,
                                                   const unsigned short* __restrict__ Wc1g,
                                                   const float* __restrict__ cb1,   // conv1_b [20]
                                                   const unsigned short* __restrict__ Wg,
                                                   const float* __restrict__ cb2,   // conv2_b [50]
                                                   unsigned short* __restrict__ flat16) {
  __shared__ unsigned short xcl[3200];       // [800px][4ci] fp16 (tail 784..799 zero)
  __shared__ unsigned short h1s[3472];       // [144px][24co] + 16-short zero pad
  int tid = threadIdx.x;
  int n = blockIdx.x;
  int w = tid >> 6;                          // wave 0/1
  int lane = tid & 63;
  int r16 = lane & 15, g = lane >> 4;

  // zero h1s pad (conv2 g=3 junk A-read at pixel 143, tap 24 lands here)
  if (tid < 16) h1s[3456 + tid] = 0;
  // zero xcl tail (conv1 kw-pad junk reads)
  if (tid < 64) xcl[3136 + tid] = 0;
  // stage x -> channel-last fp16: load-all-then-write (static unroll, regs not scratch)
  {
    const float* xg = x + (size_t)n * 2352;
    float v0[7], v1[7], v2[7];
    #pragma unroll
    for (int i = 0; i < 7; ++i) {
      int p = tid + i * 128;
      if (p < 784) { v0[i] = xg[p]; v1[i] = xg[784 + p]; v2[i] = xg[1568 + p]; }
    }
    #pragma unroll
    for (int i = 0; i < 7; ++i) {
      int p = tid + i * 128;
      if (p < 784) {
        unsigned int lo = (unsigned int)f2h(v0[i]) | ((unsigned int)f2h(v1[i]) << 16);
        uint2 vv; vv.x = lo; vv.y = (unsigned int)f2h(v2[i]);   // ci3 = 0
        *(uint2*)(xcl + 4 * p) = vv;
      }
    }
  }
  __syncthreads();

  // ================= conv1: wave w takes chunks w, w+2, ... =================
  {
    f16x8 bv[5][2];
    #pragma unroll
    for (int kh = 0; kh < 5; kh++) {
      bv[kh][0] = __builtin_bit_cast(f16x8, *(const uint4*)(Wc1g + (kh * 32 + r16) * 40 + 8 * g));
      bv[kh][1] = __builtin_bit_cast(f16x8, *(const uint4*)(Wc1g + (kh * 32 + 16 + r16) * 40 + 8 * g));
    }
    float bias0 = cb1[r16];
    float bias1 = (r16 < 4) ? cb1[16 + r16] : 0.f;
    int ay = (r16 >> 3), ax = (r16 & 7) + 2 * g;

    for (int chunk = w; chunk < 9; chunk += 2) {
      f32x4 acc[4][2];
      #pragma unroll
      for (int ti = 0; ti < 4; ti++) {
        acc[ti][0] = (f32x4){0.f, 0.f, 0.f, 0.f};
        acc[ti][1] = (f32x4){0.f, 0.f, 0.f, 0.f};
      }
      #pragma unroll
      for (int kh = 0; kh < 5; kh++) {
        #pragma unroll
        for (int ti = 0; ti < 4; ti++) {
          int t = chunk * 4 + ti;
          int ty = t / 3, tx = t - ty * 3;
          int oy = 2 * ty + ay + kh;
          int ox = 8 * tx + ax;
          const unsigned short* p = xcl + (oy * 28 + ox) * 4;
          uint2 lo = *(const uint2*)p;
          uint2 hi = *(const uint2*)(p + 4);
          uint4 af; af.x = lo.x; af.y = lo.y; af.z = hi.x; af.w = hi.y;
          f16x8 av = __builtin_bit_cast(f16x8, af);
          acc[ti][0] = __builtin_amdgcn_mfma_f32_16x16x32_f16(av, bv[kh][0], acc[ti][0], 0, 0, 0);
          acc[ti][1] = __builtin_amdgcn_mfma_f32_16x16x32_f16(av, bv[kh][1], acc[ti][1], 0, 0, 0);
        }
      }
      // epilogue: 2x2 maxpool + bias + relu -> LDS h1s (channel-last, stride 24)
      #pragma unroll
      for (int ti = 0; ti < 4; ti++) {
        int t = chunk * 4 + ti;
        int ty = t / 3, tx = t - ty * 3;
        #pragma unroll
        for (int nt = 0; nt < 2; nt++) {
          int co = 16 * nt + r16;
          f32x4 c = acc[ti][nt];
          float h0 = fmaxf(c[0], c[1]);
          float h1 = fmaxf(c[2], c[3]);
          float v0 = fmaxf(h0, __shfl_xor(h0, 32));
          float v1 = fmaxf(h1, __shfl_xor(h1, 32));
          if (g < 2 && co < 24) {
            float bias = nt ? bias1 : bias0;          // co 20..23: acc=0,bias=0 -> 0
            v0 = fmaxf(v0 + bias, 0.f);
            v1 = fmaxf(v1 + bias, 0.f);
            int px0 = 4 * tx + 2 * g;
            unsigned short* o = h1s + (ty * 12 + px0) * 24 + co;
            o[0]  = f2h(v0);
            o[24] = f2h(v1);
          }
        }
      }
    }
  }
  __syncthreads();

  // ================= conv2: wave w takes m-tiles 2w, 2w+1 =================
  {
    float cbias0 = cb2[r16];
    float cbias1 = cb2[16 + r16];
    float cbias2 = cb2[32 + r16];
    float cbias3 = (r16 < 2) ? cb2[48 + r16] : 0.f;

    f32x4 acc[2][4];
    #pragma unroll
    for (int mt = 0; mt < 2; mt++)
      #pragma unroll
      for (int nt = 0; nt < 4; nt++) acc[mt][nt] = (f32x4){0.f, 0.f, 0.f, 0.f};

    uint4 FAa[2], FAb[4], FBa[2], FBb[4];
    auto load_frags = [&](uint4* A, uint4* B, int tap) {
      int kh = tap / 5, kw = tap % 5;
      #pragma unroll
      for (int nt = 0; nt < 4; nt++) {
        uint4 u = make_uint4(0, 0, 0, 0);
        if (g < 3) {
          int co = 16 * nt + r16;
          u = *(const uint4*)(Wg + tap * 1536 + co * 24 + 8 * g);
        }
        B[nt] = u;
      }
      #pragma unroll
      for (int mtp = 0; mtp < 2; mtp++) {
        int posl = (2 * w + mtp) * 16 + r16;
        int oy = posl >> 3, ox = posl & 7;
        A[mtp] = *(const uint4*)(h1s + ((oy + kh) * 12 + (ox + kw)) * 24 + 8 * g);
      }
    };
    auto mma = [&](const uint4* A, const uint4* B) {
      #pragma unroll
      for (int mt = 0; mt < 2; mt++) {
        f16x8 av = __builtin_bit_cast(f16x8, A[mt]);
        #pragma unroll
        for (int nt = 0; nt < 4; nt++) {
          acc[mt][nt] = __builtin_amdgcn_mfma_f32_16x16x32_f16(
              av, __builtin_bit_cast(f16x8, B[nt]), acc[mt][nt], 0, 0, 0);
        }
      }
    };

    load_frags(FAa, FAb, 0);
    for (int tap = 0; tap < 25; tap += 2) {
      if (tap + 1 < 25) load_frags(FBa, FBb, tap + 1);
      mma(FAa, FAb);
      if (tap + 2 < 25) load_frags(FAa, FAb, tap + 2);
      if (tap + 1 < 25) mma(FBa, FBb);
    }

    #pragma unroll
    for (int mtp = 0; mtp < 2; mtp++) {
      int py = 2 * w + mtp;
      #pragma unroll
      for (int nt = 0; nt < 4; nt++) {
        int co = 16 * nt + r16;
        f32x4 c = acc[mtp][nt];
        float h0 = fmaxf(c[0], c[1]);
        float h1 = fmaxf(c[2], c[3]);
        float v0 = fmaxf(h0, __shfl_xor(h0, 32));
        float v1 = fmaxf(h1, __shfl_xor(h1, 32));
        if (g < 2 && co < 50) {
          float bias = (nt == 0) ? cbias0 : (nt == 1) ? cbias1 : (nt == 2) ? cbias2 : cbias3;
          v0 = fmaxf(v0 + bias, 0.f);
          v1 = fmaxf(v1 + bias, 0.f);
          unsigned short* o = flat16 + ((size_t)n * 50 + co) * 16 + py * 4 + 2 * g;
          o[0] = f2h(v0);
          o[1] = f2h(v1);
        }
      }
    }
  }
}

// ---------------- K3: FC 800->500 via fp16 MFMA ----------------
__global__ __launch_bounds__(256) void k_fc_mfma(const unsigned short* __restrict__ flat16,
                                                 const unsigned short* __restrict__ Wt,
                                                 const float* __restrict__ b,
                                                 float* __restrict__ H,
                                                 unsigned short* __restrict__ H16) {
  int tid = threadIdx.x;
  int wave = tid >> 6, lane = tid & 63;
  int r16 = lane & 15, g = lane >> 4;
  int bm = blockIdx.x & 15, bn = blockIdx.x >> 4;
  int m0 = bm * 256 + wave * 64;
  int n0 = bn * 32;

  f32x4 acc[4][2];
  #pragma unroll
  for (int mt = 0; mt < 4; mt++) {
    acc[mt][0] = (f32x4){0.f, 0.f, 0.f, 0.f};
    acc[mt][1] = (f32x4){0.f, 0.f, 0.f, 0.f};
  }

  const unsigned short* Abase = flat16 + (size_t)(m0 + r16) * 800 + 8 * g;
  const unsigned short* Bbase = Wt + (size_t)(n0 + r16) * 32 + 8 * g;

  for (int kt = 0; kt < 25; kt++) {
    uint4 bf0 = *(const uint4*)(Bbase + kt * 16384);
    uint4 bf1 = *(const uint4*)(Bbase + kt * 16384 + 512);
    f16x8 bv0 = __builtin_bit_cast(f16x8, bf0);
    f16x8 bv1 = __builtin_bit_cast(f16x8, bf1);
    #pragma unroll
    for (int mt = 0; mt < 4; mt++) {
      uint4 af = *(const uint4*)(Abase + mt * 12800 + kt * 32);
      f16x8 av = __builtin_bit_cast(f16x8, af);
      acc[mt][0] = __builtin_amdgcn_mfma_f32_16x16x32_f16(av, bv0, acc[mt][0], 0, 0, 0);
      acc[mt][1] = __builtin_amdgcn_mfma_f32_16x16x32_f16(av, bv1, acc[mt][1], 0, 0, 0);
    }
  }

  #pragma unroll
  for (int nt = 0; nt < 2; nt++) {
    int col = n0 + nt * 16 + r16;
    bool real = col < 500;
    float bias = real ? b[col] : 0.f;
    #pragma unroll
    for (int mt = 0; mt < 4; mt++) {
      #pragma unroll
      for (int j = 0; j < 4; j++) {
        int row = m0 + mt * 16 + 4 * g + j;
        float val = fmaxf(acc[mt][nt][j] + bias, 0.f);
        if (real) H[(size_t)row * 500 + col] = val;
        H16[(size_t)row * 512 + col] = f2h(val);
      }
    }
  }
}

// ---------------- K4: attn1 via fp16 MFMA + fused tanh/w2 reduction ----------------
__global__ __launch_bounds__(64) void k_attn1_mfma(const unsigned short* __restrict__ H16,
                                                   const unsigned short* __restrict__ Wt1,
                                                   const float* __restrict__ b1,   // [128]
                                                   const float* __restrict__ w2,   // [128]
                                                   const float* __restrict__ b2,   // [1]
                                                   float* __restrict__ a,
                                                   float* __restrict__ outA) {
  int lane = threadIdx.x;
  int r16 = lane & 15, g = lane >> 4;
  int m0 = blockIdx.x * 32;

  f32x4 acc[2][8];
  #pragma unroll
  for (int mt = 0; mt < 2; mt++)
    #pragma unroll
    for (int nt = 0; nt < 8; nt++) acc[mt][nt] = (f32x4){0.f, 0.f, 0.f, 0.f};

  const unsigned short* Abase = H16 + (size_t)(m0 + r16) * 512 + 8 * g;
  const unsigned short* Bbase = Wt1 + r16 * 32 + 8 * g;

  for (int kt = 0; kt < 16; kt++) {
    uint4 a0 = *(const uint4*)(Abase + kt * 32);
    uint4 a1 = *(const uint4*)(Abase + 16 * 512 + kt * 32);
    f16x8 av0 = __builtin_bit_cast(f16x8, a0);
    f16x8 av1 = __builtin_bit_cast(f16x8, a1);
    #pragma unroll
    for (int nt = 0; nt < 8; nt++) {
      uint4 bf = *(const uint4*)(Bbase + kt * 4096 + nt * 512);
      f16x8 bv = __builtin_bit_cast(f16x8, bf);
      acc[0][nt] = __builtin_amdgcn_mfma_f32_16x16x32_f16(av0, bv, acc[0][nt], 0, 0, 0);
      acc[1][nt] = __builtin_amdgcn_mfma_f32_16x16x32_f16(av1, bv, acc[1][nt], 0, 0, 0);
    }
  }

  float b1v[8], w2v[8];
  #pragma unroll
  for (int nt = 0; nt < 8; nt++) {
    int col = nt * 16 + r16;
    b1v[nt] = b1[col];
    w2v[nt] = w2[col];
  }
  float bb2 = b2[0];

  #pragma unroll
  for (int mt = 0; mt < 2; mt++) {
    float part[4];
    #pragma unroll
    for (int j = 0; j < 4; j++) {
      float s = 0.f;
      #pragma unroll
      for (int nt = 0; nt < 8; nt++)
        s += tanhf(acc[mt][nt][j] + b1v[nt]) * w2v[nt];
      part[j] = s;
    }
    #pragma unroll
    for (int off = 1; off < 16; off <<= 1) {
      #pragma unroll
      for (int j = 0; j < 4; j++) part[j] += __shfl_xor(part[j], off);
    }
    if (r16 == 0) {
      #pragma unroll
      for (int j = 0; j < 4; j++) {
        int row = m0 + mt * 16 + 4 * g + j;
        float val = part[j] + bb2;
        a[row] = val;
        outA[row] = val;
      }
    }
  }
}

// ---------------- K5: FUSED per-segment softmax pooling + bag-attn logit ----------------
// block s: instf[s][500] (kept in LDS) and batt[s]
__global__ __launch_bounds__(512) void k_segbatt(const float* __restrict__ a,
                                                 const float* __restrict__ H,
                                                 const int* __restrict__ idx,
                                                 const float* __restrict__ w1,   // a2_w1 [500,128]
                                                 const float* __restrict__ b1,   // a2_b1 [128]
                                                 const float* __restrict__ w2,   // a2_w2 [128]
                                                 const float* __restrict__ b2,   // a2_b2 [1]
                                                 float* __restrict__ instf,
                                                 float* __restrict__ batt) {
  __shared__ float fs[500];
  __shared__ float part[512];
  __shared__ float red[8];
  __shared__ float sval;
  int s = blockIdx.x, tid = threadIdx.x;
  int i0 = idx[s], i1 = idx[s + 1];

  // segment max
  float mx = -INFINITY;
  for (int i = i0 + tid; i < i1; i += 512) mx = fmaxf(mx, a[i]);
  #pragma unroll
  for (int off = 32; off > 0; off >>= 1) mx = fmaxf(mx, __shfl_down(mx, off));
  if ((tid & 63) == 0) red[tid >> 6] = mx;
  __syncthreads();
  if (tid == 0) {
    float m2 = red[0];
    #pragma unroll
    for (int j = 1; j < 8; j++) m2 = fmaxf(m2, red[j]);
    sval = m2;
  }
  __syncthreads();
  float m = sval;
  // denom
  float sm = 0.f;
  for (int i = i0 + tid; i < i1; i += 512) sm += expf(a[i] - m);
  #pragma unroll
  for (int off = 32; off > 0; off >>= 1) sm += __shfl_down(sm, off);
  if ((tid & 63) == 0) red[tid >> 6] = sm;
  __syncthreads();
  if (tid == 0) {
    float t2 = 0.f;
    #pragma unroll
    for (int j = 0; j < 8; j++) t2 += red[j];
    sval = t2;
  }
  __syncthreads();
  float inv = 1.f / sval;
  // weighted pooling -> fs + instf
  if (tid < 250) {
    float acc0 = 0.f, acc1 = 0.f;
    for (int i = i0; i < i1; i++) {
      float e = expf(a[i] - m) * inv;
      acc0 += e * H[(size_t)i * 500 + tid];
      acc1 += e * H[(size_t)i * 500 + tid + 250];
    }
    instf[s * 500 + tid] = acc0;
    instf[s * 500 + tid + 250] = acc1;
    fs[tid] = acc0;
    fs[tid + 250] = acc1;
  }
  __syncthreads();
  // bag-attn logit (split-K over 4 chunks of 125)
  int c = tid & 127, q = tid >> 7;
  float t = 0.f;
  int k0 = q * 125;
  #pragma unroll 5
  for (int k = k0; k < k0 + 125; k++) t += fs[k] * w1[k * 128 + c];
  part[tid] = t;
  __syncthreads();
  if (tid < 128) {
    float tt = part[tid] + part[tid + 128] + part[tid + 256] + part[tid + 384] + b1[tid];
    float v = tanhf(tt) * w2[tid];
    #pragma unroll
    for (int off = 32; off > 0; off >>= 1) v += __shfl_down(v, off);
    if ((tid & 63) == 0) red[tid >> 6] = v;
  }
  __syncthreads();
  if (tid == 0) batt[s] = red[0] + red[1] + b2[0];
}

// ---------------- K7: softmax(b_att) -> bag feature -> classifier ----------------
__global__ __launch_bounds__(256) void k_final(const float* __restrict__ batt,
                                               const float* __restrict__ instf,
                                               const float* __restrict__ clfw,
                                               const float* __restrict__ clfb,
                                               float* __restrict__ out) {
  __shared__ float Bsh[64];
  __shared__ float red[4];
  int tid = threadIdx.x;
  if (tid < 64) {
    float v = batt[tid];
    float mx = v;
    #pragma unroll
    for (int off = 32; off > 0; off >>= 1) mx = fmaxf(mx, __shfl_xor(mx, off));
    float e = expf(v - mx);
    float smv = e;
    #pragma unroll
    for (int off = 32; off > 0; off >>= 1) smv += __shfl_xor(smv, off);
    Bsh[tid] = e / smv;
  }
  __syncthreads();
  float part = 0.f;
  if (tid < 250) {
    float bag0 = 0.f, bag1 = 0.f;
    #pragma unroll 4
    for (int s2 = 0; s2 < 64; s2++) {
      float Bv = Bsh[s2];
      bag0 += Bv * instf[s2 * 500 + tid];
      bag1 += Bv * instf[s2 * 500 + tid + 250];
    }
    part = bag0 * clfw[tid] + bag1 * clfw[tid + 250];
  }
  #pragma unroll
  for (int off = 32; off > 0; off >>= 1) part += __shfl_down(part, off);
  if ((tid & 63) == 0) red[tid >> 6] = part;
  __syncthreads();
  if (tid == 0) {
    float z = red[0] + red[1] + red[2] + red[3] + clfb[0];
    out[0] = 1.f / (1.f + expf(-z));
    out[1] = (z >= 0.f) ? 1.f : 0.f;
  }
}

extern "C" void kernel_launch(void* const* d_in, const int* in_sizes, int n_in,
                              void* d_out, int out_size, void* d_ws, size_t ws_size,
                              hipStream_t stream) {
  const float* x       = (const float*)d_in[0];
  const int*   idx     = (const int*)d_in[1];
  const float* conv1_w = (const float*)d_in[2];
  const float* conv1_b = (const float*)d_in[3];
  const float* conv2_w = (const float*)d_in[4];
  const float* conv2_b = (const float*)d_in[5];
  const float* fc_w    = (const float*)d_in[6];
  const float* fc_b    = (const float*)d_in[7];
  const float* a1_w1   = (const float*)d_in[8];
  const float* a1_b1   = (const float*)d_in[9];
  const float* a1_w2   = (const float*)d_in[10];
  const float* a1_b2   = (const float*)d_in[11];
  const float* a2_w1   = (const float*)d_in[12];
  const float* a2_b1   = (const float*)d_in[13];
  const float* a2_w2   = (const float*)d_in[14];
  const float* a2_b2   = (const float*)d_in[15];
  const float* clf_w   = (const float*)d_in[16];
  const float* clf_b   = (const float*)d_in[17];
  float* out = (float*)d_out;

  int N = in_sizes[0] / 2352;     // 4096
  int S = in_sizes[1] - 1;        // 64

  // workspace layout
  float* wsf   = (float*)d_ws;
  float* H     = wsf;                          // N*500 f32
  float* a     = H + (size_t)N * 500;          // N
  float* instf = a + N;                        // S*500
  float* batt  = instf + (size_t)S * 500;      // S
  unsigned short* Wg    = (unsigned short*)(batt + S + 8);   // 38400
  unsigned short* Wc1g  = Wg + 38400;                        // 6400
  unsigned short* Wtfc  = Wc1g + 6400;                       // 409600
  unsigned short* Wt1   = Wtfc + 409600;                     // 65536
  unsigned short* flat16= Wt1 + 65536;                       // N*800 fp16
  unsigned short* H16   = flat16 + (size_t)N * 800;          // N*512 fp16

  k_prep_all<<<2031, 256, 0, stream>>>(conv1_w, conv2_w, fc_w, a1_w1, Wc1g, Wg, Wtfc, Wt1);
  k_conv12<<<N, 128, 0, stream>>>(x, Wc1g, conv1_b, Wg, conv2_b, flat16);
  k_fc_mfma<<<256, 256, 0, stream>>>(flat16, Wtfc, fc_b, H, H16);
  k_attn1_mfma<<<N / 32, 64, 0, stream>>>(H16, Wt1, a1_b1, a1_w2, a1_b2, a, out + 2);
  k_segbatt<<<S, 512, 0, stream>>>(a, H, idx, a2_w1, a2_b1, a2_w2, a2_b2, instf, batt);
  k_final<<<1, 256, 0, stream>>>(batt, instf, clf_w, clf_b, out);
}

// Round 12
// 130.659 us; speedup vs baseline: 4.4176x; 1.1460x over previous
//
#include <hip/hip_runtime.h>
#include <math.h>

typedef _Float16 f16x8 __attribute__((ext_vector_type(8)));
typedef float    f32x4 __attribute__((ext_vector_type(4)));

static __device__ __forceinline__ unsigned short f2h(float f) {
  _Float16 h = (_Float16)f;                       // RNE
  return __builtin_bit_cast(unsigned short, h);
}

// ---------------- K0: merged one-time weight prep ----------------
__global__ __launch_bounds__(256) void k_prep_all(const float* __restrict__ c1w,
                                                  const float* __restrict__ c2w,
                                                  const float* __restrict__ fcw,
                                                  const float* __restrict__ a1w1,
                                                  unsigned short* __restrict__ Wc1g,
                                                  unsigned short* __restrict__ Wg,
                                                  unsigned short* __restrict__ Wtfc,
                                                  unsigned short* __restrict__ Wt1) {
  int i = blockIdx.x * 256 + threadIdx.x;
  if (i < 6400) {
    int kh = i / 1280, r = i % 1280;
    int co = r / 40, q = r % 40;
    int kw = q >> 2, ci = q & 3;
    Wc1g[i] = f2h((co < 20 && ci < 3 && kw < 5) ? c1w[((co * 3 + ci) * 5 + kh) * 5 + kw] : 0.f);
    return;
  }
  i -= 6400;
  if (i < 38400) {
    int tap = i / 1536, r = i % 1536;
    int co = r / 24, ci = r % 24;
    Wg[i] = f2h((co < 50 && ci < 20) ? c2w[(co * 20 + ci) * 25 + tap] : 0.f);
    return;
  }
  i -= 38400;
  if (i < 409600) {
    int kt = i >> 14, r = i & 16383;
    int nn = r >> 5, kk = r & 31;
    int k = kt * 32 + kk;
    Wtfc[i] = f2h((nn < 500) ? fcw[k * 500 + nn] : 0.f);
    return;
  }
  i -= 409600;
  if (i < 65536) {
    int kt = i >> 12, r = i & 4095;
    int col = r >> 5, kk = r & 31;
    int k = kt * 32 + kk;
    Wt1[i] = f2h((k < 500) ? a1w1[k * 128 + col] : 0.f);
  }
}

// ---------------- K1: FUSED conv1+pool -> conv2+pool, 128 threads / 1 image ----------------
// All LDS/global addresses = lane-base + compile-time immediate (static chunk/tap unroll).
__global__ __launch_bounds__(128, 2) void k_conv12(const float* __restrict__ x,
                                                   const unsigned short* __restrict__ Wc1g,
                                                   const float* __restrict__ cb1,   // conv1_b [20]
                                                   const unsigned short* __restrict__ Wg,
                                                   const float* __restrict__ cb2,   // conv2_b [50]
                                                   unsigned short* __restrict__ flat16) {
  __shared__ unsigned short xcl[3200];       // [800px][4ci] fp16 (tail 784..799 zero)
  __shared__ unsigned short h1s[3472];       // [144px][24co] + 16-short zero pad
  int tid = threadIdx.x;
  int n = blockIdx.x;
  int w = tid >> 6;                          // wave 0/1
  int lane = tid & 63;
  int r16 = lane & 15, g = lane >> 4;

  if (tid < 16) h1s[3456 + tid] = 0;         // conv2 g=3 junk A-read target: must be finite
  if (tid < 64) xcl[3136 + tid] = 0;         // conv1 kw-pad junk reads
  // stage x -> channel-last fp16 (load-all-then-write, static indices)
  {
    const float* xg = x + (size_t)n * 2352;
    float v0[7], v1[7], v2[7];
    #pragma unroll
    for (int i = 0; i < 7; ++i) {
      int p = tid + i * 128;
      if (p < 784) { v0[i] = xg[p]; v1[i] = xg[784 + p]; v2[i] = xg[1568 + p]; }
    }
    #pragma unroll
    for (int i = 0; i < 7; ++i) {
      int p = tid + i * 128;
      if (p < 784) {
        unsigned int lo = (unsigned int)f2h(v0[i]) | ((unsigned int)f2h(v1[i]) << 16);
        uint2 vv; vv.x = lo; vv.y = (unsigned int)f2h(v2[i]);   // ci3 = 0
        *(uint2*)(xcl + 4 * p) = vv;
      }
    }
  }
  __syncthreads();

  // ================= conv1: static chunks per wave =================
  {
    f16x8 bv[5][2];
    #pragma unroll
    for (int kh = 0; kh < 5; kh++) {
      bv[kh][0] = __builtin_bit_cast(f16x8, *(const uint4*)(Wc1g + (kh * 32 + r16) * 40 + 8 * g));
      bv[kh][1] = __builtin_bit_cast(f16x8, *(const uint4*)(Wc1g + (kh * 32 + 16 + r16) * 40 + 8 * g));
    }
    float bias0 = cb1[r16];
    float bias1 = (r16 < 4) ? cb1[16 + r16] : 0.f;
    int ay = (r16 >> 3), ax = (r16 & 7) + 2 * g;
    const unsigned short* xlane = xcl + (ay * 28 + ax) * 4;   // lane base (shorts)

    auto do_chunk = [&](const int chunk) {
      f32x4 acc[4][2];
      #pragma unroll
      for (int ti = 0; ti < 4; ti++) {
        acc[ti][0] = (f32x4){0.f, 0.f, 0.f, 0.f};
        acc[ti][1] = (f32x4){0.f, 0.f, 0.f, 0.f};
      }
      #pragma unroll
      for (int kh = 0; kh < 5; kh++) {
        #pragma unroll
        for (int ti = 0; ti < 4; ti++) {
          const int t = chunk * 4 + ti;
          const int ty = t / 3, tx = t - ty * 3;
          // compile-time immediate offset (shorts)
          const unsigned short* p = xlane + ((2 * ty + kh) * 28 + 8 * tx) * 4;
          uint2 lo = *(const uint2*)p;
          uint2 hi = *(const uint2*)(p + 4);
          uint4 af; af.x = lo.x; af.y = lo.y; af.z = hi.x; af.w = hi.y;
          f16x8 av = __builtin_bit_cast(f16x8, af);
          acc[ti][0] = __builtin_amdgcn_mfma_f32_16x16x32_f16(av, bv[kh][0], acc[ti][0], 0, 0, 0);
          acc[ti][1] = __builtin_amdgcn_mfma_f32_16x16x32_f16(av, bv[kh][1], acc[ti][1], 0, 0, 0);
        }
      }
      #pragma unroll
      for (int ti = 0; ti < 4; ti++) {
        const int t = chunk * 4 + ti;
        const int ty = t / 3, tx = t - ty * 3;
        #pragma unroll
        for (int nt = 0; nt < 2; nt++) {
          int co = 16 * nt + r16;
          f32x4 c = acc[ti][nt];
          float h0 = fmaxf(c[0], c[1]);
          float h1 = fmaxf(c[2], c[3]);
          float v0 = fmaxf(h0, __shfl_xor(h0, 32));
          float v1 = fmaxf(h1, __shfl_xor(h1, 32));
          if (g < 2 && co < 24) {
            float bias = nt ? bias1 : bias0;          // co 20..23: acc=0,bias=0 -> 0
            v0 = fmaxf(v0 + bias, 0.f);
            v1 = fmaxf(v1 + bias, 0.f);
            int px0 = 4 * tx + 2 * g;
            unsigned short* o = h1s + (ty * 12 + px0) * 24 + co;
            o[0]  = f2h(v0);
            o[24] = f2h(v1);
          }
        }
      }
    };
    if (w == 0) { do_chunk(0); do_chunk(2); do_chunk(4); do_chunk(6); do_chunk(8); }
    else        { do_chunk(1); do_chunk(3); do_chunk(5); do_chunk(7); }
  }
  __syncthreads();

  // ================= conv2: wave w takes m-tiles 2w, 2w+1 =================
  {
    float cbias0 = cb2[r16];
    float cbias1 = cb2[16 + r16];
    float cbias2 = cb2[32 + r16];
    float cbias3 = (r16 < 2) ? cb2[48 + r16] : 0.f;

    // hoisted lane bases; per-tap deltas are compile-time constants
    const unsigned short* Ab[2];
    #pragma unroll
    for (int mtp = 0; mtp < 2; mtp++) {
      int posl = (2 * w + mtp) * 16 + r16;
      int oy = posl >> 3, ox = posl & 7;
      Ab[mtp] = h1s + (oy * 12 + ox) * 24 + 8 * g;
    }
    const unsigned short* Bb = Wg + r16 * 24 + 8 * g;   // + nt*384 + tap*1536

    f32x4 acc[2][4];
    #pragma unroll
    for (int mt = 0; mt < 2; mt++)
      #pragma unroll
      for (int nt = 0; nt < 4; nt++) acc[mt][nt] = (f32x4){0.f, 0.f, 0.f, 0.f};

    uint4 FAa[2], FAb[4], FBa[2], FBb[4];
    auto lf = [&](uint4* A, uint4* B, const int tap) {
      const int kh = tap / 5, kw = tap % 5;             // folds: tap is literal
      const int dA = (kh * 12 + kw) * 24;
      const int dB = tap * 1536;
      #pragma unroll
      for (int nt = 0; nt < 4; nt++) {
        uint4 u = make_uint4(0, 0, 0, 0);
        if (g < 3) u = *(const uint4*)(Bb + dB + nt * 384);
        B[nt] = u;
      }
      A[0] = *(const uint4*)(Ab[0] + dA);
      A[1] = *(const uint4*)(Ab[1] + dA);
    };
    auto mma = [&](const uint4* A, const uint4* B) {
      #pragma unroll
      for (int mt = 0; mt < 2; mt++) {
        f16x8 av = __builtin_bit_cast(f16x8, A[mt]);
        #pragma unroll
        for (int nt = 0; nt < 4; nt++) {
          acc[mt][nt] = __builtin_amdgcn_mfma_f32_16x16x32_f16(
              av, __builtin_bit_cast(f16x8, B[nt]), acc[mt][nt], 0, 0, 0);
        }
      }
    };

    lf(FAa, FAb, 0);
    #pragma unroll
    for (int tap = 0; tap < 25; tap += 2) {
      if (tap + 1 < 25) lf(FBa, FBb, tap + 1);
      mma(FAa, FAb);
      if (tap + 2 < 25) lf(FAa, FAb, tap + 2);
      if (tap + 1 < 25) mma(FBa, FBb);
    }

    #pragma unroll
    for (int mtp = 0; mtp < 2; mtp++) {
      int py = 2 * w + mtp;
      #pragma unroll
      for (int nt = 0; nt < 4; nt++) {
        int co = 16 * nt + r16;
        f32x4 c = acc[mtp][nt];
        float h0 = fmaxf(c[0], c[1]);
        float h1 = fmaxf(c[2], c[3]);
        float v0 = fmaxf(h0, __shfl_xor(h0, 32));
        float v1 = fmaxf(h1, __shfl_xor(h1, 32));
        if (g < 2 && co < 50) {
          float bias = (nt == 0) ? cbias0 : (nt == 1) ? cbias1 : (nt == 2) ? cbias2 : cbias3;
          v0 = fmaxf(v0 + bias, 0.f);
          v1 = fmaxf(v1 + bias, 0.f);
          unsigned short* o = flat16 + ((size_t)n * 50 + co) * 16 + py * 4 + 2 * g;
          o[0] = f2h(v0);
          o[1] = f2h(v1);
        }
      }
    }
  }
}

// ---------------- K3: FC 800->500 via fp16 MFMA ----------------
__global__ __launch_bounds__(256) void k_fc_mfma(const unsigned short* __restrict__ flat16,
                                                 const unsigned short* __restrict__ Wt,
                                                 const float* __restrict__ b,
                                                 float* __restrict__ H,
                                                 unsigned short* __restrict__ H16) {
  int tid = threadIdx.x;
  int wave = tid >> 6, lane = tid & 63;
  int r16 = lane & 15, g = lane >> 4;
  int bm = blockIdx.x & 15, bn = blockIdx.x >> 4;
  int m0 = bm * 256 + wave * 64;
  int n0 = bn * 32;

  f32x4 acc[4][2];
  #pragma unroll
  for (int mt = 0; mt < 4; mt++) {
    acc[mt][0] = (f32x4){0.f, 0.f, 0.f, 0.f};
    acc[mt][1] = (f32x4){0.f, 0.f, 0.f, 0.f};
  }

  const unsigned short* Abase = flat16 + (size_t)(m0 + r16) * 800 + 8 * g;
  const unsigned short* Bbase = Wt + (size_t)(n0 + r16) * 32 + 8 * g;

  for (int kt = 0; kt < 25; kt++) {
    uint4 bf0 = *(const uint4*)(Bbase + kt * 16384);
    uint4 bf1 = *(const uint4*)(Bbase + kt * 16384 + 512);
    f16x8 bv0 = __builtin_bit_cast(f16x8, bf0);
    f16x8 bv1 = __builtin_bit_cast(f16x8, bf1);
    #pragma unroll
    for (int mt = 0; mt < 4; mt++) {
      uint4 af = *(const uint4*)(Abase + mt * 12800 + kt * 32);
      f16x8 av = __builtin_bit_cast(f16x8, af);
      acc[mt][0] = __builtin_amdgcn_mfma_f32_16x16x32_f16(av, bv0, acc[mt][0], 0, 0, 0);
      acc[mt][1] = __builtin_amdgcn_mfma_f32_16x16x32_f16(av, bv1, acc[mt][1], 0, 0, 0);
    }
  }

  #pragma unroll
  for (int nt = 0; nt < 2; nt++) {
    int col = n0 + nt * 16 + r16;
    bool real = col < 500;
    float bias = real ? b[col] : 0.f;
    #pragma unroll
    for (int mt = 0; mt < 4; mt++) {
      #pragma unroll
      for (int j = 0; j < 4; j++) {
        int row = m0 + mt * 16 + 4 * g + j;
        float val = fmaxf(acc[mt][nt][j] + bias, 0.f);
        if (real) H[(size_t)row * 500 + col] = val;
        H16[(size_t)row * 512 + col] = f2h(val);
      }
    }
  }
}

// ---------------- K4: attn1 via fp16 MFMA + fused tanh/w2 reduction ----------------
__global__ __launch_bounds__(64) void k_attn1_mfma(const unsigned short* __restrict__ H16,
                                                   const unsigned short* __restrict__ Wt1,
                                                   const float* __restrict__ b1,   // [128]
                                                   const float* __restrict__ w2,   // [128]
                                                   const float* __restrict__ b2,   // [1]
                                                   float* __restrict__ a,
                                                   float* __restrict__ outA) {
  int lane = threadIdx.x;
  int r16 = lane & 15, g = lane >> 4;
  int m0 = blockIdx.x * 32;

  f32x4 acc[2][8];
  #pragma unroll
  for (int mt = 0; mt < 2; mt++)
    #pragma unroll
    for (int nt = 0; nt < 8; nt++) acc[mt][nt] = (f32x4){0.f, 0.f, 0.f, 0.f};

  const unsigned short* Abase = H16 + (size_t)(m0 + r16) * 512 + 8 * g;
  const unsigned short* Bbase = Wt1 + r16 * 32 + 8 * g;

  for (int kt = 0; kt < 16; kt++) {
    uint4 a0 = *(const uint4*)(Abase + kt * 32);
    uint4 a1 = *(const uint4*)(Abase + 16 * 512 + kt * 32);
    f16x8 av0 = __builtin_bit_cast(f16x8, a0);
    f16x8 av1 = __builtin_bit_cast(f16x8, a1);
    #pragma unroll
    for (int nt = 0; nt < 8; nt++) {
      uint4 bf = *(const uint4*)(Bbase + kt * 4096 + nt * 512);
      f16x8 bv = __builtin_bit_cast(f16x8, bf);
      acc[0][nt] = __builtin_amdgcn_mfma_f32_16x16x32_f16(av0, bv, acc[0][nt], 0, 0, 0);
      acc[1][nt] = __builtin_amdgcn_mfma_f32_16x16x32_f16(av1, bv, acc[1][nt], 0, 0, 0);
    }
  }

  float b1v[8], w2v[8];
  #pragma unroll
  for (int nt = 0; nt < 8; nt++) {
    int col = nt * 16 + r16;
    b1v[nt] = b1[col];
    w2v[nt] = w2[col];
  }
  float bb2 = b2[0];

  #pragma unroll
  for (int mt = 0; mt < 2; mt++) {
    float part[4];
    #pragma unroll
    for (int j = 0; j < 4; j++) {
      float s = 0.f;
      #pragma unroll
      for (int nt = 0; nt < 8; nt++)
        s += tanhf(acc[mt][nt][j] + b1v[nt]) * w2v[nt];
      part[j] = s;
    }
    #pragma unroll
    for (int off = 1; off < 16; off <<= 1) {
      #pragma unroll
      for (int j = 0; j < 4; j++) part[j] += __shfl_xor(part[j], off);
    }
    if (r16 == 0) {
      #pragma unroll
      for (int j = 0; j < 4; j++) {
        int row = m0 + mt * 16 + 4 * g + j;
        float val = part[j] + bb2;
        a[row] = val;
        outA[row] = val;
      }
    }
  }
}

// ---------------- K5: FUSED per-segment softmax pooling + bag-attn logit ----------------
// Pooling parallelized 2x over instance halves.
__global__ __launch_bounds__(512) void k_segbatt(const float* __restrict__ a,
                                                 const float* __restrict__ H,
                                                 const int* __restrict__ idx,
                                                 const float* __restrict__ w1,   // a2_w1 [500,128]
                                                 const float* __restrict__ b1,   // a2_b1 [128]
                                                 const float* __restrict__ w2,   // a2_w2 [128]
                                                 const float* __restrict__ b2,   // a2_b2 [1]
                                                 float* __restrict__ instf,
                                                 float* __restrict__ batt) {
  __shared__ float fs[500];
  __shared__ float part[512];
  __shared__ float poolA[2][256];
  __shared__ float poolB[2][256];
  __shared__ float red[8];
  __shared__ float sval;
  int s = blockIdx.x, tid = threadIdx.x;
  int i0 = idx[s], i1 = idx[s + 1];

  // segment max
  float mx = -INFINITY;
  for (int i = i0 + tid; i < i1; i += 512) mx = fmaxf(mx, a[i]);
  #pragma unroll
  for (int off = 32; off > 0; off >>= 1) mx = fmaxf(mx, __shfl_down(mx, off));
  if ((tid & 63) == 0) red[tid >> 6] = mx;
  __syncthreads();
  if (tid == 0) {
    float m2 = red[0];
    #pragma unroll
    for (int j = 1; j < 8; j++) m2 = fmaxf(m2, red[j]);
    sval = m2;
  }
  __syncthreads();
  float m = sval;
  // denom
  float sm = 0.f;
  for (int i = i0 + tid; i < i1; i += 512) sm += expf(a[i] - m);
  #pragma unroll
  for (int off = 32; off > 0; off >>= 1) sm += __shfl_down(sm, off);
  if ((tid & 63) == 0) red[tid >> 6] = sm;
  __syncthreads();
  if (tid == 0) {
    float t2 = 0.f;
    #pragma unroll
    for (int j = 0; j < 8; j++) t2 += red[j];
    sval = t2;
  }
  __syncthreads();
  float inv = 1.f / sval;
  // weighted pooling: 2 halves of the instance range in parallel
  {
    int half = tid >> 8;          // 0/1
    int col = tid & 255;
    int mid = (i0 + i1) >> 1;
    int lo = half ? mid : i0;
    int hi = half ? i1 : mid;
    if (col < 250) {
      float acc0 = 0.f, acc1 = 0.f;
      for (int i = lo; i < hi; i++) {
        float e = expf(a[i] - m) * inv;
        acc0 += e * H[(size_t)i * 500 + col];
        acc1 += e * H[(size_t)i * 500 + col + 250];
      }
      poolA[half][col] = acc0;
      poolB[half][col] = acc1;
    }
  }
  __syncthreads();
  if (tid < 250) {
    float acc0 = poolA[0][tid] + poolA[1][tid];
    float acc1 = poolB[0][tid] + poolB[1][tid];
    instf[s * 500 + tid] = acc0;
    instf[s * 500 + tid + 250] = acc1;
    fs[tid] = acc0;
    fs[tid + 250] = acc1;
  }
  __syncthreads();
  // bag-attn logit (split-K over 4 chunks of 125)
  int c = tid & 127, q = tid >> 7;
  float t = 0.f;
  int k0 = q * 125;
  #pragma unroll 5
  for (int k = k0; k < k0 + 125; k++) t += fs[k] * w1[k * 128 + c];
  part[tid] = t;
  __syncthreads();
  if (tid < 128) {
    float tt = part[tid] + part[tid + 128] + part[tid + 256] + part[tid + 384] + b1[tid];
    float v = tanhf(tt) * w2[tid];
    #pragma unroll
    for (int off = 32; off > 0; off >>= 1) v += __shfl_down(v, off);
    if ((tid & 63) == 0) red[tid >> 6] = v;
  }
  __syncthreads();
  if (tid == 0) batt[s] = red[0] + red[1] + b2[0];
}

// ---------------- K7: softmax(b_att) -> bag feature -> classifier ----------------
__global__ __launch_bounds__(256) void k_final(const float* __restrict__ batt,
                                               const float* __restrict__ instf,
                                               const float* __restrict__ clfw,
                                               const float* __restrict__ clfb,
                                               float* __restrict__ out) {
  __shared__ float Bsh[64];
  __shared__ float red[4];
  int tid = threadIdx.x;
  if (tid < 64) {
    float v = batt[tid];
    float mx = v;
    #pragma unroll
    for (int off = 32; off > 0; off >>= 1) mx = fmaxf(mx, __shfl_xor(mx, off));
    float e = expf(v - mx);
    float smv = e;
    #pragma unroll
    for (int off = 32; off > 0; off >>= 1) smv += __shfl_xor(smv, off);
    Bsh[tid] = e / smv;
  }
  __syncthreads();
  float part = 0.f;
  if (tid < 250) {
    float bag0 = 0.f, bag1 = 0.f;
    #pragma unroll 4
    for (int s2 = 0; s2 < 64; s2++) {
      float Bv = Bsh[s2];
      bag0 += Bv * instf[s2 * 500 + tid];
      bag1 += Bv * instf[s2 * 500 + tid + 250];
    }
    part = bag0 * clfw[tid] + bag1 * clfw[tid + 250];
  }
  #pragma unroll
  for (int off = 32; off > 0; off >>= 1) part += __shfl_down(part, off);
  if ((tid & 63) == 0) red[tid >> 6] = part;
  __syncthreads();
  if (tid == 0) {
    float z = red[0] + red[1] + red[2] + red[3] + clfb[0];
    out[0] = 1.f / (1.f + expf(-z));
    out[1] = (z >= 0.f) ? 1.f : 0.f;
  }
}

extern "C" void kernel_launch(void* const* d_in, const int* in_sizes, int n_in,
                              void* d_out, int out_size, void* d_ws, size_t ws_size,
                              hipStream_t stream) {
  const float* x       = (const float*)d_in[0];
  const int*   idx     = (const int*)d_in[1];
  const float* conv1_w = (const float*)d_in[2];
  const float* conv1_b = (const float*)d_in[3];
  const float* conv2_w = (const float*)d_in[4];
  const float* conv2_b = (const float*)d_in[5];
  const float* fc_w    = (const float*)d_in[6];
  const float* fc_b    = (const float*)d_in[7];
  const float* a1_w1   = (const float*)d_in[8];
  const float* a1_b1   = (const float*)d_in[9];
  const float* a1_w2   = (const float*)d_in[10];
  const float* a1_b2   = (const float*)d_in[11];
  const float* a2_w1   = (const float*)d_in[12];
  const float* a2_b1   = (const float*)d_in[13];
  const float* a2_w2   = (const float*)d_in[14];
  const float* a2_b2   = (const float*)d_in[15];
  const float* clf_w   = (const float*)d_in[16];
  const float* clf_b   = (const float*)d_in[17];
  float* out = (float*)d_out;

  int N = in_sizes[0] / 2352;     // 4096
  int S = in_sizes[1] - 1;        // 64

  // workspace layout
  float* wsf   = (float*)d_ws;
  float* H     = wsf;                          // N*500 f32
  float* a     = H + (size_t)N * 500;          // N
  float* instf = a + N;                        // S*500
  float* batt  = instf + (size_t)S * 500;      // S
  unsigned short* Wg    = (unsigned short*)(batt + S + 8);   // 38400
  unsigned short* Wc1g  = Wg + 38400;                        // 6400
  unsigned short* Wtfc  = Wc1g + 6400;                       // 409600
  unsigned short* Wt1   = Wtfc + 409600;                     // 65536
  unsigned short* flat16= Wt1 + 65536;                       // N*800 fp16
  unsigned short* H16   = flat16 + (size_t)N * 800;          // N*512 fp16

  k_prep_all<<<2031, 256, 0, stream>>>(conv1_w, conv2_w, fc_w, a1_w1, Wc1g, Wg, Wtfc, Wt1);
  k_conv12<<<N, 128, 0, stream>>>(x, Wc1g, conv1_b, Wg, conv2_b, flat16);
  k_fc_mfma<<<256, 256, 0, stream>>>(flat16, Wtfc, fc_b, H, H16);
  k_attn1_mfma<<<N / 32, 64, 0, stream>>>(H16, Wt1, a1_b1, a1_w2, a1_b2, a, out + 2);
  k_segbatt<<<S, 512, 0, stream>>>(a, H, idx, a2_w1, a2_b1, a2_w2, a2_b2, instf, batt);
  k_final<<<1, 256, 0, stream>>>(batt, instf, clf_w, clf_b, out);
}

// Round 13
// 125.526 us; speedup vs baseline: 4.5982x; 1.0409x over previous
//
#include <hip/hip_runtime.h>
#include <math.h>

typedef _Float16 f16x8 __attribute__((ext_vector_type(8)));
typedef float    f32x4 __attribute__((ext_vector_type(4)));

static __device__ __forceinline__ unsigned short f2h(float f) {
  _Float16 h = (_Float16)f;                       // RNE
  return __builtin_bit_cast(unsigned short, h);
}
// packed f16 helpers (VOP3P)
static __device__ __forceinline__ unsigned int pk_max(unsigned int a, unsigned int b) {
  unsigned int d;
  asm("v_pk_max_f16 %0, %1, %2" : "=v"(d) : "v"(a), "v"(b));
  return d;
}
static __device__ __forceinline__ unsigned int pk_add(unsigned int a, unsigned int b) {
  unsigned int d;
  asm("v_pk_add_f16 %0, %1, %2" : "=v"(d) : "v"(a), "v"(b));
  return d;
}
static __device__ __forceinline__ unsigned int pkh2(float lo, float hi) {
  return (unsigned int)f2h(lo) | ((unsigned int)f2h(hi) << 16);
}

// ---------------- K0: merged one-time weight prep ----------------
__global__ __launch_bounds__(256) void k_prep_all(const float* __restrict__ c1w,
                                                  const float* __restrict__ c2w,
                                                  const float* __restrict__ fcw,
                                                  const float* __restrict__ a1w1,
                                                  unsigned short* __restrict__ Wc1g,
                                                  unsigned short* __restrict__ Wg,
                                                  unsigned short* __restrict__ Wtfc,
                                                  unsigned short* __restrict__ Wt1) {
  int i = blockIdx.x * 256 + threadIdx.x;
  if (i < 6400) {
    int kh = i / 1280, r = i % 1280;
    int co = r / 40, q = r % 40;
    int kw = q >> 2, ci = q & 3;
    Wc1g[i] = f2h((co < 20 && ci < 3 && kw < 5) ? c1w[((co * 3 + ci) * 5 + kh) * 5 + kw] : 0.f);
    return;
  }
  i -= 6400;
  if (i < 38400) {
    int tap = i / 1536, r = i % 1536;
    int co = r / 24, ci = r % 24;
    Wg[i] = f2h((co < 50 && ci < 20) ? c2w[(co * 20 + ci) * 25 + tap] : 0.f);
    return;
  }
  i -= 38400;
  if (i < 409600) {
    int kt = i >> 14, r = i & 16383;
    int nn = r >> 5, kk = r & 31;
    int k = kt * 32 + kk;
    Wtfc[i] = f2h((nn < 500) ? fcw[k * 500 + nn] : 0.f);
    return;
  }
  i -= 409600;
  if (i < 65536) {
    int kt = i >> 12, r = i & 4095;
    int col = r >> 5, kk = r & 31;
    int k = kt * 32 + kk;
    Wt1[i] = f2h((k < 500) ? a1w1[k * 128 + col] : 0.f);
  }
}

// ---------------- K1: FUSED conv1+pool -> conv2+pool, 128 threads / 1 image ----------------
__global__ __launch_bounds__(128, 2) void k_conv12(const float* __restrict__ x,
                                                   const unsigned short* __restrict__ Wc1g,
                                                   const float* __restrict__ cb1,   // conv1_b [20]
                                                   const unsigned short* __restrict__ Wg,
                                                   const float* __restrict__ cb2,   // conv2_b [50]
                                                   unsigned short* __restrict__ flat16) {
  __shared__ unsigned short xcl[3200];       // [800px][4ci] fp16 (tail 784..799 zero)
  __shared__ unsigned short h1s[3472];       // [144px][24co] + 16-short zero pad
  int tid = threadIdx.x;
  int n = blockIdx.x;
  int w = tid >> 6;                          // wave 0/1
  int lane = tid & 63;
  int r16 = lane & 15, g = lane >> 4;

  if (tid < 16) h1s[3456 + tid] = 0;         // conv2 g=3 junk A-read target: must be finite
  if (tid < 64) xcl[3136 + tid] = 0;         // conv1 kw-pad junk reads
  // stage x -> channel-last fp16 (load-all-then-write, static indices)
  {
    const float* xg = x + (size_t)n * 2352;
    float v0[7], v1[7], v2[7];
    #pragma unroll
    for (int i = 0; i < 7; ++i) {
      int p = tid + i * 128;
      if (p < 784) { v0[i] = xg[p]; v1[i] = xg[784 + p]; v2[i] = xg[1568 + p]; }
    }
    #pragma unroll
    for (int i = 0; i < 7; ++i) {
      int p = tid + i * 128;
      if (p < 784) {
        uint2 vv; vv.x = pkh2(v0[i], v1[i]); vv.y = (unsigned int)f2h(v2[i]);  // ci3 = 0
        *(uint2*)(xcl + 4 * p) = vv;
      }
    }
  }
  __syncthreads();

  // ================= conv1: static chunks per wave =================
  {
    f16x8 bv[5][2];
    #pragma unroll
    for (int kh = 0; kh < 5; kh++) {
      bv[kh][0] = __builtin_bit_cast(f16x8, *(const uint4*)(Wc1g + (kh * 32 + r16) * 40 + 8 * g));
      bv[kh][1] = __builtin_bit_cast(f16x8, *(const uint4*)(Wc1g + (kh * 32 + 16 + r16) * 40 + 8 * g));
    }
    float bias0 = cb1[r16];
    float bias1 = (r16 < 4) ? cb1[16 + r16] : 0.f;
    unsigned int b2_0 = pkh2(bias0, bias0);
    unsigned int b2_1 = pkh2(bias1, bias1);
    int ay = (r16 >> 3), ax = (r16 & 7) + 2 * g;
    const unsigned short* xlane = xcl + (ay * 28 + ax) * 4;   // lane base (shorts)

    auto do_chunk = [&](const int chunk) {
      f32x4 acc[4][2];
      #pragma unroll
      for (int ti = 0; ti < 4; ti++) {
        acc[ti][0] = (f32x4){0.f, 0.f, 0.f, 0.f};
        acc[ti][1] = (f32x4){0.f, 0.f, 0.f, 0.f};
      }
      #pragma unroll
      for (int kh = 0; kh < 5; kh++) {
        #pragma unroll
        for (int ti = 0; ti < 4; ti++) {
          const int t = chunk * 4 + ti;
          const int ty = t / 3, tx = t - ty * 3;
          const unsigned short* p = xlane + ((2 * ty + kh) * 28 + 8 * tx) * 4;
          uint2 lo = *(const uint2*)p;
          uint2 hi = *(const uint2*)(p + 4);
          uint4 af; af.x = lo.x; af.y = lo.y; af.z = hi.x; af.w = hi.y;
          f16x8 av = __builtin_bit_cast(f16x8, af);
          acc[ti][0] = __builtin_amdgcn_mfma_f32_16x16x32_f16(av, bv[kh][0], acc[ti][0], 0, 0, 0);
          acc[ti][1] = __builtin_amdgcn_mfma_f32_16x16x32_f16(av, bv[kh][1], acc[ti][1], 0, 0, 0);
        }
      }
      // packed-f16 epilogue: pool + bias + relu -> h1s
      #pragma unroll
      for (int ti = 0; ti < 4; ti++) {
        const int t = chunk * 4 + ti;
        const int ty = t / 3, tx = t - ty * 3;
        #pragma unroll
        for (int nt = 0; nt < 2; nt++) {
          int co = 16 * nt + r16;
          f32x4 c = acc[ti][nt];
          // horizontal pool in f32, pack (px0,px0+1) -> one u32
          unsigned int pk = pkh2(fmaxf(c[0], c[1]), fmaxf(c[2], c[3]));
          unsigned int other = (unsigned int)__shfl_xor((int)pk, 32);   // vertical pool partner
          unsigned int m2 = pk_max(pk, other);
          unsigned int r2 = pk_max(pk_add(m2, nt ? b2_1 : b2_0), 0u);   // +bias, relu
          if (g < 2 && co < 24) {
            int px0 = 4 * tx + 2 * g;
            unsigned short* o = h1s + (ty * 12 + px0) * 24 + co;
            o[0]  = (unsigned short)r2;
            o[24] = (unsigned short)(r2 >> 16);
          }
        }
      }
    };
    if (w == 0) { do_chunk(0); do_chunk(2); do_chunk(4); do_chunk(6); do_chunk(8); }
    else        { do_chunk(1); do_chunk(3); do_chunk(5); do_chunk(7); }
  }
  __syncthreads();

  // ================= conv2: wave w takes m-tiles 2w, 2w+1 =================
  {
    unsigned int cbp[4];
    cbp[0] = pkh2(cb2[r16], cb2[r16]);
    cbp[1] = pkh2(cb2[16 + r16], cb2[16 + r16]);
    cbp[2] = pkh2(cb2[32 + r16], cb2[32 + r16]);
    float cb3 = (r16 < 2) ? cb2[48 + r16] : 0.f;
    cbp[3] = pkh2(cb3, cb3);

    const unsigned short* Ab[2];
    #pragma unroll
    for (int mtp = 0; mtp < 2; mtp++) {
      int posl = (2 * w + mtp) * 16 + r16;
      int oy = posl >> 3, ox = posl & 7;
      Ab[mtp] = h1s + (oy * 12 + ox) * 24 + 8 * g;
    }
    const unsigned short* Bb = Wg + r16 * 24 + 8 * g;   // + nt*384 + tap*1536

    f32x4 acc[2][4];
    #pragma unroll
    for (int mt = 0; mt < 2; mt++)
      #pragma unroll
      for (int nt = 0; nt < 4; nt++) acc[mt][nt] = (f32x4){0.f, 0.f, 0.f, 0.f};

    uint4 FAa[2], FAb[4], FBa[2], FBb[4];
    auto lf = [&](uint4* A, uint4* B, const int tap) {
      const int kh = tap / 5, kw = tap % 5;             // folds: tap is literal
      const int dA = (kh * 12 + kw) * 24;
      const int dB = tap * 1536;
      #pragma unroll
      for (int nt = 0; nt < 4; nt++) {
        uint4 u = make_uint4(0, 0, 0, 0);
        if (g < 3) u = *(const uint4*)(Bb + dB + nt * 384);
        B[nt] = u;
      }
      A[0] = *(const uint4*)(Ab[0] + dA);
      A[1] = *(const uint4*)(Ab[1] + dA);
    };
    auto mma = [&](const uint4* A, const uint4* B) {
      #pragma unroll
      for (int mt = 0; mt < 2; mt++) {
        f16x8 av = __builtin_bit_cast(f16x8, A[mt]);
        #pragma unroll
        for (int nt = 0; nt < 4; nt++) {
          acc[mt][nt] = __builtin_amdgcn_mfma_f32_16x16x32_f16(
              av, __builtin_bit_cast(f16x8, B[nt]), acc[mt][nt], 0, 0, 0);
        }
      }
    };

    lf(FAa, FAb, 0);
    #pragma unroll
    for (int tap = 0; tap < 25; tap += 2) {
      if (tap + 1 < 25) lf(FBa, FBb, tap + 1);
      mma(FAa, FAb);
      if (tap + 2 < 25) lf(FAa, FAb, tap + 2);
      if (tap + 1 < 25) mma(FBa, FBb);
    }

    #pragma unroll
    for (int mtp = 0; mtp < 2; mtp++) {
      int py = 2 * w + mtp;
      #pragma unroll
      for (int nt = 0; nt < 4; nt++) {
        int co = 16 * nt + r16;
        f32x4 c = acc[mtp][nt];
        unsigned int pk = pkh2(fmaxf(c[0], c[1]), fmaxf(c[2], c[3]));
        unsigned int other = (unsigned int)__shfl_xor((int)pk, 32);
        unsigned int m2 = pk_max(pk, other);
        unsigned int r2 = pk_max(pk_add(m2, cbp[nt]), 0u);
        if (g < 2 && co < 50) {
          // two adjacent shorts -> single u32 store (4B aligned)
          *(unsigned int*)(flat16 + ((size_t)n * 50 + co) * 16 + py * 4 + 2 * g) = r2;
        }
      }
    }
  }
}

// ---------------- K3: FC 800->500 via fp16 MFMA ----------------
__global__ __launch_bounds__(256) void k_fc_mfma(const unsigned short* __restrict__ flat16,
                                                 const unsigned short* __restrict__ Wt,
                                                 const float* __restrict__ b,
                                                 float* __restrict__ H,
                                                 unsigned short* __restrict__ H16) {
  int tid = threadIdx.x;
  int wave = tid >> 6, lane = tid & 63;
  int r16 = lane & 15, g = lane >> 4;
  int bm = blockIdx.x & 15, bn = blockIdx.x >> 4;
  int m0 = bm * 256 + wave * 64;
  int n0 = bn * 32;

  f32x4 acc[4][2];
  #pragma unroll
  for (int mt = 0; mt < 4; mt++) {
    acc[mt][0] = (f32x4){0.f, 0.f, 0.f, 0.f};
    acc[mt][1] = (f32x4){0.f, 0.f, 0.f, 0.f};
  }

  const unsigned short* Abase = flat16 + (size_t)(m0 + r16) * 800 + 8 * g;
  const unsigned short* Bbase = Wt + (size_t)(n0 + r16) * 32 + 8 * g;

  for (int kt = 0; kt < 25; kt++) {
    uint4 bf0 = *(const uint4*)(Bbase + kt * 16384);
    uint4 bf1 = *(const uint4*)(Bbase + kt * 16384 + 512);
    f16x8 bv0 = __builtin_bit_cast(f16x8, bf0);
    f16x8 bv1 = __builtin_bit_cast(f16x8, bf1);
    #pragma unroll
    for (int mt = 0; mt < 4; mt++) {
      uint4 af = *(const uint4*)(Abase + mt * 12800 + kt * 32);
      f16x8 av = __builtin_bit_cast(f16x8, af);
      acc[mt][0] = __builtin_amdgcn_mfma_f32_16x16x32_f16(av, bv0, acc[mt][0], 0, 0, 0);
      acc[mt][1] = __builtin_amdgcn_mfma_f32_16x16x32_f16(av, bv1, acc[mt][1], 0, 0, 0);
    }
  }

  #pragma unroll
  for (int nt = 0; nt < 2; nt++) {
    int col = n0 + nt * 16 + r16;
    bool real = col < 500;
    float bias = real ? b[col] : 0.f;
    #pragma unroll
    for (int mt = 0; mt < 4; mt++) {
      #pragma unroll
      for (int j = 0; j < 4; j++) {
        int row = m0 + mt * 16 + 4 * g + j;
        float val = fmaxf(acc[mt][nt][j] + bias, 0.f);
        if (real) H[(size_t)row * 500 + col] = val;
        H16[(size_t)row * 512 + col] = f2h(val);
      }
    }
  }
}

// ---------------- K4: attn1 via fp16 MFMA + fused tanh/w2 reduction ----------------
__global__ __launch_bounds__(64) void k_attn1_mfma(const unsigned short* __restrict__ H16,
                                                   const unsigned short* __restrict__ Wt1,
                                                   const float* __restrict__ b1,   // [128]
                                                   const float* __restrict__ w2,   // [128]
                                                   const float* __restrict__ b2,   // [1]
                                                   float* __restrict__ a,
                                                   float* __restrict__ outA) {
  int lane = threadIdx.x;
  int r16 = lane & 15, g = lane >> 4;
  int m0 = blockIdx.x * 32;

  f32x4 acc[2][8];
  #pragma unroll
  for (int mt = 0; mt < 2; mt++)
    #pragma unroll
    for (int nt = 0; nt < 8; nt++) acc[mt][nt] = (f32x4){0.f, 0.f, 0.f, 0.f};

  const unsigned short* Abase = H16 + (size_t)(m0 + r16) * 512 + 8 * g;
  const unsigned short* Bbase = Wt1 + r16 * 32 + 8 * g;

  for (int kt = 0; kt < 16; kt++) {
    uint4 a0 = *(const uint4*)(Abase + kt * 32);
    uint4 a1 = *(const uint4*)(Abase + 16 * 512 + kt * 32);
    f16x8 av0 = __builtin_bit_cast(f16x8, a0);
    f16x8 av1 = __builtin_bit_cast(f16x8, a1);
    #pragma unroll
    for (int nt = 0; nt < 8; nt++) {
      uint4 bf = *(const uint4*)(Bbase + kt * 4096 + nt * 512);
      f16x8 bv = __builtin_bit_cast(f16x8, bf);
      acc[0][nt] = __builtin_amdgcn_mfma_f32_16x16x32_f16(av0, bv, acc[0][nt], 0, 0, 0);
      acc[1][nt] = __builtin_amdgcn_mfma_f32_16x16x32_f16(av1, bv, acc[1][nt], 0, 0, 0);
    }
  }

  float b1v[8], w2v[8];
  #pragma unroll
  for (int nt = 0; nt < 8; nt++) {
    int col = nt * 16 + r16;
    b1v[nt] = b1[col];
    w2v[nt] = w2[col];
  }
  float bb2 = b2[0];

  #pragma unroll
  for (int mt = 0; mt < 2; mt++) {
    float part[4];
    #pragma unroll
    for (int j = 0; j < 4; j++) {
      float s = 0.f;
      #pragma unroll
      for (int nt = 0; nt < 8; nt++)
        s += tanhf(acc[mt][nt][j] + b1v[nt]) * w2v[nt];
      part[j] = s;
    }
    #pragma unroll
    for (int off = 1; off < 16; off <<= 1) {
      #pragma unroll
      for (int j = 0; j < 4; j++) part[j] += __shfl_xor(part[j], off);
    }
    if (r16 == 0) {
      #pragma unroll
      for (int j = 0; j < 4; j++) {
        int row = m0 + mt * 16 + 4 * g + j;
        float val = part[j] + bb2;
        a[row] = val;
        outA[row] = val;
      }
    }
  }
}

// ---------------- K5: FUSED per-segment softmax pooling + bag-attn logit ----------------
// Pooling 4-way over instance quarters; thread t<125 handles cols t,t+125,t+250,t+375.
__global__ __launch_bounds__(512) void k_segbatt(const float* __restrict__ a,
                                                 const float* __restrict__ H,
                                                 const int* __restrict__ idx,
                                                 const float* __restrict__ w1,   // a2_w1 [500,128]
                                                 const float* __restrict__ b1,   // a2_b1 [128]
                                                 const float* __restrict__ w2,   // a2_w2 [128]
                                                 const float* __restrict__ b2,   // a2_b2 [1]
                                                 float* __restrict__ instf,
                                                 float* __restrict__ batt) {
  __shared__ float fs[500];
  __shared__ float part[512];
  __shared__ float pool[4][500];
  __shared__ float red[8];
  __shared__ float sval;
  int s = blockIdx.x, tid = threadIdx.x;
  int i0 = idx[s], i1 = idx[s + 1];

  // segment max
  float mx = -INFINITY;
  for (int i = i0 + tid; i < i1; i += 512) mx = fmaxf(mx, a[i]);
  #pragma unroll
  for (int off = 32; off > 0; off >>= 1) mx = fmaxf(mx, __shfl_down(mx, off));
  if ((tid & 63) == 0) red[tid >> 6] = mx;
  __syncthreads();
  if (tid == 0) {
    float m2 = red[0];
    #pragma unroll
    for (int j = 1; j < 8; j++) m2 = fmaxf(m2, red[j]);
    sval = m2;
  }
  __syncthreads();
  float m = sval;
  // denom
  float sm = 0.f;
  for (int i = i0 + tid; i < i1; i += 512) sm += expf(a[i] - m);
  #pragma unroll
  for (int off = 32; off > 0; off >>= 1) sm += __shfl_down(sm, off);
  if ((tid & 63) == 0) red[tid >> 6] = sm;
  __syncthreads();
  if (tid == 0) {
    float t2 = 0.f;
    #pragma unroll
    for (int j = 0; j < 8; j++) t2 += red[j];
    sval = t2;
  }
  __syncthreads();
  float inv = 1.f / sval;
  // weighted pooling: 4 instance-quarters in parallel
  {
    int q = tid >> 7;             // 0..3
    int t = tid & 127;
    int len = i1 - i0;
    int lo = i0 + (len * q) / 4;
    int hi = i0 + (len * (q + 1)) / 4;
    if (t < 125) {
      float a0 = 0.f, a1 = 0.f, a2 = 0.f, a3 = 0.f;
      for (int i = lo; i < hi; i++) {
        float e = expf(a[i] - m) * inv;
        const float* Hr = H + (size_t)i * 500 + t;
        a0 += e * Hr[0];
        a1 += e * Hr[125];
        a2 += e * Hr[250];
        a3 += e * Hr[375];
      }
      pool[q][t]       = a0;
      pool[q][t + 125] = a1;
      pool[q][t + 250] = a2;
      pool[q][t + 375] = a3;
    }
  }
  __syncthreads();
  if (tid < 500) {
    float v = pool[0][tid] + pool[1][tid] + pool[2][tid] + pool[3][tid];
    instf[s * 500 + tid] = v;
    fs[tid] = v;
  }
  __syncthreads();
  // bag-attn logit (split-K over 4 chunks of 125)
  int c = tid & 127, q = tid >> 7;
  float t = 0.f;
  int k0 = q * 125;
  #pragma unroll 5
  for (int k = k0; k < k0 + 125; k++) t += fs[k] * w1[k * 128 + c];
  part[tid] = t;
  __syncthreads();
  if (tid < 128) {
    float tt = part[tid] + part[tid + 128] + part[tid + 256] + part[tid + 384] + b1[tid];
    float v = tanhf(tt) * w2[tid];
    #pragma unroll
    for (int off = 32; off > 0; off >>= 1) v += __shfl_down(v, off);
    if ((tid & 63) == 0) red[tid >> 6] = v;
  }
  __syncthreads();
  if (tid == 0) batt[s] = red[0] + red[1] + b2[0];
}

// ---------------- K7: softmax(b_att) -> bag feature -> classifier ----------------
__global__ __launch_bounds__(256) void k_final(const float* __restrict__ batt,
                                               const float* __restrict__ instf,
                                               const float* __restrict__ clfw,
                                               const float* __restrict__ clfb,
                                               float* __restrict__ out) {
  __shared__ float Bsh[64];
  __shared__ float red[4];
  int tid = threadIdx.x;
  if (tid < 64) {
    float v = batt[tid];
    float mx = v;
    #pragma unroll
    for (int off = 32; off > 0; off >>= 1) mx = fmaxf(mx, __shfl_xor(mx, off));
    float e = expf(v - mx);
    float smv = e;
    #pragma unroll
    for (int off = 32; off > 0; off >>= 1) smv += __shfl_xor(smv, off);
    Bsh[tid] = e / smv;
  }
  __syncthreads();
  float part = 0.f;
  if (tid < 250) {
    float bag0 = 0.f, bag1 = 0.f;
    #pragma unroll 4
    for (int s2 = 0; s2 < 64; s2++) {
      float Bv = Bsh[s2];
      bag0 += Bv * instf[s2 * 500 + tid];
      bag1 += Bv * instf[s2 * 500 + tid + 250];
    }
    part = bag0 * clfw[tid] + bag1 * clfw[tid + 250];
  }
  #pragma unroll
  for (int off = 32; off > 0; off >>= 1) part += __shfl_down(part, off);
  if ((tid & 63) == 0) red[tid >> 6] = part;
  __syncthreads();
  if (tid == 0) {
    float z = red[0] + red[1] + red[2] + red[3] + clfb[0];
    out[0] = 1.f / (1.f + expf(-z));
    out[1] = (z >= 0.f) ? 1.f : 0.f;
  }
}

extern "C" void kernel_launch(void* const* d_in, const int* in_sizes, int n_in,
                              void* d_out, int out_size, void* d_ws, size_t ws_size,
                              hipStream_t stream) {
  const float* x       = (const float*)d_in[0];
  const int*   idx     = (const int*)d_in[1];
  const float* conv1_w = (const float*)d_in[2];
  const float* conv1_b = (const float*)d_in[3];
  const float* conv2_w = (const float*)d_in[4];
  const float* conv2_b = (const float*)d_in[5];
  const float* fc_w    = (const float*)d_in[6];
  const float* fc_b    = (const float*)d_in[7];
  const float* a1_w1   = (const float*)d_in[8];
  const float* a1_b1   = (const float*)d_in[9];
  const float* a1_w2   = (const float*)d_in[10];
  const float* a1_b2   = (const float*)d_in[11];
  const float* a2_w1   = (const float*)d_in[12];
  const float* a2_b1   = (const float*)d_in[13];
  const float* a2_w2   = (const float*)d_in[14];
  const float* a2_b2   = (const float*)d_in[15];
  const float* clf_w   = (const float*)d_in[16];
  const float* clf_b   = (const float*)d_in[17];
  float* out = (float*)d_out;

  int N = in_sizes[0] / 2352;     // 4096
  int S = in_sizes[1] - 1;        // 64

  // workspace layout
  float* wsf   = (float*)d_ws;
  float* H     = wsf;                          // N*500 f32
  float* a     = H + (size_t)N * 500;          // N
  float* instf = a + N;                        // S*500
  float* batt  = instf + (size_t)S * 500;      // S
  unsigned short* Wg    = (unsigned short*)(batt + S + 8);   // 38400
  unsigned short* Wc1g  = Wg + 38400;                        // 6400
  unsigned short* Wtfc  = Wc1g + 6400;                       // 409600
  unsigned short* Wt1   = Wtfc + 409600;                     // 65536
  unsigned short* flat16= Wt1 + 65536;                       // N*800 fp16
  unsigned short* H16   = flat16 + (size_t)N * 800;          // N*512 fp16

  k_prep_all<<<2031, 256, 0, stream>>>(conv1_w, conv2_w, fc_w, a1_w1, Wc1g, Wg, Wtfc, Wt1);
  k_conv12<<<N, 128, 0, stream>>>(x, Wc1g, conv1_b, Wg, conv2_b, flat16);
  k_fc_mfma<<<256, 256, 0, stream>>>(flat16, Wtfc, fc_b, H, H16);
  k_attn1_mfma<<<N / 32, 64, 0, stream>>>(H16, Wt1, a1_b1, a1_w2, a1_b2, a, out + 2);
  k_segbatt<<<S, 512, 0, stream>>>(a, H, idx, a2_w1, a2_b1, a2_w2, a2_b2, instf, batt);
  k_final<<<1, 256, 0, stream>>>(batt, instf, clf_w, clf_b, out);
}